// Round 20
// baseline (760.436 us; speedup 1.0000x reference)
//
#include <hip/hip_runtime.h>
#include <math.h>

#define HWc 65536
#define Wd 256
#define Hd 256

typedef __attribute__((ext_vector_type(8))) short bf16x8;
typedef __attribute__((ext_vector_type(4))) float f32x4;

__device__ inline ushort f2bf_hi(float a) {
    uint u = __float_as_uint(a);
    uint r = u + 0x7FFFu + ((u >> 16) & 1u);
    return (ushort)(r >> 16);
}
__device__ inline float bf2f(ushort h) { return __uint_as_float((uint)h << 16); }

// ---- ws layout (float offsets), small buffers FIRST ----
static const size_t SSQ_Q_OFF = 0;        // 768
static const size_t SSQ_K_OFF = 768;      // 768
static const size_t ATTN_OFF  = 1536;     // 18432 -> 19968
static const size_t QWF_OFF   = 19968;    // 9216 floats = hi/lo ushort frag table
static const size_t KWF_OFF   = 29184;    // 9216
static const size_t VWF_OFF   = 38400;    // 9216
static const size_t W2F_OFF   = 47616;    // 8 * 9216 = 73728 -> 121344
static const size_t WS1_OFF   = 121344;   // 8*96*HWc floats (201 MB)

// ---- precompute bf16 hi/lo weight frag table: wf[ks][m][kk], kk = c&31 ----
__global__ void prep_wfrag(const float* __restrict__ w, int woff,
                           ushort* __restrict__ wf) {
    int idx = blockIdx.x * 256 + threadIdx.x;
    if (idx < 9216) {
        int m = idx / 96, c = idx % 96;
        float val = w[(size_t)(woff + m) * 96 + c];
        ushort hi = f2bf_hi(val);
        float lo = val - bf2f(hi);
        wf[(c >> 5) * 3072 + m * 32 + (c & 31)] = hi;
        wf[9216 + (c >> 5) * 3072 + m * 32 + (c & 31)] = f2bf_hi(lo);
    }
}

// ---- 1x1 conv via MFMA (split-bf16), weights from frag table ----
__global__ __launch_bounds__(384) void conv1x1_mfma(
    const float* __restrict__ in, const ushort* __restrict__ wf,
    float* __restrict__ out)
{
    __shared__ ushort Ah[64][104];
    __shared__ ushort Al[64][104];
    int b = blockIdx.y;
    int px0 = blockIdx.x * 64;
    int t = threadIdx.x, lane = t & 63, wv = t >> 6;
    const float* inb = in + (size_t)b * 96 * HWc + px0;

    int m = 16 * wv + (lane & 15);
    int kbase = (lane >> 4) * 8;
    bf16x8 Bh[3], Bl[3];
#pragma unroll
    for (int ks = 0; ks < 3; ++ks) {
        Bh[ks] = *(const bf16x8*)&wf[ks * 3072 + m * 32 + kbase];
        Bl[ks] = *(const bf16x8*)&wf[9216 + ks * 3072 + m * 32 + kbase];
    }

#pragma unroll
    for (int rr = 0; rr < 4; ++rr) {
        int fi = rr * 384 + t;
        int c = fi >> 4;
        int p4 = (fi & 15) * 4;
        float4 v = *(const float4*)(inb + (size_t)c * HWc + p4);
        float vv[4] = {v.x, v.y, v.z, v.w};
#pragma unroll
        for (int e = 0; e < 4; ++e) {
            ushort hi = f2bf_hi(vv[e]);
            float lo = vv[e] - bf2f(hi);
            Ah[p4 + e][c] = hi;
            Al[p4 + e][c] = (ushort)f2bf_hi(lo);
        }
    }
    __syncthreads();

    f32x4 acc0 = {0.f, 0.f, 0.f, 0.f};
    f32x4 acc1 = {0.f, 0.f, 0.f, 0.f};
    f32x4 acc2 = {0.f, 0.f, 0.f, 0.f};
    f32x4 acc3 = {0.f, 0.f, 0.f, 0.f};
    int prow = lane & 15;

#pragma unroll
    for (int ks = 0; ks < 3; ++ks) {
        int ccol = ks * 32 + kbase;
#define DO_PT(PT, ACC)                                                         \
        {                                                                      \
            bf16x8 ah = *(const bf16x8*)&Ah[(PT) * 16 + prow][ccol];           \
            bf16x8 al = *(const bf16x8*)&Al[(PT) * 16 + prow][ccol];           \
            ACC = __builtin_amdgcn_mfma_f32_16x16x32_bf16(ah, Bh[ks], ACC, 0, 0, 0); \
            ACC = __builtin_amdgcn_mfma_f32_16x16x32_bf16(ah, Bl[ks], ACC, 0, 0, 0); \
            ACC = __builtin_amdgcn_mfma_f32_16x16x32_bf16(al, Bh[ks], ACC, 0, 0, 0); \
        }
        DO_PT(0, acc0) DO_PT(1, acc1) DO_PT(2, acc2) DO_PT(3, acc3)
#undef DO_PT
    }

    int pq = (lane >> 4) * 4;
    float* outm = out + (size_t)b * 96 * HWc + (size_t)m * HWc + px0 + pq;
    *(f32x4*)(outm + 0)  = acc0;
    *(f32x4*)(outm + 16) = acc1;
    *(f32x4*)(outm + 32) = acc2;
    *(f32x4*)(outm + 48) = acc3;
}

// ---- depthwise 3x3 (pad=1) + per-channel sumsq ----
__global__ __launch_bounds__(256) void depthwise3x3_kernel(
    const float* __restrict__ in, const float* __restrict__ wq,
    float* __restrict__ out, float* __restrict__ ssq_q)
{
    __shared__ float red[4];
    int c = blockIdx.y, b = blockIdx.z;
    int t = threadIdx.x;
    int lane = t & 63;
    int xq = lane * 4;
    int yb = blockIdx.x * 32 + (t >> 6) * 8;

    const float* inc = in + ((size_t)(b * 96 + c)) * HWc;
    float* outc = out + ((size_t)(b * 96 + c)) * HWc;

    float w[9];
    const float* wp = wq + (size_t)c * 9;
#pragma unroll
    for (int i = 0; i < 9; ++i) w[i] = wp[i];

    float rows[3][6];

#define LOAD_ROW(yy, slot)                                                     \
    {                                                                          \
        float4 v_;                                                             \
        if ((unsigned)(yy) < (unsigned)Hd)                                     \
            v_ = *(const float4*)(inc + (size_t)(yy) * Wd + xq);               \
        else                                                                   \
            v_ = make_float4(0.f, 0.f, 0.f, 0.f);                              \
        float lw_ = __shfl_up(v_.w, 1, 64);                                    \
        float rx_ = __shfl_down(v_.x, 1, 64);                                  \
        rows[slot][0] = (lane > 0) ? lw_ : 0.f;                                \
        rows[slot][1] = v_.x; rows[slot][2] = v_.y;                            \
        rows[slot][3] = v_.z; rows[slot][4] = v_.w;                            \
        rows[slot][5] = (lane < 63) ? rx_ : 0.f;                               \
    }

    LOAD_ROW(yb - 1, 0);
    LOAD_ROW(yb, 1);

    float ssq = 0.f;
#pragma unroll
    for (int r = 0; r < 8; ++r) {
        LOAD_ROW(yb + r + 1, (r + 2) % 3);
        const float* ra = rows[r % 3];
        const float* rb = rows[(r + 1) % 3];
        const float* rc = rows[(r + 2) % 3];
        float a[4] = {0.f, 0.f, 0.f, 0.f};
#pragma unroll
        for (int dx = 0; dx < 3; ++dx)
#pragma unroll
            for (int px = 0; px < 4; ++px) {
                a[px] = fmaf(w[dx],     ra[px + dx], a[px]);
                a[px] = fmaf(w[3 + dx], rb[px + dx], a[px]);
                a[px] = fmaf(w[6 + dx], rc[px + dx], a[px]);
            }
        *(float4*)(outc + (size_t)(yb + r) * Wd + xq) = *(float4*)a;
#pragma unroll
        for (int px = 0; px < 4; ++px) ssq = fmaf(a[px], a[px], ssq);
    }
#undef LOAD_ROW

#pragma unroll
    for (int off = 32; off; off >>= 1) ssq += __shfl_down(ssq, off, 64);
    int wvi = t >> 6;
    if (lane == 0) red[wvi] = ssq;
    __syncthreads();
    if (t == 0) atomicAdd(&ssq_q[b * 96 + c], red[0] + red[1] + red[2] + red[3]);
}

// ---- fused: grouped3x3(kmid) -> ks (LDS) + logits Gram + ssq_k ----
// Quarter-width 64-px tiles: LDS ~15KB -> occupancy no longer LDS-bound
// (8-block/CU wave cap), grid 4096 blocks (16/CU). 192 conv threads
// (12 pairs x 16 lanes x 4px) + 64 q-staging threads; Gram 16px/wave.
__global__ __launch_bounds__(256) void k_logits_kernel(
    const float* __restrict__ mid, const float* __restrict__ w2,
    const float* __restrict__ qg, float* __restrict__ attn_raw,
    float* __restrict__ ssq_k)
{
    __shared__ float smem[2 * 24 * 68];   // qs | ks
    __shared__ float wls[24 * 18];
    float* qs = smem;                     // [24][68]
    float* ks = smem + 24 * 68;           // [24][68]

    int bx = blockIdx.x;                  // 128: yt*4 + xh
    int yt = bx >> 2, xh = bx & 3;
    int h = blockIdx.y, b = blockIdx.z;
    int xbase = xh * 64;
    int t = threadIdx.x, lane = t & 63, wvi = t >> 6;
    int i0 = (lane >> 3) * 3, j0 = (lane & 7) * 3;

    const float* midb = mid + ((size_t)b * 96 + h * 24) * HWc;
    const float* qb   = qg  + ((size_t)b * 96 + h * 24) * HWc;

    if (t < 108)
        *(float4*)&wls[4 * t] = *(const float4*)(w2 + (size_t)h * 432 + 4 * t);

    int p = t >> 4;          // pair (valid 0..11 for t<192)
    int g16 = t & 15;
    int x0 = xbase + g16 * 4;

    float acc[3][3];
#pragma unroll
    for (int a = 0; a < 3; ++a)
#pragma unroll
        for (int c2 = 0; c2 < 3; ++c2) acc[a][c2] = 0.f;
    float ssq0 = 0.f, ssq1 = 0.f;

    __syncthreads();                      // wls ready

    for (int r = 0; r < 8; ++r) {
        int y = yt * 8 + r;
        __syncthreads();                  // previous Gram's readers done

        if (t < 192) {
            // conv pair p: channels 2p,2p+1 at 4 px
            const float* m0 = midb + (size_t)(2 * p) * HWc;
            const float* m1 = m0 + HWc;
            const float* wp_ = &wls[p * 36];
            float k0[4] = {0.f, 0.f, 0.f, 0.f};
            float k1[4] = {0.f, 0.f, 0.f, 0.f};
#pragma unroll
            for (int dy = 0; dy < 3; ++dy) {
                int yy = y + dy - 1;
                if ((unsigned)yy < (unsigned)Hd) {      // block-uniform
#pragma unroll
                    for (int ic = 0; ic < 2; ++ic) {
                        const float* base = (ic ? m1 : m0) + (size_t)yy * Wd;
                        float4 cv = *(const float4*)(base + x0);
                        float rr[6];
                        rr[0] = (x0 > 0) ? base[x0 - 1] : 0.f;
                        rr[1] = cv.x; rr[2] = cv.y; rr[3] = cv.z; rr[4] = cv.w;
                        rr[5] = (x0 < 252) ? base[x0 + 4] : 0.f;
                        int wb_ = ic * 9 + dy * 3;
#pragma unroll
                        for (int px = 0; px < 4; ++px) {
#pragma unroll
                            for (int dx = 0; dx < 3; ++dx) {
                                k0[px] = fmaf(wp_[wb_ + dx],      rr[px + dx], k0[px]);
                                k1[px] = fmaf(wp_[18 + wb_ + dx], rr[px + dx], k1[px]);
                            }
                        }
                    }
                }
            }
#pragma unroll
            for (int px = 0; px < 4; ++px) {
                ssq0 = fmaf(k0[px], k0[px], ssq0);
                ssq1 = fmaf(k1[px], k1[px], ssq1);
            }
            *(float4*)&ks[(2 * p) * 68 + g16 * 4]     = *(float4*)k0;
            *(float4*)&ks[(2 * p + 1) * 68 + g16 * 4] = *(float4*)k1;
        } else {
            // stage q: 24ch x 64px = 384 f4 over 64 threads (6 each)
            int u = t - 192;
            const float* qrow = qb + (size_t)y * Wd + xbase;
#pragma unroll
            for (int j = 0; j < 6; ++j) {
                int fi = u + 64 * j;
                int ch = fi >> 4;
                int xo = (fi & 15) * 4;
                *(float4*)&qs[ch * 68 + xo] =
                    *(const float4*)(qrow + (size_t)ch * HWc + xo);
            }
        }
        __syncthreads();                  // qs/ks ready

        // Gram: wave strip of 16 px
        int n0 = wvi * 16;
#pragma unroll
        for (int nn = 0; nn < 4; ++nn) {
            int n = n0 + nn * 4;
            float4 q0v = *(const float4*)&qs[i0 * 68 + n];
            float4 q1v = *(const float4*)&qs[(i0 + 1) * 68 + n];
            float4 q2v = *(const float4*)&qs[(i0 + 2) * 68 + n];
            float4 k0v = *(const float4*)&ks[j0 * 68 + n];
            float4 k1v = *(const float4*)&ks[(j0 + 1) * 68 + n];
            float4 k2v = *(const float4*)&ks[(j0 + 2) * 68 + n];
            acc[0][0] += q0v.x*k0v.x + q0v.y*k0v.y + q0v.z*k0v.z + q0v.w*k0v.w;
            acc[0][1] += q0v.x*k1v.x + q0v.y*k1v.y + q0v.z*k1v.z + q0v.w*k1v.w;
            acc[0][2] += q0v.x*k2v.x + q0v.y*k2v.y + q0v.z*k2v.z + q0v.w*k2v.w;
            acc[1][0] += q1v.x*k0v.x + q1v.y*k0v.y + q1v.z*k0v.z + q1v.w*k0v.w;
            acc[1][1] += q1v.x*k1v.x + q1v.y*k1v.y + q1v.z*k1v.z + q1v.w*k1v.w;
            acc[1][2] += q1v.x*k2v.x + q1v.y*k2v.y + q1v.z*k2v.z + q1v.w*k2v.w;
            acc[2][0] += q2v.x*k0v.x + q2v.y*k0v.y + q2v.z*k0v.z + q2v.w*k0v.w;
            acc[2][1] += q2v.x*k1v.x + q2v.y*k1v.y + q2v.z*k1v.z + q2v.w*k1v.w;
            acc[2][2] += q2v.x*k2v.x + q2v.y*k2v.y + q2v.z*k2v.z + q2v.w*k2v.w;
        }
    }

    // ssq_k: reduce within each 16-thread pair group
    if (t < 192) {
        float s0 = ssq0, s1 = ssq1;
#pragma unroll
        for (int off = 8; off; off >>= 1) {
            s0 += __shfl_down(s0, off, 16);
            s1 += __shfl_down(s1, off, 16);
        }
        if (g16 == 0) {
            atomicAdd(&ssq_k[b * 96 + h * 24 + 2 * p],     s0);
            atomicAdd(&ssq_k[b * 96 + h * 24 + 2 * p + 1], s1);
        }
    }

    __syncthreads();
    float* redbuf = smem;   // 4*576 = 2304 <= 3264
#pragma unroll
    for (int a = 0; a < 3; ++a)
#pragma unroll
        for (int c2 = 0; c2 < 3; ++c2)
            redbuf[wvi * 576 + (i0 + a) * 24 + (j0 + c2)] = acc[a][c2];
    __syncthreads();
    for (int p_ = t; p_ < 576; p_ += 256) {
        float s4 = redbuf[p_] + redbuf[576 + p_] + redbuf[1152 + p_] + redbuf[1728 + p_];
        atomicAdd(&attn_raw[((size_t)b * 4 + h) * 576 + p_], s4);
    }
}

// ---- softmax (+temperature, +norms), fold proj -> W2 bf16 hi/lo frag table ----
__global__ __launch_bounds__(256) void softmax_fold_kernel(
    const float* __restrict__ attn_raw,
    const float* __restrict__ ssq_q, const float* __restrict__ ssq_k,
    const float* __restrict__ temp, const float* __restrict__ projw,
    ushort* __restrict__ W2F)
{
    __shared__ float s[24][25];
    __shared__ float rq[24], rk[24];
    int h = blockIdx.x, b = blockIdx.y;
    int t = threadIdx.x;

    if (t < 24) {
        rq[t] = 1.f / fmaxf(sqrtf(ssq_q[b * 96 + h * 24 + t]), 1e-12f);
        rk[t] = 1.f / fmaxf(sqrtf(ssq_k[b * 96 + h * 24 + t]), 1e-12f);
    }
    __syncthreads();
    float T = temp[h];
    for (int p = t; p < 576; p += 256) {
        int i = p / 24, j = p % 24;
        s[i][j] = attn_raw[(size_t)(b * 4 + h) * 576 + p] * T * rq[i] * rk[j];
    }
    __syncthreads();
    if (t < 24) {
        float m = -1e30f;
#pragma unroll
        for (int j = 0; j < 24; ++j) m = fmaxf(m, s[t][j]);
        float sum = 0.f;
#pragma unroll
        for (int j = 0; j < 24; ++j) { float e = __expf(s[t][j] - m); s[t][j] = e; sum += e; }
        float inv = 1.f / sum;
#pragma unroll
        for (int j = 0; j < 24; ++j) s[t][j] *= inv;
    }
    __syncthreads();
    ushort* wfb = W2F + (size_t)b * 18432;
    for (int m_ = t; m_ < 96 * 24; m_ += 256) {
        int d = m_ % 24, co = m_ / 24;
        float acc = 0.f;
#pragma unroll
        for (int c = 0; c < 24; ++c)
            acc += projw[co * 96 + h * 24 + c] * s[c][d];
        int dv = h * 24 + d;
        int ks = dv >> 5, kk = dv & 31;
        ushort hi = f2bf_hi(acc);
        float lo = acc - bf2f(hi);
        wfb[ks * 3072 + co * 32 + kk] = hi;
        wfb[9216 + ks * 3072 + co * 32 + kk] = f2bf_hi(lo);
    }
}

// ---- v_proj via MFMA: fp32 conv -> swizzled hi/lo bf16 LDS -> 36 MFMAs ----
__global__ __launch_bounds__(384) void v_proj_mfma(
    const float* __restrict__ mid, const float* __restrict__ w2,
    const ushort* __restrict__ W2F, float* __restrict__ out)
{
    __shared__ ushort Ah[64][128];
    __shared__ ushort Al[64][128];
    __shared__ float wls[1728];

    int bx = blockIdx.x, b = blockIdx.y;
    int y = bx >> 2;
    int x0 = (bx & 3) * 64;
    int t = threadIdx.x, lane = t & 63, wv = t >> 6;
    const float* midb = mid + (size_t)b * 96 * HWc;

    for (int i = t; i < 432; i += 384)
        *(float4*)&wls[4 * i] = *(const float4*)(w2 + 96 * 18 + 4 * i);

    int m = 16 * wv + (lane & 15);
    int kbase = (lane >> 4) * 8;
    const ushort* wfb = W2F + (size_t)b * 18432;
    bf16x8 Bh[3], Bl[3];
#pragma unroll
    for (int ks = 0; ks < 3; ++ks) {
        Bh[ks] = *(const bf16x8*)&wfb[ks * 3072 + m * 32 + kbase];
        Bl[ks] = *(const bf16x8*)&wfb[9216 + ks * 3072 + m * 32 + kbase];
    }
    __syncthreads();   // wls ready

    {
        int p = t >> 3;
        int xl = (t & 7) * 8;
        int xg = x0 + xl;
        const float* m0 = midb + (size_t)(2 * p) * HWc;
        const float* m1 = m0 + HWc;
        const float* wp_ = &wls[p * 36];
        float k0[8] = {0.f,0.f,0.f,0.f,0.f,0.f,0.f,0.f};
        float k1[8] = {0.f,0.f,0.f,0.f,0.f,0.f,0.f,0.f};
#pragma unroll
        for (int dy = 0; dy < 3; ++dy) {
            int yy = y + dy - 1;
            if ((unsigned)yy < (unsigned)Hd) {
#pragma unroll
                for (int ic = 0; ic < 2; ++ic) {
                    const float* base = (ic ? m1 : m0) + (size_t)yy * Wd;
                    float4 a = *(const float4*)(base + xg);
                    float4 b2 = *(const float4*)(base + xg + 4);
                    float rr[10];
                    rr[0] = (xg > 0) ? base[xg - 1] : 0.f;
                    rr[1] = a.x; rr[2] = a.y; rr[3] = a.z; rr[4] = a.w;
                    rr[5] = b2.x; rr[6] = b2.y; rr[7] = b2.z; rr[8] = b2.w;
                    rr[9] = (xg + 8 < 256) ? base[xg + 8] : 0.f;
                    int wb_ = ic * 9 + dy * 3;
#pragma unroll
                    for (int px = 0; px < 8; ++px) {
#pragma unroll
                        for (int dx = 0; dx < 3; ++dx) {
                            k0[px] = fmaf(wp_[wb_ + dx],      rr[px + dx], k0[px]);
                            k1[px] = fmaf(wp_[18 + wb_ + dx], rr[px + dx], k1[px]);
                        }
                    }
                }
            }
        }
#pragma unroll
        for (int px = 0; px < 8; ++px) {
            int row = xl + px;
            uint sw = (uint)(row & 7) << 4;
            uint off = ((uint)(4 * p)) ^ sw;
            ushort h0 = f2bf_hi(k0[px]);
            ushort h1 = f2bf_hi(k1[px]);
            float l0 = k0[px] - bf2f(h0);
            float l1 = k1[px] - bf2f(h1);
            *(uint*)((char*)&Ah[row][0] + off) = (uint)h0 | ((uint)h1 << 16);
            *(uint*)((char*)&Al[row][0] + off) =
                (uint)f2bf_hi(l0) | ((uint)f2bf_hi(l1) << 16);
        }
    }
    __syncthreads();

    f32x4 acc0 = {0.f, 0.f, 0.f, 0.f};
    f32x4 acc1 = {0.f, 0.f, 0.f, 0.f};
    f32x4 acc2 = {0.f, 0.f, 0.f, 0.f};
    f32x4 acc3 = {0.f, 0.f, 0.f, 0.f};
    int prow = lane & 15;

#pragma unroll
    for (int ks = 0; ks < 3; ++ks) {
        uint cbyte = (uint)(ks * 32 + kbase) * 2;
#define DO_PT(PT, ACC)                                                         \
        {                                                                      \
            int row = (PT) * 16 + prow;                                        \
            uint sw = (uint)(row & 7) << 4;                                    \
            bf16x8 ah = *(const bf16x8*)((char*)&Ah[row][0] + (cbyte ^ sw));   \
            bf16x8 al = *(const bf16x8*)((char*)&Al[row][0] + (cbyte ^ sw));   \
            ACC = __builtin_amdgcn_mfma_f32_16x16x32_bf16(ah, Bh[ks], ACC, 0, 0, 0); \
            ACC = __builtin_amdgcn_mfma_f32_16x16x32_bf16(ah, Bl[ks], ACC, 0, 0, 0); \
            ACC = __builtin_amdgcn_mfma_f32_16x16x32_bf16(al, Bh[ks], ACC, 0, 0, 0); \
        }
        DO_PT(0, acc0) DO_PT(1, acc1) DO_PT(2, acc2) DO_PT(3, acc3)
#undef DO_PT
    }

    int pq = (lane >> 4) * 4;
    float* outm = out + (size_t)b * 96 * HWc + (size_t)m * HWc
                + (size_t)y * Wd + x0 + pq;
    *(f32x4*)(outm + 0)  = acc0;
    *(f32x4*)(outm + 16) = acc1;
    *(f32x4*)(outm + 32) = acc2;
    *(f32x4*)(outm + 48) = acc3;
}

extern "C" void kernel_launch(void* const* d_in, const int* in_sizes, int n_in,
                              void* d_out, int out_size, void* d_ws, size_t ws_size,
                              hipStream_t stream) {
    const float* x     = (const float*)d_in[0];
    const float* z     = (const float*)d_in[1];
    const float* kvw1  = (const float*)d_in[2];
    const float* kvw2  = (const float*)d_in[3];
    const float* qw1   = (const float*)d_in[4];
    const float* qw2   = (const float*)d_in[5];
    const float* projw = (const float*)d_in[6];
    const float* temp  = (const float*)d_in[7];
    float* out = (float*)d_out;
    float* ws  = (float*)d_ws;
    (void)in_sizes; (void)n_in; (void)out_size; (void)ws_size;

    float* ssq_q = ws + SSQ_Q_OFF;
    float* ssq_k = ws + SSQ_K_OFF;
    float* attn  = ws + ATTN_OFF;
    ushort* qwf  = (ushort*)(ws + QWF_OFF);
    ushort* kwf  = (ushort*)(ws + KWF_OFF);
    ushort* vwf  = (ushort*)(ws + VWF_OFF);
    ushort* w2f  = (ushort*)(ws + W2F_OFF);
    float* ws1   = ws + WS1_OFF;

    hipMemsetAsync(ws, 0, (768 + 768 + 18432) * sizeof(float), stream);

    prep_wfrag<<<dim3(36), 256, 0, stream>>>(qw1, 0, qwf);
    prep_wfrag<<<dim3(36), 256, 0, stream>>>(kvw1, 0, kwf);
    prep_wfrag<<<dim3(36), 256, 0, stream>>>(kvw1, 96, vwf);

    // ---- q path ----
    conv1x1_mfma<<<dim3(1024, 8), 384, 0, stream>>>(x, qwf, ws1);                    // q1
    depthwise3x3_kernel<<<dim3(8, 96, 8), 256, 0, stream>>>(ws1, qw2, out, ssq_q);   // q

    // ---- k path ----
    conv1x1_mfma<<<dim3(1024, 8), 384, 0, stream>>>(z, kwf, ws1);                    // kmid
    k_logits_kernel<<<dim3(128, 4, 8), 256, 0, stream>>>(ws1, kvw2, out, attn, ssq_k);

    softmax_fold_kernel<<<dim3(4, 8), 256, 0, stream>>>(attn, ssq_q, ssq_k, temp, projw, w2f);

    // ---- v path ----
    conv1x1_mfma<<<dim3(1024, 8), 384, 0, stream>>>(z, vwf, ws1);                    // vmid
    v_proj_mfma<<<dim3(1024, 8), 384, 0, stream>>>(ws1, kvw2, w2f, out);
}

// Round 21
// 738.175 us; speedup vs baseline: 1.0302x; 1.0302x over previous
//
#include <hip/hip_runtime.h>
#include <math.h>

#define HWc 65536
#define Wd 256
#define Hd 256

typedef __attribute__((ext_vector_type(8))) short bf16x8;
typedef __attribute__((ext_vector_type(4))) float f32x4;

__device__ inline ushort f2bf_hi(float a) {
    uint u = __float_as_uint(a);
    uint r = u + 0x7FFFu + ((u >> 16) & 1u);
    return (ushort)(r >> 16);
}
__device__ inline float bf2f(ushort h) { return __uint_as_float((uint)h << 16); }

// ---- ws layout (float offsets), small buffers FIRST ----
static const size_t SSQ_Q_OFF = 0;        // 768
static const size_t SSQ_K_OFF = 768;      // 768
static const size_t ATTN_OFF  = 1536;     // 18432 -> 19968
static const size_t QWF_OFF   = 19968;    // 9216 floats = hi/lo ushort frag table
static const size_t KWF_OFF   = 29184;    // 9216
static const size_t VWF_OFF   = 38400;    // 9216
static const size_t W2F_OFF   = 47616;    // 8 * 9216 = 73728 -> 121344
static const size_t WS1_OFF   = 121344;   // 8*96*HWc floats (201 MB)

// ---- precompute bf16 hi/lo weight frag table: wf[ks][m][kk], kk = c&31 ----
__global__ void prep_wfrag(const float* __restrict__ w, int woff,
                           ushort* __restrict__ wf) {
    int idx = blockIdx.x * 256 + threadIdx.x;
    if (idx < 9216) {
        int m = idx / 96, c = idx % 96;
        float val = w[(size_t)(woff + m) * 96 + c];
        ushort hi = f2bf_hi(val);
        float lo = val - bf2f(hi);
        wf[(c >> 5) * 3072 + m * 32 + (c & 31)] = hi;
        wf[9216 + (c >> 5) * 3072 + m * 32 + (c & 31)] = f2bf_hi(lo);
    }
}

// ---- 1x1 conv via MFMA (split-bf16), weights from frag table ----
__global__ __launch_bounds__(384) void conv1x1_mfma(
    const float* __restrict__ in, const ushort* __restrict__ wf,
    float* __restrict__ out)
{
    __shared__ ushort Ah[64][104];
    __shared__ ushort Al[64][104];
    int b = blockIdx.y;
    int px0 = blockIdx.x * 64;
    int t = threadIdx.x, lane = t & 63, wv = t >> 6;
    const float* inb = in + (size_t)b * 96 * HWc + px0;

    int m = 16 * wv + (lane & 15);
    int kbase = (lane >> 4) * 8;
    bf16x8 Bh[3], Bl[3];
#pragma unroll
    for (int ks = 0; ks < 3; ++ks) {
        Bh[ks] = *(const bf16x8*)&wf[ks * 3072 + m * 32 + kbase];
        Bl[ks] = *(const bf16x8*)&wf[9216 + ks * 3072 + m * 32 + kbase];
    }

#pragma unroll
    for (int rr = 0; rr < 4; ++rr) {
        int fi = rr * 384 + t;
        int c = fi >> 4;
        int p4 = (fi & 15) * 4;
        float4 v = *(const float4*)(inb + (size_t)c * HWc + p4);
        float vv[4] = {v.x, v.y, v.z, v.w};
#pragma unroll
        for (int e = 0; e < 4; ++e) {
            ushort hi = f2bf_hi(vv[e]);
            float lo = vv[e] - bf2f(hi);
            Ah[p4 + e][c] = hi;
            Al[p4 + e][c] = (ushort)f2bf_hi(lo);
        }
    }
    __syncthreads();

    f32x4 acc0 = {0.f, 0.f, 0.f, 0.f};
    f32x4 acc1 = {0.f, 0.f, 0.f, 0.f};
    f32x4 acc2 = {0.f, 0.f, 0.f, 0.f};
    f32x4 acc3 = {0.f, 0.f, 0.f, 0.f};
    int prow = lane & 15;

#pragma unroll
    for (int ks = 0; ks < 3; ++ks) {
        int ccol = ks * 32 + kbase;
#define DO_PT(PT, ACC)                                                         \
        {                                                                      \
            bf16x8 ah = *(const bf16x8*)&Ah[(PT) * 16 + prow][ccol];           \
            bf16x8 al = *(const bf16x8*)&Al[(PT) * 16 + prow][ccol];           \
            ACC = __builtin_amdgcn_mfma_f32_16x16x32_bf16(ah, Bh[ks], ACC, 0, 0, 0); \
            ACC = __builtin_amdgcn_mfma_f32_16x16x32_bf16(ah, Bl[ks], ACC, 0, 0, 0); \
            ACC = __builtin_amdgcn_mfma_f32_16x16x32_bf16(al, Bh[ks], ACC, 0, 0, 0); \
        }
        DO_PT(0, acc0) DO_PT(1, acc1) DO_PT(2, acc2) DO_PT(3, acc3)
#undef DO_PT
    }

    int pq = (lane >> 4) * 4;
    float* outm = out + (size_t)b * 96 * HWc + (size_t)m * HWc + px0 + pq;
    *(f32x4*)(outm + 0)  = acc0;
    *(f32x4*)(outm + 16) = acc1;
    *(f32x4*)(outm + 32) = acc2;
    *(f32x4*)(outm + 48) = acc3;
}

// ---- depthwise 3x3 (pad=1) + per-channel sumsq ----
__global__ __launch_bounds__(256) void depthwise3x3_kernel(
    const float* __restrict__ in, const float* __restrict__ wq,
    float* __restrict__ out, float* __restrict__ ssq_q)
{
    __shared__ float red[4];
    int c = blockIdx.y, b = blockIdx.z;
    int t = threadIdx.x;
    int lane = t & 63;
    int xq = lane * 4;
    int yb = blockIdx.x * 32 + (t >> 6) * 8;

    const float* inc = in + ((size_t)(b * 96 + c)) * HWc;
    float* outc = out + ((size_t)(b * 96 + c)) * HWc;

    float w[9];
    const float* wp = wq + (size_t)c * 9;
#pragma unroll
    for (int i = 0; i < 9; ++i) w[i] = wp[i];

    float rows[3][6];

#define LOAD_ROW(yy, slot)                                                     \
    {                                                                          \
        float4 v_;                                                             \
        if ((unsigned)(yy) < (unsigned)Hd)                                     \
            v_ = *(const float4*)(inc + (size_t)(yy) * Wd + xq);               \
        else                                                                   \
            v_ = make_float4(0.f, 0.f, 0.f, 0.f);                              \
        float lw_ = __shfl_up(v_.w, 1, 64);                                    \
        float rx_ = __shfl_down(v_.x, 1, 64);                                  \
        rows[slot][0] = (lane > 0) ? lw_ : 0.f;                                \
        rows[slot][1] = v_.x; rows[slot][2] = v_.y;                            \
        rows[slot][3] = v_.z; rows[slot][4] = v_.w;                            \
        rows[slot][5] = (lane < 63) ? rx_ : 0.f;                               \
    }

    LOAD_ROW(yb - 1, 0);
    LOAD_ROW(yb, 1);

    float ssq = 0.f;
#pragma unroll
    for (int r = 0; r < 8; ++r) {
        LOAD_ROW(yb + r + 1, (r + 2) % 3);
        const float* ra = rows[r % 3];
        const float* rb = rows[(r + 1) % 3];
        const float* rc = rows[(r + 2) % 3];
        float a[4] = {0.f, 0.f, 0.f, 0.f};
#pragma unroll
        for (int dx = 0; dx < 3; ++dx)
#pragma unroll
            for (int px = 0; px < 4; ++px) {
                a[px] = fmaf(w[dx],     ra[px + dx], a[px]);
                a[px] = fmaf(w[3 + dx], rb[px + dx], a[px]);
                a[px] = fmaf(w[6 + dx], rc[px + dx], a[px]);
            }
        *(float4*)(outc + (size_t)(yb + r) * Wd + xq) = *(float4*)a;
#pragma unroll
        for (int px = 0; px < 4; ++px) ssq = fmaf(a[px], a[px], ssq);
    }
#undef LOAD_ROW

#pragma unroll
    for (int off = 32; off; off >>= 1) ssq += __shfl_down(ssq, off, 64);
    int wvi = t >> 6;
    if (lane == 0) red[wvi] = ssq;
    __syncthreads();
    if (t == 0) atomicAdd(&ssq_q[b * 96 + c], red[0] + red[1] + red[2] + red[3]);
}

// conv macro for k_logits: pair P -> ks[2P..2P+1][l32*4], sumsq into SS0/SS1
#define CONV_PAIR(P, SS0, SS1)                                                 \
    {                                                                          \
        const float* m0 = midb + (size_t)(2 * (P)) * HWc;                      \
        const float* m1 = m0 + HWc;                                            \
        const float* wp_ = &wls[(P) * 36];                                     \
        float k0[4] = {0.f, 0.f, 0.f, 0.f};                                    \
        float k1[4] = {0.f, 0.f, 0.f, 0.f};                                    \
        _Pragma("unroll")                                                      \
        for (int dy = 0; dy < 3; ++dy) {                                       \
            int yy = y + dy - 1;                                               \
            if ((unsigned)yy < (unsigned)Hd) {                                 \
                _Pragma("unroll")                                              \
                for (int ic = 0; ic < 2; ++ic) {                               \
                    const float* base = (ic ? m1 : m0) + (size_t)yy * Wd;      \
                    float4 cv = *(const float4*)(base + x0);                   \
                    float rr[6];                                               \
                    rr[0] = (x0 > 0) ? base[x0 - 1] : 0.f;                     \
                    rr[1] = cv.x; rr[2] = cv.y; rr[3] = cv.z; rr[4] = cv.w;    \
                    rr[5] = (x0 < 252) ? base[x0 + 4] : 0.f;                   \
                    int wb_ = ic * 9 + dy * 3;                                 \
                    _Pragma("unroll")                                          \
                    for (int px = 0; px < 4; ++px) {                           \
                        _Pragma("unroll")                                      \
                        for (int dx = 0; dx < 3; ++dx) {                       \
                            k0[px] = fmaf(wp_[wb_ + dx],      rr[px + dx], k0[px]); \
                            k1[px] = fmaf(wp_[18 + wb_ + dx], rr[px + dx], k1[px]); \
                        }                                                      \
                    }                                                          \
                }                                                              \
            }                                                                  \
        }                                                                      \
        _Pragma("unroll")                                                      \
        for (int px = 0; px < 4; ++px) {                                       \
            SS0 = fmaf(k0[px], k0[px], SS0);                                   \
            SS1 = fmaf(k1[px], k1[px], SS1);                                   \
        }                                                                      \
        *(float4*)&ks[2 * (P)][l32 * 4]     = *(float4*)k0;                    \
        *(float4*)&ks[2 * (P) + 1][l32 * 4] = *(float4*)k1;                    \
    }

// ---- fused: grouped3x3(kmid) -> ks (LDS) + logits Gram + ssq_k  [R19 form] ----
__global__ __launch_bounds__(256) void k_logits_kernel(
    const float* __restrict__ mid, const float* __restrict__ w2,
    const float* __restrict__ qg, float* __restrict__ attn_raw,
    float* __restrict__ ssq_k)
{
    __shared__ float qs[24][132];
    __shared__ float ks[24][132];
    __shared__ float wls[24 * 18];

    int bx = blockIdx.x;
    int yt = bx >> 1, xh = bx & 1;
    int h = blockIdx.y, b = blockIdx.z;
    int xbase = xh * 128;
    int t = threadIdx.x, lane = t & 63, wvi = t >> 6;
    int hi = lane >> 5, l32 = lane & 31;
    int i0 = (lane >> 3) * 3, j0 = (lane & 7) * 3;

    const float* midb = mid + ((size_t)b * 96 + h * 24) * HWc;
    const float* qb   = qg  + ((size_t)b * 96 + h * 24) * HWc;

    if (t < 108)
        *(float4*)&wls[4 * t] = *(const float4*)(w2 + (size_t)h * 432 + 4 * t);

    int pA = 2 * wvi + hi;
    int pB = 8 + 2 * wvi + hi;
    int x0 = xbase + l32 * 4;

    float acc[3][3];
#pragma unroll
    for (int a = 0; a < 3; ++a)
#pragma unroll
        for (int c2 = 0; c2 < 3; ++c2) acc[a][c2] = 0.f;
    float ssqA0 = 0.f, ssqA1 = 0.f, ssqB0 = 0.f, ssqB1 = 0.f;

    __syncthreads();

    for (int r = 0; r < 8; ++r) {
        int y = yt * 8 + r;
        __syncthreads();

        {
            const float* qrow = qb + (size_t)y * Wd + xbase;
            int fi = t;
            *(float4*)&qs[fi >> 5][(fi & 31) * 4] =
                *(const float4*)(qrow + (size_t)(fi >> 5) * HWc + (fi & 31) * 4);
            fi = t + 256;
            *(float4*)&qs[fi >> 5][(fi & 31) * 4] =
                *(const float4*)(qrow + (size_t)(fi >> 5) * HWc + (fi & 31) * 4);
        }
        CONV_PAIR(pA, ssqA0, ssqA1);
        if (t < 128) {
            CONV_PAIR(pB, ssqB0, ssqB1);
        } else {
            const float* qrow = qb + (size_t)y * Wd + xbase;
            int fi = 512 + (t - 128);
            *(float4*)&qs[fi >> 5][(fi & 31) * 4] =
                *(const float4*)(qrow + (size_t)(fi >> 5) * HWc + (fi & 31) * 4);
            fi = 640 + (t - 128);
            *(float4*)&qs[fi >> 5][(fi & 31) * 4] =
                *(const float4*)(qrow + (size_t)(fi >> 5) * HWc + (fi & 31) * 4);
        }
        __syncthreads();

        int n0 = wvi * 32;
#pragma unroll 4
        for (int nn = 0; nn < 8; ++nn) {
            int n = n0 + nn * 4;
            float4 q0v = *(const float4*)&qs[i0][n];
            float4 q1v = *(const float4*)&qs[i0 + 1][n];
            float4 q2v = *(const float4*)&qs[i0 + 2][n];
            float4 k0v = *(const float4*)&ks[j0][n];
            float4 k1v = *(const float4*)&ks[j0 + 1][n];
            float4 k2v = *(const float4*)&ks[j0 + 2][n];
            acc[0][0] += q0v.x*k0v.x + q0v.y*k0v.y + q0v.z*k0v.z + q0v.w*k0v.w;
            acc[0][1] += q0v.x*k1v.x + q0v.y*k1v.y + q0v.z*k1v.z + q0v.w*k1v.w;
            acc[0][2] += q0v.x*k2v.x + q0v.y*k2v.y + q0v.z*k2v.z + q0v.w*k2v.w;
            acc[1][0] += q1v.x*k0v.x + q1v.y*k0v.y + q1v.z*k0v.z + q1v.w*k0v.w;
            acc[1][1] += q1v.x*k1v.x + q1v.y*k1v.y + q1v.z*k1v.z + q1v.w*k1v.w;
            acc[1][2] += q1v.x*k2v.x + q1v.y*k2v.y + q1v.z*k2v.z + q1v.w*k2v.w;
            acc[2][0] += q2v.x*k0v.x + q2v.y*k0v.y + q2v.z*k0v.z + q2v.w*k0v.w;
            acc[2][1] += q2v.x*k1v.x + q2v.y*k1v.y + q2v.z*k1v.z + q2v.w*k1v.w;
            acc[2][2] += q2v.x*k2v.x + q2v.y*k2v.y + q2v.z*k2v.z + q2v.w*k2v.w;
        }
    }

    {
        float s0 = ssqA0, s1 = ssqA1;
#pragma unroll
        for (int off = 16; off; off >>= 1) {
            s0 += __shfl_down(s0, off, 32);
            s1 += __shfl_down(s1, off, 32);
        }
        if (l32 == 0) {
            atomicAdd(&ssq_k[b * 96 + h * 24 + 2 * pA],     s0);
            atomicAdd(&ssq_k[b * 96 + h * 24 + 2 * pA + 1], s1);
        }
    }
    if (t < 128) {
        float s0 = ssqB0, s1 = ssqB1;
#pragma unroll
        for (int off = 16; off; off >>= 1) {
            s0 += __shfl_down(s0, off, 32);
            s1 += __shfl_down(s1, off, 32);
        }
        if (l32 == 0) {
            atomicAdd(&ssq_k[b * 96 + h * 24 + 2 * pB],     s0);
            atomicAdd(&ssq_k[b * 96 + h * 24 + 2 * pB + 1], s1);
        }
    }

    __syncthreads();
    float* redbuf = &qs[0][0];
#pragma unroll
    for (int a = 0; a < 3; ++a)
#pragma unroll
        for (int c2 = 0; c2 < 3; ++c2)
            redbuf[wvi * 576 + (i0 + a) * 24 + (j0 + c2)] = acc[a][c2];
    __syncthreads();
    for (int p_ = t; p_ < 576; p_ += 256) {
        float s4 = redbuf[p_] + redbuf[576 + p_] + redbuf[1152 + p_] + redbuf[1728 + p_];
        atomicAdd(&attn_raw[((size_t)b * 4 + h) * 576 + p_], s4);
    }
}

// ---- softmax (+temperature, +norms), fold proj -> W2 bf16 hi/lo frag table ----
__global__ __launch_bounds__(256) void softmax_fold_kernel(
    const float* __restrict__ attn_raw,
    const float* __restrict__ ssq_q, const float* __restrict__ ssq_k,
    const float* __restrict__ temp, const float* __restrict__ projw,
    ushort* __restrict__ W2F)
{
    __shared__ float s[24][25];
    __shared__ float rq[24], rk[24];
    int h = blockIdx.x, b = blockIdx.y;
    int t = threadIdx.x;

    if (t < 24) {
        rq[t] = 1.f / fmaxf(sqrtf(ssq_q[b * 96 + h * 24 + t]), 1e-12f);
        rk[t] = 1.f / fmaxf(sqrtf(ssq_k[b * 96 + h * 24 + t]), 1e-12f);
    }
    __syncthreads();
    float T = temp[h];
    for (int p = t; p < 576; p += 256) {
        int i = p / 24, j = p % 24;
        s[i][j] = attn_raw[(size_t)(b * 4 + h) * 576 + p] * T * rq[i] * rk[j];
    }
    __syncthreads();
    if (t < 24) {
        float m = -1e30f;
#pragma unroll
        for (int j = 0; j < 24; ++j) m = fmaxf(m, s[t][j]);
        float sum = 0.f;
#pragma unroll
        for (int j = 0; j < 24; ++j) { float e = __expf(s[t][j] - m); s[t][j] = e; sum += e; }
        float inv = 1.f / sum;
#pragma unroll
        for (int j = 0; j < 24; ++j) s[t][j] *= inv;
    }
    __syncthreads();
    ushort* wfb = W2F + (size_t)b * 18432;
    for (int m_ = t; m_ < 96 * 24; m_ += 256) {
        int d = m_ % 24, co = m_ / 24;
        float acc = 0.f;
#pragma unroll
        for (int c = 0; c < 24; ++c)
            acc += projw[co * 96 + h * 24 + c] * s[c][d];
        int dv = h * 24 + d;
        int ks = dv >> 5, kk = dv & 31;
        ushort hi = f2bf_hi(acc);
        float lo = acc - bf2f(hi);
        wfb[ks * 3072 + co * 32 + kk] = hi;
        wfb[9216 + ks * 3072 + co * 32 + kk] = f2bf_hi(lo);
    }
}

// ---- v_proj via MFMA: fp32 conv -> swizzled hi/lo bf16 LDS -> 36 MFMAs ----
__global__ __launch_bounds__(384) void v_proj_mfma(
    const float* __restrict__ mid, const float* __restrict__ w2,
    const ushort* __restrict__ W2F, float* __restrict__ out)
{
    __shared__ ushort Ah[64][128];
    __shared__ ushort Al[64][128];
    __shared__ float wls[1728];

    int bx = blockIdx.x, b = blockIdx.y;
    int y = bx >> 2;
    int x0 = (bx & 3) * 64;
    int t = threadIdx.x, lane = t & 63, wv = t >> 6;
    const float* midb = mid + (size_t)b * 96 * HWc;

    for (int i = t; i < 432; i += 384)
        *(float4*)&wls[4 * i] = *(const float4*)(w2 + 96 * 18 + 4 * i);

    int m = 16 * wv + (lane & 15);
    int kbase = (lane >> 4) * 8;
    const ushort* wfb = W2F + (size_t)b * 18432;
    bf16x8 Bh[3], Bl[3];
#pragma unroll
    for (int ks = 0; ks < 3; ++ks) {
        Bh[ks] = *(const bf16x8*)&wfb[ks * 3072 + m * 32 + kbase];
        Bl[ks] = *(const bf16x8*)&wfb[9216 + ks * 3072 + m * 32 + kbase];
    }
    __syncthreads();   // wls ready

    {
        int p = t >> 3;
        int xl = (t & 7) * 8;
        int xg = x0 + xl;
        const float* m0 = midb + (size_t)(2 * p) * HWc;
        const float* m1 = m0 + HWc;
        const float* wp_ = &wls[p * 36];
        float k0[8] = {0.f,0.f,0.f,0.f,0.f,0.f,0.f,0.f};
        float k1[8] = {0.f,0.f,0.f,0.f,0.f,0.f,0.f,0.f};
#pragma unroll
        for (int dy = 0; dy < 3; ++dy) {
            int yy = y + dy - 1;
            if ((unsigned)yy < (unsigned)Hd) {
#pragma unroll
                for (int ic = 0; ic < 2; ++ic) {
                    const float* base = (ic ? m1 : m0) + (size_t)yy * Wd;
                    float4 a = *(const float4*)(base + xg);
                    float4 b2 = *(const float4*)(base + xg + 4);
                    float rr[10];
                    rr[0] = (xg > 0) ? base[xg - 1] : 0.f;
                    rr[1] = a.x; rr[2] = a.y; rr[3] = a.z; rr[4] = a.w;
                    rr[5] = b2.x; rr[6] = b2.y; rr[7] = b2.z; rr[8] = b2.w;
                    rr[9] = (xg + 8 < 256) ? base[xg + 8] : 0.f;
                    int wb_ = ic * 9 + dy * 3;
#pragma unroll
                    for (int px = 0; px < 8; ++px) {
#pragma unroll
                        for (int dx = 0; dx < 3; ++dx) {
                            k0[px] = fmaf(wp_[wb_ + dx],      rr[px + dx], k0[px]);
                            k1[px] = fmaf(wp_[18 + wb_ + dx], rr[px + dx], k1[px]);
                        }
                    }
                }
            }
        }
#pragma unroll
        for (int px = 0; px < 8; ++px) {
            int row = xl + px;
            uint sw = (uint)(row & 7) << 4;
            uint off = ((uint)(4 * p)) ^ sw;
            ushort h0 = f2bf_hi(k0[px]);
            ushort h1 = f2bf_hi(k1[px]);
            float l0 = k0[px] - bf2f(h0);
            float l1 = k1[px] - bf2f(h1);
            *(uint*)((char*)&Ah[row][0] + off) = (uint)h0 | ((uint)h1 << 16);
            *(uint*)((char*)&Al[row][0] + off) =
                (uint)f2bf_hi(l0) | ((uint)f2bf_hi(l1) << 16);
        }
    }
    __syncthreads();

    f32x4 acc0 = {0.f, 0.f, 0.f, 0.f};
    f32x4 acc1 = {0.f, 0.f, 0.f, 0.f};
    f32x4 acc2 = {0.f, 0.f, 0.f, 0.f};
    f32x4 acc3 = {0.f, 0.f, 0.f, 0.f};
    int prow = lane & 15;

#pragma unroll
    for (int ks = 0; ks < 3; ++ks) {
        uint cbyte = (uint)(ks * 32 + kbase) * 2;
#define DO_PT(PT, ACC)                                                         \
        {                                                                      \
            int row = (PT) * 16 + prow;                                        \
            uint sw = (uint)(row & 7) << 4;                                    \
            bf16x8 ah = *(const bf16x8*)((char*)&Ah[row][0] + (cbyte ^ sw));   \
            bf16x8 al = *(const bf16x8*)((char*)&Al[row][0] + (cbyte ^ sw));   \
            ACC = __builtin_amdgcn_mfma_f32_16x16x32_bf16(ah, Bh[ks], ACC, 0, 0, 0); \
            ACC = __builtin_amdgcn_mfma_f32_16x16x32_bf16(ah, Bl[ks], ACC, 0, 0, 0); \
            ACC = __builtin_amdgcn_mfma_f32_16x16x32_bf16(al, Bh[ks], ACC, 0, 0, 0); \
        }
        DO_PT(0, acc0) DO_PT(1, acc1) DO_PT(2, acc2) DO_PT(3, acc3)
#undef DO_PT
    }

    int pq = (lane >> 4) * 4;
    float* outm = out + (size_t)b * 96 * HWc + (size_t)m * HWc
                + (size_t)y * Wd + x0 + pq;
    *(f32x4*)(outm + 0)  = acc0;
    *(f32x4*)(outm + 16) = acc1;
    *(f32x4*)(outm + 32) = acc2;
    *(f32x4*)(outm + 48) = acc3;
}

extern "C" void kernel_launch(void* const* d_in, const int* in_sizes, int n_in,
                              void* d_out, int out_size, void* d_ws, size_t ws_size,
                              hipStream_t stream) {
    const float* x     = (const float*)d_in[0];
    const float* z     = (const float*)d_in[1];
    const float* kvw1  = (const float*)d_in[2];
    const float* kvw2  = (const float*)d_in[3];
    const float* qw1   = (const float*)d_in[4];
    const float* qw2   = (const float*)d_in[5];
    const float* projw = (const float*)d_in[6];
    const float* temp  = (const float*)d_in[7];
    float* out = (float*)d_out;
    float* ws  = (float*)d_ws;
    (void)in_sizes; (void)n_in; (void)out_size; (void)ws_size;

    float* ssq_q = ws + SSQ_Q_OFF;
    float* ssq_k = ws + SSQ_K_OFF;
    float* attn  = ws + ATTN_OFF;
    ushort* qwf  = (ushort*)(ws + QWF_OFF);
    ushort* kwf  = (ushort*)(ws + KWF_OFF);
    ushort* vwf  = (ushort*)(ws + VWF_OFF);
    ushort* w2f  = (ushort*)(ws + W2F_OFF);
    float* ws1   = ws + WS1_OFF;

    hipMemsetAsync(ws, 0, (768 + 768 + 18432) * sizeof(float), stream);

    prep_wfrag<<<dim3(36), 256, 0, stream>>>(qw1, 0, qwf);
    prep_wfrag<<<dim3(36), 256, 0, stream>>>(kvw1, 0, kwf);
    prep_wfrag<<<dim3(36), 256, 0, stream>>>(kvw1, 96, vwf);

    // ---- q path ----
    conv1x1_mfma<<<dim3(1024, 8), 384, 0, stream>>>(x, qwf, ws1);                    // q1
    depthwise3x3_kernel<<<dim3(8, 96, 8), 256, 0, stream>>>(ws1, qw2, out, ssq_q);   // q

    // ---- k path ----
    conv1x1_mfma<<<dim3(1024, 8), 384, 0, stream>>>(z, kwf, ws1);                    // kmid
    k_logits_kernel<<<dim3(64, 4, 8), 256, 0, stream>>>(ws1, kvw2, out, attn, ssq_k);

    softmax_fold_kernel<<<dim3(4, 8), 256, 0, stream>>>(attn, ssq_q, ssq_k, temp, projw, w2f);

    // ---- v path ----
    conv1x1_mfma<<<dim3(1024, 8), 384, 0, stream>>>(z, vwf, ws1);                    // vmid
    v_proj_mfma<<<dim3(1024, 8), 384, 0, stream>>>(ws1, kvw2, w2f, out);
}

// Round 22
// 735.782 us; speedup vs baseline: 1.0335x; 1.0033x over previous
//
#include <hip/hip_runtime.h>
#include <math.h>

#define HWc 65536
#define Wd 256
#define Hd 256

typedef __attribute__((ext_vector_type(8))) short bf16x8;
typedef __attribute__((ext_vector_type(4))) float f32x4;

__device__ inline ushort f2bf_hi(float a) {
    uint u = __float_as_uint(a);
    uint r = u + 0x7FFFu + ((u >> 16) & 1u);
    return (ushort)(r >> 16);
}
__device__ inline float bf2f(ushort h) { return __uint_as_float((uint)h << 16); }

// store 4 fp32 as hi/lo bf16 (two uint2 stores)
__device__ inline void store_hl4(ushort* hp, ushort* lp, const float* v) {
    ushort hs[4], ls[4];
#pragma unroll
    for (int e = 0; e < 4; ++e) {
        hs[e] = f2bf_hi(v[e]);
        ls[e] = f2bf_hi(v[e] - bf2f(hs[e]));
    }
    uint2 hv = make_uint2((uint)hs[0] | ((uint)hs[1] << 16),
                          (uint)hs[2] | ((uint)hs[3] << 16));
    uint2 lv = make_uint2((uint)ls[0] | ((uint)ls[1] << 16),
                          (uint)ls[2] | ((uint)ls[3] << 16));
    *(uint2*)hp = hv;
    *(uint2*)lp = lv;
}

// ---- ws layout (float offsets), small buffers FIRST ----
static const size_t SSQ_Q_OFF = 0;        // 768
static const size_t SSQ_K_OFF = 768;      // 768
static const size_t ATTN_OFF  = 1536;     // 18432 -> 19968
static const size_t QWF_OFF   = 19968;    // 9216 floats = hi/lo ushort frag table
static const size_t KWF_OFF   = 29184;    // 9216
static const size_t VWF_OFF   = 38400;    // 9216
static const size_t W2F_OFF   = 47616;    // 8 * 9216 = 73728 -> 121344
static const size_t WS1_OFF   = 121344;   // 8*96*HWc floats (201 MB)

// ---- precompute bf16 hi/lo weight frag table: wf[ks][m][kk], kk = c&31 ----
__global__ void prep_wfrag(const float* __restrict__ w, int woff,
                           ushort* __restrict__ wf) {
    int idx = blockIdx.x * 256 + threadIdx.x;
    if (idx < 9216) {
        int m = idx / 96, c = idx % 96;
        float val = w[(size_t)(woff + m) * 96 + c];
        ushort hi = f2bf_hi(val);
        float lo = val - bf2f(hi);
        wf[(c >> 5) * 3072 + m * 32 + (c & 31)] = hi;
        wf[9216 + (c >> 5) * 3072 + m * 32 + (c & 31)] = f2bf_hi(lo);
    }
}

// ---- 1x1 conv via MFMA (split-bf16), weights from frag table ----
__global__ __launch_bounds__(384) void conv1x1_mfma(
    const float* __restrict__ in, const ushort* __restrict__ wf,
    float* __restrict__ out)
{
    __shared__ ushort Ah[64][104];
    __shared__ ushort Al[64][104];
    int b = blockIdx.y;
    int px0 = blockIdx.x * 64;
    int t = threadIdx.x, lane = t & 63, wv = t >> 6;
    const float* inb = in + (size_t)b * 96 * HWc + px0;

    int m = 16 * wv + (lane & 15);
    int kbase = (lane >> 4) * 8;
    bf16x8 Bh[3], Bl[3];
#pragma unroll
    for (int ks = 0; ks < 3; ++ks) {
        Bh[ks] = *(const bf16x8*)&wf[ks * 3072 + m * 32 + kbase];
        Bl[ks] = *(const bf16x8*)&wf[9216 + ks * 3072 + m * 32 + kbase];
    }

#pragma unroll
    for (int rr = 0; rr < 4; ++rr) {
        int fi = rr * 384 + t;
        int c = fi >> 4;
        int p4 = (fi & 15) * 4;
        float4 v = *(const float4*)(inb + (size_t)c * HWc + p4);
        float vv[4] = {v.x, v.y, v.z, v.w};
#pragma unroll
        for (int e = 0; e < 4; ++e) {
            ushort hi = f2bf_hi(vv[e]);
            float lo = vv[e] - bf2f(hi);
            Ah[p4 + e][c] = hi;
            Al[p4 + e][c] = (ushort)f2bf_hi(lo);
        }
    }
    __syncthreads();

    f32x4 acc0 = {0.f, 0.f, 0.f, 0.f};
    f32x4 acc1 = {0.f, 0.f, 0.f, 0.f};
    f32x4 acc2 = {0.f, 0.f, 0.f, 0.f};
    f32x4 acc3 = {0.f, 0.f, 0.f, 0.f};
    int prow = lane & 15;

#pragma unroll
    for (int ks = 0; ks < 3; ++ks) {
        int ccol = ks * 32 + kbase;
#define DO_PT(PT, ACC)                                                         \
        {                                                                      \
            bf16x8 ah = *(const bf16x8*)&Ah[(PT) * 16 + prow][ccol];           \
            bf16x8 al = *(const bf16x8*)&Al[(PT) * 16 + prow][ccol];           \
            ACC = __builtin_amdgcn_mfma_f32_16x16x32_bf16(ah, Bh[ks], ACC, 0, 0, 0); \
            ACC = __builtin_amdgcn_mfma_f32_16x16x32_bf16(ah, Bl[ks], ACC, 0, 0, 0); \
            ACC = __builtin_amdgcn_mfma_f32_16x16x32_bf16(al, Bh[ks], ACC, 0, 0, 0); \
        }
        DO_PT(0, acc0) DO_PT(1, acc1) DO_PT(2, acc2) DO_PT(3, acc3)
#undef DO_PT
    }

    int pq = (lane >> 4) * 4;
    float* outm = out + (size_t)b * 96 * HWc + (size_t)m * HWc + px0 + pq;
    *(f32x4*)(outm + 0)  = acc0;
    *(f32x4*)(outm + 16) = acc1;
    *(f32x4*)(outm + 32) = acc2;
    *(f32x4*)(outm + 48) = acc3;
}

// ---- depthwise 3x3 (pad=1) + per-channel sumsq ----
__global__ __launch_bounds__(256) void depthwise3x3_kernel(
    const float* __restrict__ in, const float* __restrict__ wq,
    float* __restrict__ out, float* __restrict__ ssq_q)
{
    __shared__ float red[4];
    int c = blockIdx.y, b = blockIdx.z;
    int t = threadIdx.x;
    int lane = t & 63;
    int xq = lane * 4;
    int yb = blockIdx.x * 32 + (t >> 6) * 8;

    const float* inc = in + ((size_t)(b * 96 + c)) * HWc;
    float* outc = out + ((size_t)(b * 96 + c)) * HWc;

    float w[9];
    const float* wp = wq + (size_t)c * 9;
#pragma unroll
    for (int i = 0; i < 9; ++i) w[i] = wp[i];

    float rows[3][6];

#define LOAD_ROW(yy, slot)                                                     \
    {                                                                          \
        float4 v_;                                                             \
        if ((unsigned)(yy) < (unsigned)Hd)                                     \
            v_ = *(const float4*)(inc + (size_t)(yy) * Wd + xq);               \
        else                                                                   \
            v_ = make_float4(0.f, 0.f, 0.f, 0.f);                              \
        float lw_ = __shfl_up(v_.w, 1, 64);                                    \
        float rx_ = __shfl_down(v_.x, 1, 64);                                  \
        rows[slot][0] = (lane > 0) ? lw_ : 0.f;                                \
        rows[slot][1] = v_.x; rows[slot][2] = v_.y;                            \
        rows[slot][3] = v_.z; rows[slot][4] = v_.w;                            \
        rows[slot][5] = (lane < 63) ? rx_ : 0.f;                               \
    }

    LOAD_ROW(yb - 1, 0);
    LOAD_ROW(yb, 1);

    float ssq = 0.f;
#pragma unroll
    for (int r = 0; r < 8; ++r) {
        LOAD_ROW(yb + r + 1, (r + 2) % 3);
        const float* ra = rows[r % 3];
        const float* rb = rows[(r + 1) % 3];
        const float* rc = rows[(r + 2) % 3];
        float a[4] = {0.f, 0.f, 0.f, 0.f};
#pragma unroll
        for (int dx = 0; dx < 3; ++dx)
#pragma unroll
            for (int px = 0; px < 4; ++px) {
                a[px] = fmaf(w[dx],     ra[px + dx], a[px]);
                a[px] = fmaf(w[3 + dx], rb[px + dx], a[px]);
                a[px] = fmaf(w[6 + dx], rc[px + dx], a[px]);
            }
        *(float4*)(outc + (size_t)(yb + r) * Wd + xq) = *(float4*)a;
#pragma unroll
        for (int px = 0; px < 4; ++px) ssq = fmaf(a[px], a[px], ssq);
    }
#undef LOAD_ROW

#pragma unroll
    for (int off = 32; off; off >>= 1) ssq += __shfl_down(ssq, off, 64);
    int wvi = t >> 6;
    if (lane == 0) red[wvi] = ssq;
    __syncthreads();
    if (t == 0) atomicAdd(&ssq_q[b * 96 + c], red[0] + red[1] + red[2] + red[3]);
}

// conv macro for k_logits: pair P -> fr[2/3] rows 2P,2P+1 at local col x0l
#define CONV_PAIR(P, SS0, SS1)                                                 \
    {                                                                          \
        const float* m0 = midb + (size_t)(2 * (P)) * HWc;                      \
        const float* m1 = m0 + HWc;                                            \
        const float* wp_ = &wls[(P) * 36];                                     \
        float k0[4] = {0.f, 0.f, 0.f, 0.f};                                    \
        float k1[4] = {0.f, 0.f, 0.f, 0.f};                                    \
        _Pragma("unroll")                                                      \
        for (int dy = 0; dy < 3; ++dy) {                                       \
            int yy = y + dy - 1;                                               \
            if ((unsigned)yy < (unsigned)Hd) {                                 \
                _Pragma("unroll")                                              \
                for (int ic = 0; ic < 2; ++ic) {                               \
                    const float* base = (ic ? m1 : m0) + (size_t)yy * Wd;      \
                    float4 cv = *(const float4*)(base + xg);                   \
                    float rr[6];                                               \
                    rr[0] = (xg > 0) ? base[xg - 1] : 0.f;                     \
                    rr[1] = cv.x; rr[2] = cv.y; rr[3] = cv.z; rr[4] = cv.w;    \
                    rr[5] = (xg < 252) ? base[xg + 4] : 0.f;                   \
                    int wb_ = ic * 9 + dy * 3;                                 \
                    _Pragma("unroll")                                          \
                    for (int px = 0; px < 4; ++px) {                           \
                        _Pragma("unroll")                                      \
                        for (int dx = 0; dx < 3; ++dx) {                       \
                            k0[px] = fmaf(wp_[wb_ + dx],      rr[px + dx], k0[px]); \
                            k1[px] = fmaf(wp_[18 + wb_ + dx], rr[px + dx], k1[px]); \
                        }                                                      \
                    }                                                          \
                }                                                              \
            }                                                                  \
        }                                                                      \
        _Pragma("unroll")                                                      \
        for (int px = 0; px < 4; ++px) {                                       \
            SS0 = fmaf(k0[px], k0[px], SS0);                                   \
            SS1 = fmaf(k1[px], k1[px], SS1);                                   \
        }                                                                      \
        store_hl4(&fr[2][2 * (P)][x0l],     &fr[3][2 * (P)][x0l],     k0);     \
        store_hl4(&fr[2][2 * (P) + 1][x0l], &fr[3][2 * (P) + 1][x0l], k1);     \
    }

#define ST_Q(FI)                                                               \
    {                                                                          \
        int ch = (FI) >> 5;                                                    \
        int xo = ((FI) & 31) * 4;                                              \
        float4 v = *(const float4*)(qrow + (size_t)ch * HWc + xo);             \
        float vv[4] = {v.x, v.y, v.z, v.w};                                    \
        store_hl4(&fr[0][ch][xo], &fr[1][ch][xo], vv);                         \
    }

// ---- fused: grouped3x3(kmid) -> k (hi/lo bf16 LDS) + MFMA Gram + ssq_k ----
// fr planes: 0=q_hi 1=q_lo 2=k_hi 3=k_lo; rows 0..23 = channels (24..31 zero),
// cols = 128 px. Gram C[24,24] += Q.K^T via 2x2 quadrants of padded 32x32;
// wave wvi owns quadrant (mi=wvi>>1, nj=wvi&1); split-bf16 (3 MFMA per ks).
// D layout (verified): col=lane&15 -> k-ch (B), row=(lane>>4)*4+reg -> q-ch (A).
__global__ __launch_bounds__(256) void k_logits_kernel(
    const float* __restrict__ mid, const float* __restrict__ w2,
    const float* __restrict__ qg, float* __restrict__ attn_raw,
    float* __restrict__ ssq_k)
{
    __shared__ ushort fr[4][32][136];
    __shared__ float wls[24 * 18];

    int bx = blockIdx.x;
    int yt = bx >> 1, xh = bx & 1;
    int h = blockIdx.y, b = blockIdx.z;
    int xbase = xh * 128;
    int t = threadIdx.x, lane = t & 63, wvi = t >> 6;
    int hi = lane >> 5, l32 = lane & 31;

    const float* midb = mid + ((size_t)b * 96 + h * 24) * HWc;
    const float* qb   = qg  + ((size_t)b * 96 + h * 24) * HWc;

    if (t < 108)
        *(float4*)&wls[4 * t] = *(const float4*)(w2 + (size_t)h * 432 + 4 * t);
    // zero pad rows 24..31 of all 4 planes (544 uints per plane)
    for (int i = t; i < 2176; i += 256) {
        int plane = i / 544, idx = i % 544;
        ((uint*)&fr[plane][24][0])[idx] = 0;
    }

    int pA = 2 * wvi + hi;             // pairs 0..7
    int pB = 8 + 2 * wvi + hi;         // pairs 8..11 (waves 0-1)
    int x0l = l32 * 4;                 // local col
    int xg = xbase + x0l;              // global px

    int mi = wvi >> 1, nj = wvi & 1;   // C quadrant
    int prow16 = lane & 15, kb = (lane >> 4) * 8;

    f32x4 acc = {0.f, 0.f, 0.f, 0.f};
    float ssqA0 = 0.f, ssqA1 = 0.f, ssqB0 = 0.f, ssqB1 = 0.f;

    __syncthreads();                   // wls + zero pads ready

    for (int r = 0; r < 8; ++r) {
        int y = yt * 8 + r;
        __syncthreads();               // previous Gram's readers done

        // q staging part A: channels 0..15, all threads
        {
            const float* qrow = qb + (size_t)y * Wd + xbase;
            int fi = t;
            ST_Q(fi);
            fi = t + 256;
            ST_Q(fi);
        }
        CONV_PAIR(pA, ssqA0, ssqA1);
        if (t < 128) {
            CONV_PAIR(pB, ssqB0, ssqB1);
        } else {
            const float* qrow = qb + (size_t)y * Wd + xbase;
            int fi = 512 + (t - 128);
            ST_Q(fi);
            fi = 640 + (t - 128);
            ST_Q(fi);
        }
        __syncthreads();               // fr ready

        // MFMA Gram: quadrant (mi, nj), contraction over 128 px (4 ks steps)
#pragma unroll
        for (int ks2 = 0; ks2 < 4; ++ks2) {
            int col = ks2 * 32 + kb;
            bf16x8 ah = *(const bf16x8*)&fr[0][mi * 16 + prow16][col];
            bf16x8 al = *(const bf16x8*)&fr[1][mi * 16 + prow16][col];
            bf16x8 bh = *(const bf16x8*)&fr[2][nj * 16 + prow16][col];
            bf16x8 bl = *(const bf16x8*)&fr[3][nj * 16 + prow16][col];
            acc = __builtin_amdgcn_mfma_f32_16x16x32_bf16(ah, bh, acc, 0, 0, 0);
            acc = __builtin_amdgcn_mfma_f32_16x16x32_bf16(ah, bl, acc, 0, 0, 0);
            acc = __builtin_amdgcn_mfma_f32_16x16x32_bf16(al, bh, acc, 0, 0, 0);
        }
    }

    // ssq_k: reduce within 32-lane pair groups (fp32 values pre-conversion)
    {
        float s0 = ssqA0, s1 = ssqA1;
#pragma unroll
        for (int off = 16; off; off >>= 1) {
            s0 += __shfl_down(s0, off, 32);
            s1 += __shfl_down(s1, off, 32);
        }
        if (l32 == 0) {
            atomicAdd(&ssq_k[b * 96 + h * 24 + 2 * pA],     s0);
            atomicAdd(&ssq_k[b * 96 + h * 24 + 2 * pA + 1], s1);
        }
    }
    if (t < 128) {
        float s0 = ssqB0, s1 = ssqB1;
#pragma unroll
        for (int off = 16; off; off >>= 1) {
            s0 += __shfl_down(s0, off, 32);
            s1 += __shfl_down(s1, off, 32);
        }
        if (l32 == 0) {
            atomicAdd(&ssq_k[b * 96 + h * 24 + 2 * pB],     s0);
            atomicAdd(&ssq_k[b * 96 + h * 24 + 2 * pB + 1], s1);
        }
    }

    // write quadrant (wave-disjoint -> no cross-wave reduce needed)
    int jcol = nj * 16 + (lane & 15);
    if (jcol < 24) {
        float* dst = attn_raw + ((size_t)b * 4 + h) * 576;
#pragma unroll
        for (int rg = 0; rg < 4; ++rg) {
            int irow = mi * 16 + (lane >> 4) * 4 + rg;
            if (irow < 24)
                atomicAdd(&dst[irow * 24 + jcol], acc[rg]);
        }
    }
}

// ---- softmax (+temperature, +norms), fold proj -> W2 bf16 hi/lo frag table ----
__global__ __launch_bounds__(256) void softmax_fold_kernel(
    const float* __restrict__ attn_raw,
    const float* __restrict__ ssq_q, const float* __restrict__ ssq_k,
    const float* __restrict__ temp, const float* __restrict__ projw,
    ushort* __restrict__ W2F)
{
    __shared__ float s[24][25];
    __shared__ float rq[24], rk[24];
    int h = blockIdx.x, b = blockIdx.y;
    int t = threadIdx.x;

    if (t < 24) {
        rq[t] = 1.f / fmaxf(sqrtf(ssq_q[b * 96 + h * 24 + t]), 1e-12f);
        rk[t] = 1.f / fmaxf(sqrtf(ssq_k[b * 96 + h * 24 + t]), 1e-12f);
    }
    __syncthreads();
    float T = temp[h];
    for (int p = t; p < 576; p += 256) {
        int i = p / 24, j = p % 24;
        s[i][j] = attn_raw[(size_t)(b * 4 + h) * 576 + p] * T * rq[i] * rk[j];
    }
    __syncthreads();
    if (t < 24) {
        float m = -1e30f;
#pragma unroll
        for (int j = 0; j < 24; ++j) m = fmaxf(m, s[t][j]);
        float sum = 0.f;
#pragma unroll
        for (int j = 0; j < 24; ++j) { float e = __expf(s[t][j] - m); s[t][j] = e; sum += e; }
        float inv = 1.f / sum;
#pragma unroll
        for (int j = 0; j < 24; ++j) s[t][j] *= inv;
    }
    __syncthreads();
    ushort* wfb = W2F + (size_t)b * 18432;
    for (int m_ = t; m_ < 96 * 24; m_ += 256) {
        int d = m_ % 24, co = m_ / 24;
        float acc = 0.f;
#pragma unroll
        for (int c = 0; c < 24; ++c)
            acc += projw[co * 96 + h * 24 + c] * s[c][d];
        int dv = h * 24 + d;
        int ks = dv >> 5, kk = dv & 31;
        ushort hi = f2bf_hi(acc);
        float lo = acc - bf2f(hi);
        wfb[ks * 3072 + co * 32 + kk] = hi;
        wfb[9216 + ks * 3072 + co * 32 + kk] = f2bf_hi(lo);
    }
}

// ---- v_proj via MFMA: fp32 conv -> swizzled hi/lo bf16 LDS -> 36 MFMAs ----
__global__ __launch_bounds__(384) void v_proj_mfma(
    const float* __restrict__ mid, const float* __restrict__ w2,
    const ushort* __restrict__ W2F, float* __restrict__ out)
{
    __shared__ ushort Ah[64][128];
    __shared__ ushort Al[64][128];
    __shared__ float wls[1728];

    int bx = blockIdx.x, b = blockIdx.y;
    int y = bx >> 2;
    int x0 = (bx & 3) * 64;
    int t = threadIdx.x, lane = t & 63, wv = t >> 6;
    const float* midb = mid + (size_t)b * 96 * HWc;

    for (int i = t; i < 432; i += 384)
        *(float4*)&wls[4 * i] = *(const float4*)(w2 + 96 * 18 + 4 * i);

    int m = 16 * wv + (lane & 15);
    int kbase = (lane >> 4) * 8;
    const ushort* wfb = W2F + (size_t)b * 18432;
    bf16x8 Bh[3], Bl[3];
#pragma unroll
    for (int ks = 0; ks < 3; ++ks) {
        Bh[ks] = *(const bf16x8*)&wfb[ks * 3072 + m * 32 + kbase];
        Bl[ks] = *(const bf16x8*)&wfb[9216 + ks * 3072 + m * 32 + kbase];
    }
    __syncthreads();   // wls ready

    {
        int p = t >> 3;
        int xl = (t & 7) * 8;
        int xg = x0 + xl;
        const float* m0 = midb + (size_t)(2 * p) * HWc;
        const float* m1 = m0 + HWc;
        const float* wp_ = &wls[p * 36];
        float k0[8] = {0.f,0.f,0.f,0.f,0.f,0.f,0.f,0.f};
        float k1[8] = {0.f,0.f,0.f,0.f,0.f,0.f,0.f,0.f};
#pragma unroll
        for (int dy = 0; dy < 3; ++dy) {
            int yy = y + dy - 1;
            if ((unsigned)yy < (unsigned)Hd) {
#pragma unroll
                for (int ic = 0; ic < 2; ++ic) {
                    const float* base = (ic ? m1 : m0) + (size_t)yy * Wd;
                    float4 a = *(const float4*)(base + xg);
                    float4 b2 = *(const float4*)(base + xg + 4);
                    float rr[10];
                    rr[0] = (xg > 0) ? base[xg - 1] : 0.f;
                    rr[1] = a.x; rr[2] = a.y; rr[3] = a.z; rr[4] = a.w;
                    rr[5] = b2.x; rr[6] = b2.y; rr[7] = b2.z; rr[8] = b2.w;
                    rr[9] = (xg + 8 < 256) ? base[xg + 8] : 0.f;
                    int wb_ = ic * 9 + dy * 3;
#pragma unroll
                    for (int px = 0; px < 8; ++px) {
#pragma unroll
                        for (int dx = 0; dx < 3; ++dx) {
                            k0[px] = fmaf(wp_[wb_ + dx],      rr[px + dx], k0[px]);
                            k1[px] = fmaf(wp_[18 + wb_ + dx], rr[px + dx], k1[px]);
                        }
                    }
                }
            }
        }
#pragma unroll
        for (int px = 0; px < 8; ++px) {
            int row = xl + px;
            uint sw = (uint)(row & 7) << 4;
            uint off = ((uint)(4 * p)) ^ sw;
            ushort h0 = f2bf_hi(k0[px]);
            ushort h1 = f2bf_hi(k1[px]);
            float l0 = k0[px] - bf2f(h0);
            float l1 = k1[px] - bf2f(h1);
            *(uint*)((char*)&Ah[row][0] + off) = (uint)h0 | ((uint)h1 << 16);
            *(uint*)((char*)&Al[row][0] + off) =
                (uint)f2bf_hi(l0) | ((uint)f2bf_hi(l1) << 16);
        }
    }
    __syncthreads();

    f32x4 acc0 = {0.f, 0.f, 0.f, 0.f};
    f32x4 acc1 = {0.f, 0.f, 0.f, 0.f};
    f32x4 acc2 = {0.f, 0.f, 0.f, 0.f};
    f32x4 acc3 = {0.f, 0.f, 0.f, 0.f};
    int prow = lane & 15;

#pragma unroll
    for (int ks = 0; ks < 3; ++ks) {
        uint cbyte = (uint)(ks * 32 + kbase) * 2;
#define DO_PT(PT, ACC)                                                         \
        {                                                                      \
            int row = (PT) * 16 + prow;                                        \
            uint sw = (uint)(row & 7) << 4;                                    \
            bf16x8 ah = *(const bf16x8*)((char*)&Ah[row][0] + (cbyte ^ sw));   \
            bf16x8 al = *(const bf16x8*)((char*)&Al[row][0] + (cbyte ^ sw));   \
            ACC = __builtin_amdgcn_mfma_f32_16x16x32_bf16(ah, Bh[ks], ACC, 0, 0, 0); \
            ACC = __builtin_amdgcn_mfma_f32_16x16x32_bf16(ah, Bl[ks], ACC, 0, 0, 0); \
            ACC = __builtin_amdgcn_mfma_f32_16x16x32_bf16(al, Bh[ks], ACC, 0, 0, 0); \
        }
        DO_PT(0, acc0) DO_PT(1, acc1) DO_PT(2, acc2) DO_PT(3, acc3)
#undef DO_PT
    }

    int pq = (lane >> 4) * 4;
    float* outm = out + (size_t)b * 96 * HWc + (size_t)m * HWc
                + (size_t)y * Wd + x0 + pq;
    *(f32x4*)(outm + 0)  = acc0;
    *(f32x4*)(outm + 16) = acc1;
    *(f32x4*)(outm + 32) = acc2;
    *(f32x4*)(outm + 48) = acc3;
}

extern "C" void kernel_launch(void* const* d_in, const int* in_sizes, int n_in,
                              void* d_out, int out_size, void* d_ws, size_t ws_size,
                              hipStream_t stream) {
    const float* x     = (const float*)d_in[0];
    const float* z     = (const float*)d_in[1];
    const float* kvw1  = (const float*)d_in[2];
    const float* kvw2  = (const float*)d_in[3];
    const float* qw1   = (const float*)d_in[4];
    const float* qw2   = (const float*)d_in[5];
    const float* projw = (const float*)d_in[6];
    const float* temp  = (const float*)d_in[7];
    float* out = (float*)d_out;
    float* ws  = (float*)d_ws;
    (void)in_sizes; (void)n_in; (void)out_size; (void)ws_size;

    float* ssq_q = ws + SSQ_Q_OFF;
    float* ssq_k = ws + SSQ_K_OFF;
    float* attn  = ws + ATTN_OFF;
    ushort* qwf  = (ushort*)(ws + QWF_OFF);
    ushort* kwf  = (ushort*)(ws + KWF_OFF);
    ushort* vwf  = (ushort*)(ws + VWF_OFF);
    ushort* w2f  = (ushort*)(ws + W2F_OFF);
    float* ws1   = ws + WS1_OFF;

    hipMemsetAsync(ws, 0, (768 + 768 + 18432) * sizeof(float), stream);

    prep_wfrag<<<dim3(36), 256, 0, stream>>>(qw1, 0, qwf);
    prep_wfrag<<<dim3(36), 256, 0, stream>>>(kvw1, 0, kwf);
    prep_wfrag<<<dim3(36), 256, 0, stream>>>(kvw1, 96, vwf);

    // ---- q path ----
    conv1x1_mfma<<<dim3(1024, 8), 384, 0, stream>>>(x, qwf, ws1);                    // q1
    depthwise3x3_kernel<<<dim3(8, 96, 8), 256, 0, stream>>>(ws1, qw2, out, ssq_q);   // q

    // ---- k path ----
    conv1x1_mfma<<<dim3(1024, 8), 384, 0, stream>>>(z, kwf, ws1);                    // kmid
    k_logits_kernel<<<dim3(64, 4, 8), 256, 0, stream>>>(ws1, kvw2, out, attn, ssq_k);

    softmax_fold_kernel<<<dim3(4, 8), 256, 0, stream>>>(attn, ssq_q, ssq_k, temp, projw, w2f);

    // ---- v path ----
    conv1x1_mfma<<<dim3(1024, 8), 384, 0, stream>>>(z, vwf, ws1);                    // vmid
    v_proj_mfma<<<dim3(1024, 8), 384, 0, stream>>>(ws1, kvw2, w2f, out);
}

// Round 23
// 714.469 us; speedup vs baseline: 1.0643x; 1.0298x over previous
//
#include <hip/hip_runtime.h>
#include <math.h>

#define HWc 65536
#define Wd 256
#define Hd 256

typedef __attribute__((ext_vector_type(8))) short bf16x8;
typedef __attribute__((ext_vector_type(4))) float f32x4;

__device__ inline ushort f2bf_hi(float a) {
    uint u = __float_as_uint(a);
    uint r = u + 0x7FFFu + ((u >> 16) & 1u);
    return (ushort)(r >> 16);
}
__device__ inline float bf2f(ushort h) { return __uint_as_float((uint)h << 16); }
// row-hash for 256B-row LDS tiles: spreads both row&7 and row>>3 access patterns
__device__ inline uint rsw(int row) {
    return (uint)(((row & 7) ^ ((row >> 3) & 7)) << 4);
}

// store 4 fp32 as hi/lo bf16 (two uint2 stores)
__device__ inline void store_hl4(ushort* hp, ushort* lp, const float* v) {
    ushort hs[4], ls[4];
#pragma unroll
    for (int e = 0; e < 4; ++e) {
        hs[e] = f2bf_hi(v[e]);
        ls[e] = f2bf_hi(v[e] - bf2f(hs[e]));
    }
    uint2 hv = make_uint2((uint)hs[0] | ((uint)hs[1] << 16),
                          (uint)hs[2] | ((uint)hs[3] << 16));
    uint2 lv = make_uint2((uint)ls[0] | ((uint)ls[1] << 16),
                          (uint)ls[2] | ((uint)ls[3] << 16));
    *(uint2*)hp = hv;
    *(uint2*)lp = lv;
}

// ---- ws layout (float offsets), small buffers FIRST ----
static const size_t SSQ_Q_OFF = 0;        // 768
static const size_t SSQ_K_OFF = 768;      // 768
static const size_t ATTN_OFF  = 1536;     // 18432 -> 19968
static const size_t QWF_OFF   = 19968;    // 9216 floats = hi/lo ushort frag table
static const size_t KWF_OFF   = 29184;    // 9216
static const size_t VWF_OFF   = 38400;    // 9216
static const size_t W2F_OFF   = 47616;    // 8 * 9216 = 73728 -> 121344
static const size_t WS1_OFF   = 121344;   // 8*96*HWc floats (201 MB)

// ---- precompute bf16 hi/lo weight frag table: wf[ks][m][kk], kk = c&31 ----
__global__ void prep_wfrag(const float* __restrict__ w, int woff,
                           ushort* __restrict__ wf) {
    int idx = blockIdx.x * 256 + threadIdx.x;
    if (idx < 9216) {
        int m = idx / 96, c = idx % 96;
        float val = w[(size_t)(woff + m) * 96 + c];
        ushort hi = f2bf_hi(val);
        float lo = val - bf2f(hi);
        wf[(c >> 5) * 3072 + m * 32 + (c & 31)] = hi;
        wf[9216 + (c >> 5) * 3072 + m * 32 + (c & 31)] = f2bf_hi(lo);
    }
}

// ---- 1x1 conv via MFMA (split-bf16), weights from frag table ----
// Rows padded to 128 ushorts (256B); rsw XOR on staging writes + MFMA reads
// kills the 8-way write conflict (4-row-step writes hit one bank otherwise).
__global__ __launch_bounds__(384) void conv1x1_mfma(
    const float* __restrict__ in, const ushort* __restrict__ wf,
    float* __restrict__ out)
{
    __shared__ ushort Ah[64][128];
    __shared__ ushort Al[64][128];
    int b = blockIdx.y;
    int px0 = blockIdx.x * 64;
    int t = threadIdx.x, lane = t & 63, wv = t >> 6;
    const float* inb = in + (size_t)b * 96 * HWc + px0;

    int m = 16 * wv + (lane & 15);
    int kbase = (lane >> 4) * 8;
    bf16x8 Bh[3], Bl[3];
#pragma unroll
    for (int ks = 0; ks < 3; ++ks) {
        Bh[ks] = *(const bf16x8*)&wf[ks * 3072 + m * 32 + kbase];
        Bl[ks] = *(const bf16x8*)&wf[9216 + ks * 3072 + m * 32 + kbase];
    }

#pragma unroll
    for (int rr = 0; rr < 4; ++rr) {
        int fi = rr * 384 + t;
        int c = fi >> 4;
        int p4 = (fi & 15) * 4;
        float4 v = *(const float4*)(inb + (size_t)c * HWc + p4);
        float vv[4] = {v.x, v.y, v.z, v.w};
#pragma unroll
        for (int e = 0; e < 4; ++e) {
            int row = p4 + e;
            uint off = ((uint)(2 * c)) ^ rsw(row);
            ushort hi = f2bf_hi(vv[e]);
            float lo = vv[e] - bf2f(hi);
            *(ushort*)((char*)&Ah[row][0] + off) = hi;
            *(ushort*)((char*)&Al[row][0] + off) = f2bf_hi(lo);
        }
    }
    __syncthreads();

    f32x4 acc0 = {0.f, 0.f, 0.f, 0.f};
    f32x4 acc1 = {0.f, 0.f, 0.f, 0.f};
    f32x4 acc2 = {0.f, 0.f, 0.f, 0.f};
    f32x4 acc3 = {0.f, 0.f, 0.f, 0.f};
    int prow = lane & 15;

#pragma unroll
    for (int ks = 0; ks < 3; ++ks) {
        uint cbyte = (uint)(ks * 32 + kbase) * 2;
#define DO_PT(PT, ACC)                                                         \
        {                                                                      \
            int row = (PT) * 16 + prow;                                        \
            uint off = cbyte ^ rsw(row);                                       \
            bf16x8 ah = *(const bf16x8*)((char*)&Ah[row][0] + off);            \
            bf16x8 al = *(const bf16x8*)((char*)&Al[row][0] + off);            \
            ACC = __builtin_amdgcn_mfma_f32_16x16x32_bf16(ah, Bh[ks], ACC, 0, 0, 0); \
            ACC = __builtin_amdgcn_mfma_f32_16x16x32_bf16(ah, Bl[ks], ACC, 0, 0, 0); \
            ACC = __builtin_amdgcn_mfma_f32_16x16x32_bf16(al, Bh[ks], ACC, 0, 0, 0); \
        }
        DO_PT(0, acc0) DO_PT(1, acc1) DO_PT(2, acc2) DO_PT(3, acc3)
#undef DO_PT
    }

    int pq = (lane >> 4) * 4;
    float* outm = out + (size_t)b * 96 * HWc + (size_t)m * HWc + px0 + pq;
    *(f32x4*)(outm + 0)  = acc0;
    *(f32x4*)(outm + 16) = acc1;
    *(f32x4*)(outm + 32) = acc2;
    *(f32x4*)(outm + 48) = acc3;
}

// ---- depthwise 3x3 (pad=1) + per-channel sumsq ----
__global__ __launch_bounds__(256) void depthwise3x3_kernel(
    const float* __restrict__ in, const float* __restrict__ wq,
    float* __restrict__ out, float* __restrict__ ssq_q)
{
    __shared__ float red[4];
    int c = blockIdx.y, b = blockIdx.z;
    int t = threadIdx.x;
    int lane = t & 63;
    int xq = lane * 4;
    int yb = blockIdx.x * 32 + (t >> 6) * 8;

    const float* inc = in + ((size_t)(b * 96 + c)) * HWc;
    float* outc = out + ((size_t)(b * 96 + c)) * HWc;

    float w[9];
    const float* wp = wq + (size_t)c * 9;
#pragma unroll
    for (int i = 0; i < 9; ++i) w[i] = wp[i];

    float rows[3][6];

#define LOAD_ROW(yy, slot)                                                     \
    {                                                                          \
        float4 v_;                                                             \
        if ((unsigned)(yy) < (unsigned)Hd)                                     \
            v_ = *(const float4*)(inc + (size_t)(yy) * Wd + xq);               \
        else                                                                   \
            v_ = make_float4(0.f, 0.f, 0.f, 0.f);                              \
        float lw_ = __shfl_up(v_.w, 1, 64);                                    \
        float rx_ = __shfl_down(v_.x, 1, 64);                                  \
        rows[slot][0] = (lane > 0) ? lw_ : 0.f;                                \
        rows[slot][1] = v_.x; rows[slot][2] = v_.y;                            \
        rows[slot][3] = v_.z; rows[slot][4] = v_.w;                            \
        rows[slot][5] = (lane < 63) ? rx_ : 0.f;                               \
    }

    LOAD_ROW(yb - 1, 0);
    LOAD_ROW(yb, 1);

    float ssq = 0.f;
#pragma unroll
    for (int r = 0; r < 8; ++r) {
        LOAD_ROW(yb + r + 1, (r + 2) % 3);
        const float* ra = rows[r % 3];
        const float* rb = rows[(r + 1) % 3];
        const float* rc = rows[(r + 2) % 3];
        float a[4] = {0.f, 0.f, 0.f, 0.f};
#pragma unroll
        for (int dx = 0; dx < 3; ++dx)
#pragma unroll
            for (int px = 0; px < 4; ++px) {
                a[px] = fmaf(w[dx],     ra[px + dx], a[px]);
                a[px] = fmaf(w[3 + dx], rb[px + dx], a[px]);
                a[px] = fmaf(w[6 + dx], rc[px + dx], a[px]);
            }
        *(float4*)(outc + (size_t)(yb + r) * Wd + xq) = *(float4*)a;
#pragma unroll
        for (int px = 0; px < 4; ++px) ssq = fmaf(a[px], a[px], ssq);
    }
#undef LOAD_ROW

#pragma unroll
    for (int off = 32; off; off >>= 1) ssq += __shfl_down(ssq, off, 64);
    int wvi = t >> 6;
    if (lane == 0) red[wvi] = ssq;
    __syncthreads();
    if (t == 0) atomicAdd(&ssq_q[b * 96 + c], red[0] + red[1] + red[2] + red[3]);
}

// conv macro for k_logits: pair P -> fr[2/3] rows 2P,2P+1 at local col x0l
#define CONV_PAIR(P, SS0, SS1)                                                 \
    {                                                                          \
        const float* m0 = midb + (size_t)(2 * (P)) * HWc;                      \
        const float* m1 = m0 + HWc;                                            \
        const float* wp_ = &wls[(P) * 36];                                     \
        float k0[4] = {0.f, 0.f, 0.f, 0.f};                                    \
        float k1[4] = {0.f, 0.f, 0.f, 0.f};                                    \
        _Pragma("unroll")                                                      \
        for (int dy = 0; dy < 3; ++dy) {                                       \
            int yy = y + dy - 1;                                               \
            if ((unsigned)yy < (unsigned)Hd) {                                 \
                _Pragma("unroll")                                              \
                for (int ic = 0; ic < 2; ++ic) {                               \
                    const float* base = (ic ? m1 : m0) + (size_t)yy * Wd;      \
                    float4 cv = *(const float4*)(base + xg);                   \
                    float rr[6];                                               \
                    rr[0] = (xg > 0) ? base[xg - 1] : 0.f;                     \
                    rr[1] = cv.x; rr[2] = cv.y; rr[3] = cv.z; rr[4] = cv.w;    \
                    rr[5] = (xg < 252) ? base[xg + 4] : 0.f;                   \
                    int wb_ = ic * 9 + dy * 3;                                 \
                    _Pragma("unroll")                                          \
                    for (int px = 0; px < 4; ++px) {                           \
                        _Pragma("unroll")                                      \
                        for (int dx = 0; dx < 3; ++dx) {                       \
                            k0[px] = fmaf(wp_[wb_ + dx],      rr[px + dx], k0[px]); \
                            k1[px] = fmaf(wp_[18 + wb_ + dx], rr[px + dx], k1[px]); \
                        }                                                      \
                    }                                                          \
                }                                                              \
            }                                                                  \
        }                                                                      \
        _Pragma("unroll")                                                      \
        for (int px = 0; px < 4; ++px) {                                       \
            SS0 = fmaf(k0[px], k0[px], SS0);                                   \
            SS1 = fmaf(k1[px], k1[px], SS1);                                   \
        }                                                                      \
        store_hl4(&fr[2][2 * (P)][x0l],     &fr[3][2 * (P)][x0l],     k0);     \
        store_hl4(&fr[2][2 * (P) + 1][x0l], &fr[3][2 * (P) + 1][x0l], k1);     \
    }

#define ST_Q(FI)                                                               \
    {                                                                          \
        int ch = (FI) >> 5;                                                    \
        int xo = ((FI) & 31) * 4;                                              \
        float4 v = *(const float4*)(qrow + (size_t)ch * HWc + xo);             \
        float vv[4] = {v.x, v.y, v.z, v.w};                                    \
        store_hl4(&fr[0][ch][xo], &fr[1][ch][xo], vv);                         \
    }

// ---- fused: grouped3x3(kmid) -> k (hi/lo bf16 LDS) + MFMA Gram + ssq_k ----
__global__ __launch_bounds__(256) void k_logits_kernel(
    const float* __restrict__ mid, const float* __restrict__ w2,
    const float* __restrict__ qg, float* __restrict__ attn_raw,
    float* __restrict__ ssq_k)
{
    __shared__ ushort fr[4][32][136];
    __shared__ float wls[24 * 18];

    int bx = blockIdx.x;
    int yt = bx >> 1, xh = bx & 1;
    int h = blockIdx.y, b = blockIdx.z;
    int xbase = xh * 128;
    int t = threadIdx.x, lane = t & 63, wvi = t >> 6;
    int hi = lane >> 5, l32 = lane & 31;

    const float* midb = mid + ((size_t)b * 96 + h * 24) * HWc;
    const float* qb   = qg  + ((size_t)b * 96 + h * 24) * HWc;

    if (t < 108)
        *(float4*)&wls[4 * t] = *(const float4*)(w2 + (size_t)h * 432 + 4 * t);
    for (int i = t; i < 2176; i += 256) {
        int plane = i / 544, idx = i % 544;
        ((uint*)&fr[plane][24][0])[idx] = 0;
    }

    int pA = 2 * wvi + hi;
    int pB = 8 + 2 * wvi + hi;
    int x0l = l32 * 4;
    int xg = xbase + x0l;

    int mi = wvi >> 1, nj = wvi & 1;
    int prow16 = lane & 15, kb = (lane >> 4) * 8;

    f32x4 acc = {0.f, 0.f, 0.f, 0.f};
    float ssqA0 = 0.f, ssqA1 = 0.f, ssqB0 = 0.f, ssqB1 = 0.f;

    __syncthreads();

    for (int r = 0; r < 8; ++r) {
        int y = yt * 8 + r;
        __syncthreads();

        {
            const float* qrow = qb + (size_t)y * Wd + xbase;
            int fi = t;
            ST_Q(fi);
            fi = t + 256;
            ST_Q(fi);
        }
        CONV_PAIR(pA, ssqA0, ssqA1);
        if (t < 128) {
            CONV_PAIR(pB, ssqB0, ssqB1);
        } else {
            const float* qrow = qb + (size_t)y * Wd + xbase;
            int fi = 512 + (t - 128);
            ST_Q(fi);
            fi = 640 + (t - 128);
            ST_Q(fi);
        }
        __syncthreads();

#pragma unroll
        for (int ks2 = 0; ks2 < 4; ++ks2) {
            int col = ks2 * 32 + kb;
            bf16x8 ah = *(const bf16x8*)&fr[0][mi * 16 + prow16][col];
            bf16x8 al = *(const bf16x8*)&fr[1][mi * 16 + prow16][col];
            bf16x8 bh = *(const bf16x8*)&fr[2][nj * 16 + prow16][col];
            bf16x8 bl = *(const bf16x8*)&fr[3][nj * 16 + prow16][col];
            acc = __builtin_amdgcn_mfma_f32_16x16x32_bf16(ah, bh, acc, 0, 0, 0);
            acc = __builtin_amdgcn_mfma_f32_16x16x32_bf16(ah, bl, acc, 0, 0, 0);
            acc = __builtin_amdgcn_mfma_f32_16x16x32_bf16(al, bh, acc, 0, 0, 0);
        }
    }

    {
        float s0 = ssqA0, s1 = ssqA1;
#pragma unroll
        for (int off = 16; off; off >>= 1) {
            s0 += __shfl_down(s0, off, 32);
            s1 += __shfl_down(s1, off, 32);
        }
        if (l32 == 0) {
            atomicAdd(&ssq_k[b * 96 + h * 24 + 2 * pA],     s0);
            atomicAdd(&ssq_k[b * 96 + h * 24 + 2 * pA + 1], s1);
        }
    }
    if (t < 128) {
        float s0 = ssqB0, s1 = ssqB1;
#pragma unroll
        for (int off = 16; off; off >>= 1) {
            s0 += __shfl_down(s0, off, 32);
            s1 += __shfl_down(s1, off, 32);
        }
        if (l32 == 0) {
            atomicAdd(&ssq_k[b * 96 + h * 24 + 2 * pB],     s0);
            atomicAdd(&ssq_k[b * 96 + h * 24 + 2 * pB + 1], s1);
        }
    }

    int jcol = nj * 16 + (lane & 15);
    if (jcol < 24) {
        float* dst = attn_raw + ((size_t)b * 4 + h) * 576;
#pragma unroll
        for (int rg = 0; rg < 4; ++rg) {
            int irow = mi * 16 + (lane >> 4) * 4 + rg;
            if (irow < 24)
                atomicAdd(&dst[irow * 24 + jcol], acc[rg]);
        }
    }
}

// ---- softmax (+temperature, +norms), fold proj -> W2 bf16 hi/lo frag table ----
__global__ __launch_bounds__(256) void softmax_fold_kernel(
    const float* __restrict__ attn_raw,
    const float* __restrict__ ssq_q, const float* __restrict__ ssq_k,
    const float* __restrict__ temp, const float* __restrict__ projw,
    ushort* __restrict__ W2F)
{
    __shared__ float s[24][25];
    __shared__ float rq[24], rk[24];
    int h = blockIdx.x, b = blockIdx.y;
    int t = threadIdx.x;

    if (t < 24) {
        rq[t] = 1.f / fmaxf(sqrtf(ssq_q[b * 96 + h * 24 + t]), 1e-12f);
        rk[t] = 1.f / fmaxf(sqrtf(ssq_k[b * 96 + h * 24 + t]), 1e-12f);
    }
    __syncthreads();
    float T = temp[h];
    for (int p = t; p < 576; p += 256) {
        int i = p / 24, j = p % 24;
        s[i][j] = attn_raw[(size_t)(b * 4 + h) * 576 + p] * T * rq[i] * rk[j];
    }
    __syncthreads();
    if (t < 24) {
        float m = -1e30f;
#pragma unroll
        for (int j = 0; j < 24; ++j) m = fmaxf(m, s[t][j]);
        float sum = 0.f;
#pragma unroll
        for (int j = 0; j < 24; ++j) { float e = __expf(s[t][j] - m); s[t][j] = e; sum += e; }
        float inv = 1.f / sum;
#pragma unroll
        for (int j = 0; j < 24; ++j) s[t][j] *= inv;
    }
    __syncthreads();
    ushort* wfb = W2F + (size_t)b * 18432;
    for (int m_ = t; m_ < 96 * 24; m_ += 256) {
        int d = m_ % 24, co = m_ / 24;
        float acc = 0.f;
#pragma unroll
        for (int c = 0; c < 24; ++c)
            acc += projw[co * 96 + h * 24 + c] * s[c][d];
        int dv = h * 24 + d;
        int ks = dv >> 5, kk = dv & 31;
        ushort hi = f2bf_hi(acc);
        float lo = acc - bf2f(hi);
        wfb[ks * 3072 + co * 32 + kk] = hi;
        wfb[9216 + ks * 3072 + co * 32 + kk] = f2bf_hi(lo);
    }
}

// ---- v_proj via MFMA: fp32 conv -> rsw-swizzled hi/lo bf16 LDS -> 36 MFMAs ----
__global__ __launch_bounds__(384) void v_proj_mfma(
    const float* __restrict__ mid, const float* __restrict__ w2,
    const ushort* __restrict__ W2F, float* __restrict__ out)
{
    __shared__ ushort Ah[64][128];
    __shared__ ushort Al[64][128];
    __shared__ float wls[1728];

    int bx = blockIdx.x, b = blockIdx.y;
    int y = bx >> 2;
    int x0 = (bx & 3) * 64;
    int t = threadIdx.x, lane = t & 63, wv = t >> 6;
    const float* midb = mid + (size_t)b * 96 * HWc;

    for (int i = t; i < 432; i += 384)
        *(float4*)&wls[4 * i] = *(const float4*)(w2 + 96 * 18 + 4 * i);

    int m = 16 * wv + (lane & 15);
    int kbase = (lane >> 4) * 8;
    const ushort* wfb = W2F + (size_t)b * 18432;
    bf16x8 Bh[3], Bl[3];
#pragma unroll
    for (int ks = 0; ks < 3; ++ks) {
        Bh[ks] = *(const bf16x8*)&wfb[ks * 3072 + m * 32 + kbase];
        Bl[ks] = *(const bf16x8*)&wfb[9216 + ks * 3072 + m * 32 + kbase];
    }
    __syncthreads();   // wls ready

    {
        int p = t >> 3;
        int xl = (t & 7) * 8;
        int xg = x0 + xl;
        const float* m0 = midb + (size_t)(2 * p) * HWc;
        const float* m1 = m0 + HWc;
        const float* wp_ = &wls[p * 36];
        float k0[8] = {0.f,0.f,0.f,0.f,0.f,0.f,0.f,0.f};
        float k1[8] = {0.f,0.f,0.f,0.f,0.f,0.f,0.f,0.f};
#pragma unroll
        for (int dy = 0; dy < 3; ++dy) {
            int yy = y + dy - 1;
            if ((unsigned)yy < (unsigned)Hd) {
#pragma unroll
                for (int ic = 0; ic < 2; ++ic) {
                    const float* base = (ic ? m1 : m0) + (size_t)yy * Wd;
                    float4 a = *(const float4*)(base + xg);
                    float4 b2 = *(const float4*)(base + xg + 4);
                    float rr[10];
                    rr[0] = (xg > 0) ? base[xg - 1] : 0.f;
                    rr[1] = a.x; rr[2] = a.y; rr[3] = a.z; rr[4] = a.w;
                    rr[5] = b2.x; rr[6] = b2.y; rr[7] = b2.z; rr[8] = b2.w;
                    rr[9] = (xg + 8 < 256) ? base[xg + 8] : 0.f;
                    int wb_ = ic * 9 + dy * 3;
#pragma unroll
                    for (int px = 0; px < 8; ++px) {
#pragma unroll
                        for (int dx = 0; dx < 3; ++dx) {
                            k0[px] = fmaf(wp_[wb_ + dx],      rr[px + dx], k0[px]);
                            k1[px] = fmaf(wp_[18 + wb_ + dx], rr[px + dx], k1[px]);
                        }
                    }
                }
            }
        }
#pragma unroll
        for (int px = 0; px < 8; ++px) {
            int row = xl + px;
            uint off = ((uint)(4 * p)) ^ rsw(row);
            ushort h0 = f2bf_hi(k0[px]);
            ushort h1 = f2bf_hi(k1[px]);
            float l0 = k0[px] - bf2f(h0);
            float l1 = k1[px] - bf2f(h1);
            *(uint*)((char*)&Ah[row][0] + off) = (uint)h0 | ((uint)h1 << 16);
            *(uint*)((char*)&Al[row][0] + off) =
                (uint)f2bf_hi(l0) | ((uint)f2bf_hi(l1) << 16);
        }
    }
    __syncthreads();

    f32x4 acc0 = {0.f, 0.f, 0.f, 0.f};
    f32x4 acc1 = {0.f, 0.f, 0.f, 0.f};
    f32x4 acc2 = {0.f, 0.f, 0.f, 0.f};
    f32x4 acc3 = {0.f, 0.f, 0.f, 0.f};
    int prow = lane & 15;

#pragma unroll
    for (int ks = 0; ks < 3; ++ks) {
        uint cbyte = (uint)(ks * 32 + kbase) * 2;
#define DO_PT(PT, ACC)                                                         \
        {                                                                      \
            int row = (PT) * 16 + prow;                                        \
            uint off = cbyte ^ rsw(row);                                       \
            bf16x8 ah = *(const bf16x8*)((char*)&Ah[row][0] + off);            \
            bf16x8 al = *(const bf16x8*)((char*)&Al[row][0] + off);            \
            ACC = __builtin_amdgcn_mfma_f32_16x16x32_bf16(ah, Bh[ks], ACC, 0, 0, 0); \
            ACC = __builtin_amdgcn_mfma_f32_16x16x32_bf16(ah, Bl[ks], ACC, 0, 0, 0); \
            ACC = __builtin_amdgcn_mfma_f32_16x16x32_bf16(al, Bh[ks], ACC, 0, 0, 0); \
        }
        DO_PT(0, acc0) DO_PT(1, acc1) DO_PT(2, acc2) DO_PT(3, acc3)
#undef DO_PT
    }

    int pq = (lane >> 4) * 4;
    float* outm = out + (size_t)b * 96 * HWc + (size_t)m * HWc
                + (size_t)y * Wd + x0 + pq;
    *(f32x4*)(outm + 0)  = acc0;
    *(f32x4*)(outm + 16) = acc1;
    *(f32x4*)(outm + 32) = acc2;
    *(f32x4*)(outm + 48) = acc3;
}

extern "C" void kernel_launch(void* const* d_in, const int* in_sizes, int n_in,
                              void* d_out, int out_size, void* d_ws, size_t ws_size,
                              hipStream_t stream) {
    const float* x     = (const float*)d_in[0];
    const float* z     = (const float*)d_in[1];
    const float* kvw1  = (const float*)d_in[2];
    const float* kvw2  = (const float*)d_in[3];
    const float* qw1   = (const float*)d_in[4];
    const float* qw2   = (const float*)d_in[5];
    const float* projw = (const float*)d_in[6];
    const float* temp  = (const float*)d_in[7];
    float* out = (float*)d_out;
    float* ws  = (float*)d_ws;
    (void)in_sizes; (void)n_in; (void)out_size; (void)ws_size;

    float* ssq_q = ws + SSQ_Q_OFF;
    float* ssq_k = ws + SSQ_K_OFF;
    float* attn  = ws + ATTN_OFF;
    ushort* qwf  = (ushort*)(ws + QWF_OFF);
    ushort* kwf  = (ushort*)(ws + KWF_OFF);
    ushort* vwf  = (ushort*)(ws + VWF_OFF);
    ushort* w2f  = (ushort*)(ws + W2F_OFF);
    float* ws1   = ws + WS1_OFF;

    hipMemsetAsync(ws, 0, (768 + 768 + 18432) * sizeof(float), stream);

    prep_wfrag<<<dim3(36), 256, 0, stream>>>(qw1, 0, qwf);
    prep_wfrag<<<dim3(36), 256, 0, stream>>>(kvw1, 0, kwf);
    prep_wfrag<<<dim3(36), 256, 0, stream>>>(kvw1, 96, vwf);

    // ---- q path ----
    conv1x1_mfma<<<dim3(1024, 8), 384, 0, stream>>>(x, qwf, ws1);                    // q1
    depthwise3x3_kernel<<<dim3(8, 96, 8), 256, 0, stream>>>(ws1, qw2, out, ssq_q);   // q

    // ---- k path ----
    conv1x1_mfma<<<dim3(1024, 8), 384, 0, stream>>>(z, kwf, ws1);                    // kmid
    k_logits_kernel<<<dim3(64, 4, 8), 256, 0, stream>>>(ws1, kvw2, out, attn, ssq_k);

    softmax_fold_kernel<<<dim3(4, 8), 256, 0, stream>>>(attn, ssq_q, ssq_k, temp, projw, w2f);

    // ---- v path ----
    conv1x1_mfma<<<dim3(1024, 8), 384, 0, stream>>>(z, vwf, ws1);                    // vmid
    v_proj_mfma<<<dim3(1024, 8), 384, 0, stream>>>(ws1, kvw2, w2f, out);
}

// Round 24
// 681.859 us; speedup vs baseline: 1.1152x; 1.0478x over previous
//
#include <hip/hip_runtime.h>
#include <math.h>

#define HWc 65536
#define Wd 256
#define Hd 256

typedef __attribute__((ext_vector_type(8))) short bf16x8;
typedef __attribute__((ext_vector_type(4))) float f32x4;

__device__ inline ushort f2bf_hi(float a) {
    uint u = __float_as_uint(a);
    uint r = u + 0x7FFFu + ((u >> 16) & 1u);
    return (ushort)(r >> 16);
}
__device__ inline float bf2f(ushort h) { return __uint_as_float((uint)h << 16); }
__device__ inline uint rsw(int row) {
    return (uint)(((row & 7) ^ ((row >> 3) & 7)) << 4);
}

__device__ inline void store_hl4(ushort* hp, ushort* lp, const float* v) {
    ushort hs[4], ls[4];
#pragma unroll
    for (int e = 0; e < 4; ++e) {
        hs[e] = f2bf_hi(v[e]);
        ls[e] = f2bf_hi(v[e] - bf2f(hs[e]));
    }
    uint2 hv = make_uint2((uint)hs[0] | ((uint)hs[1] << 16),
                          (uint)hs[2] | ((uint)hs[3] << 16));
    uint2 lv = make_uint2((uint)ls[0] | ((uint)ls[1] << 16),
                          (uint)ls[2] | ((uint)ls[3] << 16));
    *(uint2*)hp = hv;
    *(uint2*)lp = lv;
}

// ---- ws layout (float offsets), small buffers FIRST ----
static const size_t SSQ_Q_OFF = 0;        // 768
static const size_t SSQ_K_OFF = 768;      // 768
static const size_t ATTN_OFF  = 1536;     // 18432 -> 19968
static const size_t QWF_OFF   = 19968;
static const size_t KWF_OFF   = 29184;
static const size_t VWF_OFF   = 38400;
static const size_t W2F_OFF   = 47616;    // -> 121344
static const size_t WS1_OFF   = 121344;   // 50331648 floats (201 MB)
static const size_t WS1_LEN   = 50331648; // per mid buffer

// ---- precompute bf16 hi/lo weight frag table ----
__global__ void prep_wfrag(const float* __restrict__ w, int woff,
                           ushort* __restrict__ wf) {
    int idx = blockIdx.x * 256 + threadIdx.x;
    if (idx < 9216) {
        int m = idx / 96, c = idx % 96;
        float val = w[(size_t)(woff + m) * 96 + c];
        ushort hi = f2bf_hi(val);
        float lo = val - bf2f(hi);
        wf[(c >> 5) * 3072 + m * 32 + (c & 31)] = hi;
        wf[9216 + (c >> 5) * 3072 + m * 32 + (c & 31)] = f2bf_hi(lo);
    }
}

// ---- 1x1 conv via MFMA (split-bf16), weights from frag table ----
__global__ __launch_bounds__(384) void conv1x1_mfma(
    const float* __restrict__ in, const ushort* __restrict__ wf,
    float* __restrict__ out)
{
    __shared__ ushort Ah[64][128];
    __shared__ ushort Al[64][128];
    int b = blockIdx.y;
    int px0 = blockIdx.x * 64;
    int t = threadIdx.x, lane = t & 63, wv = t >> 6;
    const float* inb = in + (size_t)b * 96 * HWc + px0;

    int m = 16 * wv + (lane & 15);
    int kbase = (lane >> 4) * 8;
    bf16x8 Bh[3], Bl[3];
#pragma unroll
    for (int ks = 0; ks < 3; ++ks) {
        Bh[ks] = *(const bf16x8*)&wf[ks * 3072 + m * 32 + kbase];
        Bl[ks] = *(const bf16x8*)&wf[9216 + ks * 3072 + m * 32 + kbase];
    }

#pragma unroll
    for (int rr = 0; rr < 4; ++rr) {
        int fi = rr * 384 + t;
        int c = fi >> 4;
        int p4 = (fi & 15) * 4;
        float4 v = *(const float4*)(inb + (size_t)c * HWc + p4);
        float vv[4] = {v.x, v.y, v.z, v.w};
#pragma unroll
        for (int e = 0; e < 4; ++e) {
            int row = p4 + e;
            uint off = ((uint)(2 * c)) ^ rsw(row);
            ushort hi = f2bf_hi(vv[e]);
            float lo = vv[e] - bf2f(hi);
            *(ushort*)((char*)&Ah[row][0] + off) = hi;
            *(ushort*)((char*)&Al[row][0] + off) = f2bf_hi(lo);
        }
    }
    __syncthreads();

    f32x4 acc0 = {0.f, 0.f, 0.f, 0.f};
    f32x4 acc1 = {0.f, 0.f, 0.f, 0.f};
    f32x4 acc2 = {0.f, 0.f, 0.f, 0.f};
    f32x4 acc3 = {0.f, 0.f, 0.f, 0.f};
    int prow = lane & 15;

#pragma unroll
    for (int ks = 0; ks < 3; ++ks) {
        uint cbyte = (uint)(ks * 32 + kbase) * 2;
#define DO_PT(PT, ACC)                                                         \
        {                                                                      \
            int row = (PT) * 16 + prow;                                        \
            uint off = cbyte ^ rsw(row);                                       \
            bf16x8 ah = *(const bf16x8*)((char*)&Ah[row][0] + off);            \
            bf16x8 al = *(const bf16x8*)((char*)&Al[row][0] + off);            \
            ACC = __builtin_amdgcn_mfma_f32_16x16x32_bf16(ah, Bh[ks], ACC, 0, 0, 0); \
            ACC = __builtin_amdgcn_mfma_f32_16x16x32_bf16(ah, Bl[ks], ACC, 0, 0, 0); \
            ACC = __builtin_amdgcn_mfma_f32_16x16x32_bf16(al, Bh[ks], ACC, 0, 0, 0); \
        }
        DO_PT(0, acc0) DO_PT(1, acc1) DO_PT(2, acc2) DO_PT(3, acc3)
#undef DO_PT
    }

    int pq = (lane >> 4) * 4;
    float* outm = out + (size_t)b * 96 * HWc + (size_t)m * HWc + px0 + pq;
    *(f32x4*)(outm + 0)  = acc0;
    *(f32x4*)(outm + 16) = acc1;
    *(f32x4*)(outm + 32) = acc2;
    *(f32x4*)(outm + 48) = acc3;
}

// ---- fused k+v 1x1 conv: one z read, two frag tables, two outputs ----
__global__ __launch_bounds__(384) void conv1x1_mfma_kv(
    const float* __restrict__ in, const ushort* __restrict__ kwf,
    const ushort* __restrict__ vwf,
    float* __restrict__ outk, float* __restrict__ outv)
{
    __shared__ ushort Ah[64][128];
    __shared__ ushort Al[64][128];
    int b = blockIdx.y;
    int px0 = blockIdx.x * 64;
    int t = threadIdx.x, lane = t & 63, wv = t >> 6;
    const float* inb = in + (size_t)b * 96 * HWc + px0;

    int m = 16 * wv + (lane & 15);
    int kbase = (lane >> 4) * 8;
    bf16x8 Bkh[3], Bkl[3], Bvh[3], Bvl[3];
#pragma unroll
    for (int ks = 0; ks < 3; ++ks) {
        Bkh[ks] = *(const bf16x8*)&kwf[ks * 3072 + m * 32 + kbase];
        Bkl[ks] = *(const bf16x8*)&kwf[9216 + ks * 3072 + m * 32 + kbase];
        Bvh[ks] = *(const bf16x8*)&vwf[ks * 3072 + m * 32 + kbase];
        Bvl[ks] = *(const bf16x8*)&vwf[9216 + ks * 3072 + m * 32 + kbase];
    }

#pragma unroll
    for (int rr = 0; rr < 4; ++rr) {
        int fi = rr * 384 + t;
        int c = fi >> 4;
        int p4 = (fi & 15) * 4;
        float4 v = *(const float4*)(inb + (size_t)c * HWc + p4);
        float vv[4] = {v.x, v.y, v.z, v.w};
#pragma unroll
        for (int e = 0; e < 4; ++e) {
            int row = p4 + e;
            uint off = ((uint)(2 * c)) ^ rsw(row);
            ushort hi = f2bf_hi(vv[e]);
            float lo = vv[e] - bf2f(hi);
            *(ushort*)((char*)&Ah[row][0] + off) = hi;
            *(ushort*)((char*)&Al[row][0] + off) = f2bf_hi(lo);
        }
    }
    __syncthreads();

    f32x4 ak0 = {0.f,0.f,0.f,0.f}, ak1 = {0.f,0.f,0.f,0.f};
    f32x4 ak2 = {0.f,0.f,0.f,0.f}, ak3 = {0.f,0.f,0.f,0.f};
    f32x4 av0 = {0.f,0.f,0.f,0.f}, av1 = {0.f,0.f,0.f,0.f};
    f32x4 av2 = {0.f,0.f,0.f,0.f}, av3 = {0.f,0.f,0.f,0.f};
    int prow = lane & 15;

#pragma unroll
    for (int ks = 0; ks < 3; ++ks) {
        uint cbyte = (uint)(ks * 32 + kbase) * 2;
#define DO_PT2(PT, AK, AV)                                                     \
        {                                                                      \
            int row = (PT) * 16 + prow;                                        \
            uint off = cbyte ^ rsw(row);                                       \
            bf16x8 ah = *(const bf16x8*)((char*)&Ah[row][0] + off);            \
            bf16x8 al = *(const bf16x8*)((char*)&Al[row][0] + off);            \
            AK = __builtin_amdgcn_mfma_f32_16x16x32_bf16(ah, Bkh[ks], AK, 0, 0, 0); \
            AK = __builtin_amdgcn_mfma_f32_16x16x32_bf16(ah, Bkl[ks], AK, 0, 0, 0); \
            AK = __builtin_amdgcn_mfma_f32_16x16x32_bf16(al, Bkh[ks], AK, 0, 0, 0); \
            AV = __builtin_amdgcn_mfma_f32_16x16x32_bf16(ah, Bvh[ks], AV, 0, 0, 0); \
            AV = __builtin_amdgcn_mfma_f32_16x16x32_bf16(ah, Bvl[ks], AV, 0, 0, 0); \
            AV = __builtin_amdgcn_mfma_f32_16x16x32_bf16(al, Bvh[ks], AV, 0, 0, 0); \
        }
        DO_PT2(0, ak0, av0) DO_PT2(1, ak1, av1)
        DO_PT2(2, ak2, av2) DO_PT2(3, ak3, av3)
#undef DO_PT2
    }

    int pq = (lane >> 4) * 4;
    float* outm = outk + (size_t)b * 96 * HWc + (size_t)m * HWc + px0 + pq;
    *(f32x4*)(outm + 0)  = ak0;
    *(f32x4*)(outm + 16) = ak1;
    *(f32x4*)(outm + 32) = ak2;
    *(f32x4*)(outm + 48) = ak3;
    float* outn = outv + (size_t)b * 96 * HWc + (size_t)m * HWc + px0 + pq;
    *(f32x4*)(outn + 0)  = av0;
    *(f32x4*)(outn + 16) = av1;
    *(f32x4*)(outn + 32) = av2;
    *(f32x4*)(outn + 48) = av3;
}

// ---- depthwise 3x3 (pad=1) + per-channel sumsq ----
__global__ __launch_bounds__(256) void depthwise3x3_kernel(
    const float* __restrict__ in, const float* __restrict__ wq,
    float* __restrict__ out, float* __restrict__ ssq_q)
{
    __shared__ float red[4];
    int c = blockIdx.y, b = blockIdx.z;
    int t = threadIdx.x;
    int lane = t & 63;
    int xq = lane * 4;
    int yb = blockIdx.x * 32 + (t >> 6) * 8;

    const float* inc = in + ((size_t)(b * 96 + c)) * HWc;
    float* outc = out + ((size_t)(b * 96 + c)) * HWc;

    float w[9];
    const float* wp = wq + (size_t)c * 9;
#pragma unroll
    for (int i = 0; i < 9; ++i) w[i] = wp[i];

    float rows[3][6];

#define LOAD_ROW(yy, slot)                                                     \
    {                                                                          \
        float4 v_;                                                             \
        if ((unsigned)(yy) < (unsigned)Hd)                                     \
            v_ = *(const float4*)(inc + (size_t)(yy) * Wd + xq);               \
        else                                                                   \
            v_ = make_float4(0.f, 0.f, 0.f, 0.f);                              \
        float lw_ = __shfl_up(v_.w, 1, 64);                                    \
        float rx_ = __shfl_down(v_.x, 1, 64);                                  \
        rows[slot][0] = (lane > 0) ? lw_ : 0.f;                                \
        rows[slot][1] = v_.x; rows[slot][2] = v_.y;                            \
        rows[slot][3] = v_.z; rows[slot][4] = v_.w;                            \
        rows[slot][5] = (lane < 63) ? rx_ : 0.f;                               \
    }

    LOAD_ROW(yb - 1, 0);
    LOAD_ROW(yb, 1);

    float ssq = 0.f;
#pragma unroll
    for (int r = 0; r < 8; ++r) {
        LOAD_ROW(yb + r + 1, (r + 2) % 3);
        const float* ra = rows[r % 3];
        const float* rb = rows[(r + 1) % 3];
        const float* rc = rows[(r + 2) % 3];
        float a[4] = {0.f, 0.f, 0.f, 0.f};
#pragma unroll
        for (int dx = 0; dx < 3; ++dx)
#pragma unroll
            for (int px = 0; px < 4; ++px) {
                a[px] = fmaf(w[dx],     ra[px + dx], a[px]);
                a[px] = fmaf(w[3 + dx], rb[px + dx], a[px]);
                a[px] = fmaf(w[6 + dx], rc[px + dx], a[px]);
            }
        *(float4*)(outc + (size_t)(yb + r) * Wd + xq) = *(float4*)a;
#pragma unroll
        for (int px = 0; px < 4; ++px) ssq = fmaf(a[px], a[px], ssq);
    }
#undef LOAD_ROW

#pragma unroll
    for (int off = 32; off; off >>= 1) ssq += __shfl_down(ssq, off, 64);
    int wvi = t >> 6;
    if (lane == 0) red[wvi] = ssq;
    __syncthreads();
    if (t == 0) atomicAdd(&ssq_q[b * 96 + c], red[0] + red[1] + red[2] + red[3]);
}

// conv macro for k_logits
#define CONV_PAIR(P, SS0, SS1)                                                 \
    {                                                                          \
        const float* m0 = midb + (size_t)(2 * (P)) * HWc;                      \
        const float* m1 = m0 + HWc;                                            \
        const float* wp_ = &wls[(P) * 36];                                     \
        float k0[4] = {0.f, 0.f, 0.f, 0.f};                                    \
        float k1[4] = {0.f, 0.f, 0.f, 0.f};                                    \
        _Pragma("unroll")                                                      \
        for (int dy = 0; dy < 3; ++dy) {                                       \
            int yy = y + dy - 1;                                               \
            if ((unsigned)yy < (unsigned)Hd) {                                 \
                _Pragma("unroll")                                              \
                for (int ic = 0; ic < 2; ++ic) {                               \
                    const float* base = (ic ? m1 : m0) + (size_t)yy * Wd;      \
                    float4 cv = *(const float4*)(base + xg);                   \
                    float rr[6];                                               \
                    rr[0] = (xg > 0) ? base[xg - 1] : 0.f;                     \
                    rr[1] = cv.x; rr[2] = cv.y; rr[3] = cv.z; rr[4] = cv.w;    \
                    rr[5] = (xg < 252) ? base[xg + 4] : 0.f;                   \
                    int wb_ = ic * 9 + dy * 3;                                 \
                    _Pragma("unroll")                                          \
                    for (int px = 0; px < 4; ++px) {                           \
                        _Pragma("unroll")                                      \
                        for (int dx = 0; dx < 3; ++dx) {                       \
                            k0[px] = fmaf(wp_[wb_ + dx],      rr[px + dx], k0[px]); \
                            k1[px] = fmaf(wp_[18 + wb_ + dx], rr[px + dx], k1[px]); \
                        }                                                      \
                    }                                                          \
                }                                                              \
            }                                                                  \
        }                                                                      \
        _Pragma("unroll")                                                      \
        for (int px = 0; px < 4; ++px) {                                       \
            SS0 = fmaf(k0[px], k0[px], SS0);                                   \
            SS1 = fmaf(k1[px], k1[px], SS1);                                   \
        }                                                                      \
        store_hl4(&fr[2][2 * (P)][x0l],     &fr[3][2 * (P)][x0l],     k0);     \
        store_hl4(&fr[2][2 * (P) + 1][x0l], &fr[3][2 * (P) + 1][x0l], k1);     \
    }

#define ST_Q(FI)                                                               \
    {                                                                          \
        int ch = (FI) >> 5;                                                    \
        int xo = ((FI) & 31) * 4;                                              \
        float4 v = *(const float4*)(qrow + (size_t)ch * HWc + xo);             \
        float vv[4] = {v.x, v.y, v.z, v.w};                                    \
        store_hl4(&fr[0][ch][xo], &fr[1][ch][xo], vv);                         \
    }

// ---- fused: grouped3x3(kmid) -> k (hi/lo bf16 LDS) + MFMA Gram + ssq_k ----
__global__ __launch_bounds__(256) void k_logits_kernel(
    const float* __restrict__ mid, const float* __restrict__ w2,
    const float* __restrict__ qg, float* __restrict__ attn_raw,
    float* __restrict__ ssq_k)
{
    __shared__ ushort fr[4][32][136];
    __shared__ float wls[24 * 18];

    int bx = blockIdx.x;
    int yt = bx >> 1, xh = bx & 1;
    int h = blockIdx.y, b = blockIdx.z;
    int xbase = xh * 128;
    int t = threadIdx.x, lane = t & 63, wvi = t >> 6;
    int hi = lane >> 5, l32 = lane & 31;

    const float* midb = mid + ((size_t)b * 96 + h * 24) * HWc;
    const float* qb   = qg  + ((size_t)b * 96 + h * 24) * HWc;

    if (t < 108)
        *(float4*)&wls[4 * t] = *(const float4*)(w2 + (size_t)h * 432 + 4 * t);
    for (int i = t; i < 2176; i += 256) {
        int plane = i / 544, idx = i % 544;
        ((uint*)&fr[plane][24][0])[idx] = 0;
    }

    int pA = 2 * wvi + hi;
    int pB = 8 + 2 * wvi + hi;
    int x0l = l32 * 4;
    int xg = xbase + x0l;

    int mi = wvi >> 1, nj = wvi & 1;
    int prow16 = lane & 15, kb = (lane >> 4) * 8;

    f32x4 acc = {0.f, 0.f, 0.f, 0.f};
    float ssqA0 = 0.f, ssqA1 = 0.f, ssqB0 = 0.f, ssqB1 = 0.f;

    __syncthreads();

    for (int r = 0; r < 8; ++r) {
        int y = yt * 8 + r;
        __syncthreads();

        {
            const float* qrow = qb + (size_t)y * Wd + xbase;
            int fi = t;
            ST_Q(fi);
            fi = t + 256;
            ST_Q(fi);
        }
        CONV_PAIR(pA, ssqA0, ssqA1);
        if (t < 128) {
            CONV_PAIR(pB, ssqB0, ssqB1);
        } else {
            const float* qrow = qb + (size_t)y * Wd + xbase;
            int fi = 512 + (t - 128);
            ST_Q(fi);
            fi = 640 + (t - 128);
            ST_Q(fi);
        }
        __syncthreads();

#pragma unroll
        for (int ks2 = 0; ks2 < 4; ++ks2) {
            int col = ks2 * 32 + kb;
            bf16x8 ah = *(const bf16x8*)&fr[0][mi * 16 + prow16][col];
            bf16x8 al = *(const bf16x8*)&fr[1][mi * 16 + prow16][col];
            bf16x8 bh = *(const bf16x8*)&fr[2][nj * 16 + prow16][col];
            bf16x8 bl = *(const bf16x8*)&fr[3][nj * 16 + prow16][col];
            acc = __builtin_amdgcn_mfma_f32_16x16x32_bf16(ah, bh, acc, 0, 0, 0);
            acc = __builtin_amdgcn_mfma_f32_16x16x32_bf16(ah, bl, acc, 0, 0, 0);
            acc = __builtin_amdgcn_mfma_f32_16x16x32_bf16(al, bh, acc, 0, 0, 0);
        }
    }

    {
        float s0 = ssqA0, s1 = ssqA1;
#pragma unroll
        for (int off = 16; off; off >>= 1) {
            s0 += __shfl_down(s0, off, 32);
            s1 += __shfl_down(s1, off, 32);
        }
        if (l32 == 0) {
            atomicAdd(&ssq_k[b * 96 + h * 24 + 2 * pA],     s0);
            atomicAdd(&ssq_k[b * 96 + h * 24 + 2 * pA + 1], s1);
        }
    }
    if (t < 128) {
        float s0 = ssqB0, s1 = ssqB1;
#pragma unroll
        for (int off = 16; off; off >>= 1) {
            s0 += __shfl_down(s0, off, 32);
            s1 += __shfl_down(s1, off, 32);
        }
        if (l32 == 0) {
            atomicAdd(&ssq_k[b * 96 + h * 24 + 2 * pB],     s0);
            atomicAdd(&ssq_k[b * 96 + h * 24 + 2 * pB + 1], s1);
        }
    }

    int jcol = nj * 16 + (lane & 15);
    if (jcol < 24) {
        float* dst = attn_raw + ((size_t)b * 4 + h) * 576;
#pragma unroll
        for (int rg = 0; rg < 4; ++rg) {
            int irow = mi * 16 + (lane >> 4) * 4 + rg;
            if (irow < 24)
                atomicAdd(&dst[irow * 24 + jcol], acc[rg]);
        }
    }
}

// ---- softmax (+temperature, +norms), fold proj -> W2 bf16 hi/lo frag table ----
__global__ __launch_bounds__(256) void softmax_fold_kernel(
    const float* __restrict__ attn_raw,
    const float* __restrict__ ssq_q, const float* __restrict__ ssq_k,
    const float* __restrict__ temp, const float* __restrict__ projw,
    ushort* __restrict__ W2F)
{
    __shared__ float s[24][25];
    __shared__ float rq[24], rk[24];
    int h = blockIdx.x, b = blockIdx.y;
    int t = threadIdx.x;

    if (t < 24) {
        rq[t] = 1.f / fmaxf(sqrtf(ssq_q[b * 96 + h * 24 + t]), 1e-12f);
        rk[t] = 1.f / fmaxf(sqrtf(ssq_k[b * 96 + h * 24 + t]), 1e-12f);
    }
    __syncthreads();
    float T = temp[h];
    for (int p = t; p < 576; p += 256) {
        int i = p / 24, j = p % 24;
        s[i][j] = attn_raw[(size_t)(b * 4 + h) * 576 + p] * T * rq[i] * rk[j];
    }
    __syncthreads();
    if (t < 24) {
        float m = -1e30f;
#pragma unroll
        for (int j = 0; j < 24; ++j) m = fmaxf(m, s[t][j]);
        float sum = 0.f;
#pragma unroll
        for (int j = 0; j < 24; ++j) { float e = __expf(s[t][j] - m); s[t][j] = e; sum += e; }
        float inv = 1.f / sum;
#pragma unroll
        for (int j = 0; j < 24; ++j) s[t][j] *= inv;
    }
    __syncthreads();
    ushort* wfb = W2F + (size_t)b * 18432;
    for (int m_ = t; m_ < 96 * 24; m_ += 256) {
        int d = m_ % 24, co = m_ / 24;
        float acc = 0.f;
#pragma unroll
        for (int c = 0; c < 24; ++c)
            acc += projw[co * 96 + h * 24 + c] * s[c][d];
        int dv = h * 24 + d;
        int ks = dv >> 5, kk = dv & 31;
        ushort hi = f2bf_hi(acc);
        float lo = acc - bf2f(hi);
        wfb[ks * 3072 + co * 32 + kk] = hi;
        wfb[9216 + ks * 3072 + co * 32 + kk] = f2bf_hi(lo);
    }
}

// ---- v_proj via MFMA ----
__global__ __launch_bounds__(384) void v_proj_mfma(
    const float* __restrict__ mid, const float* __restrict__ w2,
    const ushort* __restrict__ W2F, float* __restrict__ out)
{
    __shared__ ushort Ah[64][128];
    __shared__ ushort Al[64][128];
    __shared__ float wls[1728];

    int bx = blockIdx.x, b = blockIdx.y;
    int y = bx >> 2;
    int x0 = (bx & 3) * 64;
    int t = threadIdx.x, lane = t & 63, wv = t >> 6;
    const float* midb = mid + (size_t)b * 96 * HWc;

    for (int i = t; i < 432; i += 384)
        *(float4*)&wls[4 * i] = *(const float4*)(w2 + 96 * 18 + 4 * i);

    int m = 16 * wv + (lane & 15);
    int kbase = (lane >> 4) * 8;
    const ushort* wfb = W2F + (size_t)b * 18432;
    bf16x8 Bh[3], Bl[3];
#pragma unroll
    for (int ks = 0; ks < 3; ++ks) {
        Bh[ks] = *(const bf16x8*)&wfb[ks * 3072 + m * 32 + kbase];
        Bl[ks] = *(const bf16x8*)&wfb[9216 + ks * 3072 + m * 32 + kbase];
    }
    __syncthreads();   // wls ready

    {
        int p = t >> 3;
        int xl = (t & 7) * 8;
        int xg = x0 + xl;
        const float* m0 = midb + (size_t)(2 * p) * HWc;
        const float* m1 = m0 + HWc;
        const float* wp_ = &wls[p * 36];
        float k0[8] = {0.f,0.f,0.f,0.f,0.f,0.f,0.f,0.f};
        float k1[8] = {0.f,0.f,0.f,0.f,0.f,0.f,0.f,0.f};
#pragma unroll
        for (int dy = 0; dy < 3; ++dy) {
            int yy = y + dy - 1;
            if ((unsigned)yy < (unsigned)Hd) {
#pragma unroll
                for (int ic = 0; ic < 2; ++ic) {
                    const float* base = (ic ? m1 : m0) + (size_t)yy * Wd;
                    float4 a = *(const float4*)(base + xg);
                    float4 b2 = *(const float4*)(base + xg + 4);
                    float rr[10];
                    rr[0] = (xg > 0) ? base[xg - 1] : 0.f;
                    rr[1] = a.x; rr[2] = a.y; rr[3] = a.z; rr[4] = a.w;
                    rr[5] = b2.x; rr[6] = b2.y; rr[7] = b2.z; rr[8] = b2.w;
                    rr[9] = (xg + 8 < 256) ? base[xg + 8] : 0.f;
                    int wb_ = ic * 9 + dy * 3;
#pragma unroll
                    for (int px = 0; px < 8; ++px) {
#pragma unroll
                        for (int dx = 0; dx < 3; ++dx) {
                            k0[px] = fmaf(wp_[wb_ + dx],      rr[px + dx], k0[px]);
                            k1[px] = fmaf(wp_[18 + wb_ + dx], rr[px + dx], k1[px]);
                        }
                    }
                }
            }
        }
#pragma unroll
        for (int px = 0; px < 8; ++px) {
            int row = xl + px;
            uint off = ((uint)(4 * p)) ^ rsw(row);
            ushort h0 = f2bf_hi(k0[px]);
            ushort h1 = f2bf_hi(k1[px]);
            float l0 = k0[px] - bf2f(h0);
            float l1 = k1[px] - bf2f(h1);
            *(uint*)((char*)&Ah[row][0] + off) = (uint)h0 | ((uint)h1 << 16);
            *(uint*)((char*)&Al[row][0] + off) =
                (uint)f2bf_hi(l0) | ((uint)f2bf_hi(l1) << 16);
        }
    }
    __syncthreads();

    f32x4 acc0 = {0.f, 0.f, 0.f, 0.f};
    f32x4 acc1 = {0.f, 0.f, 0.f, 0.f};
    f32x4 acc2 = {0.f, 0.f, 0.f, 0.f};
    f32x4 acc3 = {0.f, 0.f, 0.f, 0.f};
    int prow = lane & 15;

#pragma unroll
    for (int ks = 0; ks < 3; ++ks) {
        uint cbyte = (uint)(ks * 32 + kbase) * 2;
#define DO_PT(PT, ACC)                                                         \
        {                                                                      \
            int row = (PT) * 16 + prow;                                        \
            uint off = cbyte ^ rsw(row);                                       \
            bf16x8 ah = *(const bf16x8*)((char*)&Ah[row][0] + off);            \
            bf16x8 al = *(const bf16x8*)((char*)&Al[row][0] + off);            \
            ACC = __builtin_amdgcn_mfma_f32_16x16x32_bf16(ah, Bh[ks], ACC, 0, 0, 0); \
            ACC = __builtin_amdgcn_mfma_f32_16x16x32_bf16(ah, Bl[ks], ACC, 0, 0, 0); \
            ACC = __builtin_amdgcn_mfma_f32_16x16x32_bf16(al, Bh[ks], ACC, 0, 0, 0); \
        }
        DO_PT(0, acc0) DO_PT(1, acc1) DO_PT(2, acc2) DO_PT(3, acc3)
#undef DO_PT
    }

    int pq = (lane >> 4) * 4;
    float* outm = out + (size_t)b * 96 * HWc + (size_t)m * HWc
                + (size_t)y * Wd + x0 + pq;
    *(f32x4*)(outm + 0)  = acc0;
    *(f32x4*)(outm + 16) = acc1;
    *(f32x4*)(outm + 32) = acc2;
    *(f32x4*)(outm + 48) = acc3;
}

extern "C" void kernel_launch(void* const* d_in, const int* in_sizes, int n_in,
                              void* d_out, int out_size, void* d_ws, size_t ws_size,
                              hipStream_t stream) {
    const float* x     = (const float*)d_in[0];
    const float* z     = (const float*)d_in[1];
    const float* kvw1  = (const float*)d_in[2];
    const float* kvw2  = (const float*)d_in[3];
    const float* qw1   = (const float*)d_in[4];
    const float* qw2   = (const float*)d_in[5];
    const float* projw = (const float*)d_in[6];
    const float* temp  = (const float*)d_in[7];
    float* out = (float*)d_out;
    float* ws  = (float*)d_ws;
    (void)in_sizes; (void)n_in; (void)out_size;

    float* ssq_q = ws + SSQ_Q_OFF;
    float* ssq_k = ws + SSQ_K_OFF;
    float* attn  = ws + ATTN_OFF;
    ushort* qwf  = (ushort*)(ws + QWF_OFF);
    ushort* kwf  = (ushort*)(ws + KWF_OFF);
    ushort* vwf  = (ushort*)(ws + VWF_OFF);
    ushort* w2f  = (ushort*)(ws + W2F_OFF);
    float* ws1   = ws + WS1_OFF;
    float* ws2   = ws1 + WS1_LEN;

    // can kmid + vmid live simultaneously?
    bool fused_kv = ws_size >= (size_t)(WS1_OFF + 2 * WS1_LEN) * sizeof(float);

    hipMemsetAsync(ws, 0, (768 + 768 + 18432) * sizeof(float), stream);

    prep_wfrag<<<dim3(36), 256, 0, stream>>>(qw1, 0, qwf);
    prep_wfrag<<<dim3(36), 256, 0, stream>>>(kvw1, 0, kwf);
    prep_wfrag<<<dim3(36), 256, 0, stream>>>(kvw1, 96, vwf);

    // ---- q path ----
    conv1x1_mfma<<<dim3(1024, 8), 384, 0, stream>>>(x, qwf, ws1);                    // q1
    depthwise3x3_kernel<<<dim3(8, 96, 8), 256, 0, stream>>>(ws1, qw2, out, ssq_q);   // q

    if (fused_kv) {
        // one z read: kmid -> ws1, vmid -> ws2
        conv1x1_mfma_kv<<<dim3(1024, 8), 384, 0, stream>>>(z, kwf, vwf, ws1, ws2);
        k_logits_kernel<<<dim3(64, 4, 8), 256, 0, stream>>>(ws1, kvw2, out, attn, ssq_k);
        softmax_fold_kernel<<<dim3(4, 8), 256, 0, stream>>>(attn, ssq_q, ssq_k, temp, projw, w2f);
        v_proj_mfma<<<dim3(1024, 8), 384, 0, stream>>>(ws2, kvw2, w2f, out);
    } else {
        conv1x1_mfma<<<dim3(1024, 8), 384, 0, stream>>>(z, kwf, ws1);                // kmid
        k_logits_kernel<<<dim3(64, 4, 8), 256, 0, stream>>>(ws1, kvw2, out, attn, ssq_k);
        softmax_fold_kernel<<<dim3(4, 8), 256, 0, stream>>>(attn, ssq_q, ssq_k, temp, projw, w2f);
        conv1x1_mfma<<<dim3(1024, 8), 384, 0, stream>>>(z, vwf, ws1);                // vmid
        v_proj_mfma<<<dim3(1024, 8), 384, 0, stream>>>(ws1, kvw2, w2f, out);
    }
}

// Round 25
// 678.426 us; speedup vs baseline: 1.1209x; 1.0051x over previous
//
#include <hip/hip_runtime.h>
#include <math.h>

#define HWc 65536
#define Wd 256
#define Hd 256

typedef __attribute__((ext_vector_type(8))) short bf16x8;
typedef __attribute__((ext_vector_type(4))) float f32x4;

__device__ inline ushort f2bf_hi(float a) {
    uint u = __float_as_uint(a);
    uint r = u + 0x7FFFu + ((u >> 16) & 1u);
    return (ushort)(r >> 16);
}
__device__ inline float bf2f(ushort h) { return __uint_as_float((uint)h << 16); }
__device__ inline uint rsw(int row) {
    return (uint)(((row & 7) ^ ((row >> 3) & 7)) << 4);
}

__device__ inline void store_hl4(ushort* hp, ushort* lp, const float* v) {
    ushort hs[4], ls[4];
#pragma unroll
    for (int e = 0; e < 4; ++e) {
        hs[e] = f2bf_hi(v[e]);
        ls[e] = f2bf_hi(v[e] - bf2f(hs[e]));
    }
    uint2 hv = make_uint2((uint)hs[0] | ((uint)hs[1] << 16),
                          (uint)hs[2] | ((uint)hs[3] << 16));
    uint2 lv = make_uint2((uint)ls[0] | ((uint)ls[1] << 16),
                          (uint)ls[2] | ((uint)ls[3] << 16));
    *(uint2*)hp = hv;
    *(uint2*)lp = lv;
}

// ---- ws layout (float offsets), small buffers FIRST ----
static const size_t SSQ_Q_OFF = 0;        // 768
static const size_t SSQ_K_OFF = 768;      // 768
static const size_t ATTN_OFF  = 1536;     // 18432 -> 19968
static const size_t QWF_OFF   = 19968;
static const size_t KWF_OFF   = 29184;
static const size_t VWF_OFF   = 38400;
static const size_t W2F_OFF   = 47616;    // -> 121344
static const size_t WS1_OFF   = 121344;   // 50331648 floats (201 MB)
static const size_t WS1_LEN   = 50331648; // per mid buffer

// ---- precompute bf16 hi/lo weight frag table ----
__global__ void prep_wfrag(const float* __restrict__ w, int woff,
                           ushort* __restrict__ wf) {
    int idx = blockIdx.x * 256 + threadIdx.x;
    if (idx < 9216) {
        int m = idx / 96, c = idx % 96;
        float val = w[(size_t)(woff + m) * 96 + c];
        ushort hi = f2bf_hi(val);
        float lo = val - bf2f(hi);
        wf[(c >> 5) * 3072 + m * 32 + (c & 31)] = hi;
        wf[9216 + (c >> 5) * 3072 + m * 32 + (c & 31)] = f2bf_hi(lo);
    }
}

// ---- 1x1 conv via MFMA (split-bf16), weights from frag table ----
__global__ __launch_bounds__(384) void conv1x1_mfma(
    const float* __restrict__ in, const ushort* __restrict__ wf,
    float* __restrict__ out)
{
    __shared__ ushort Ah[64][128];
    __shared__ ushort Al[64][128];
    int b = blockIdx.y;
    int px0 = blockIdx.x * 64;
    int t = threadIdx.x, lane = t & 63, wv = t >> 6;
    const float* inb = in + (size_t)b * 96 * HWc + px0;

    int m = 16 * wv + (lane & 15);
    int kbase = (lane >> 4) * 8;
    bf16x8 Bh[3], Bl[3];
#pragma unroll
    for (int ks = 0; ks < 3; ++ks) {
        Bh[ks] = *(const bf16x8*)&wf[ks * 3072 + m * 32 + kbase];
        Bl[ks] = *(const bf16x8*)&wf[9216 + ks * 3072 + m * 32 + kbase];
    }

#pragma unroll
    for (int rr = 0; rr < 4; ++rr) {
        int fi = rr * 384 + t;
        int c = fi >> 4;
        int p4 = (fi & 15) * 4;
        float4 v = *(const float4*)(inb + (size_t)c * HWc + p4);
        float vv[4] = {v.x, v.y, v.z, v.w};
#pragma unroll
        for (int e = 0; e < 4; ++e) {
            int row = p4 + e;
            uint off = ((uint)(2 * c)) ^ rsw(row);
            ushort hi = f2bf_hi(vv[e]);
            float lo = vv[e] - bf2f(hi);
            *(ushort*)((char*)&Ah[row][0] + off) = hi;
            *(ushort*)((char*)&Al[row][0] + off) = f2bf_hi(lo);
        }
    }
    __syncthreads();

    f32x4 acc0 = {0.f, 0.f, 0.f, 0.f};
    f32x4 acc1 = {0.f, 0.f, 0.f, 0.f};
    f32x4 acc2 = {0.f, 0.f, 0.f, 0.f};
    f32x4 acc3 = {0.f, 0.f, 0.f, 0.f};
    int prow = lane & 15;

#pragma unroll
    for (int ks = 0; ks < 3; ++ks) {
        uint cbyte = (uint)(ks * 32 + kbase) * 2;
#define DO_PT(PT, ACC)                                                         \
        {                                                                      \
            int row = (PT) * 16 + prow;                                        \
            uint off = cbyte ^ rsw(row);                                       \
            bf16x8 ah = *(const bf16x8*)((char*)&Ah[row][0] + off);            \
            bf16x8 al = *(const bf16x8*)((char*)&Al[row][0] + off);            \
            ACC = __builtin_amdgcn_mfma_f32_16x16x32_bf16(ah, Bh[ks], ACC, 0, 0, 0); \
            ACC = __builtin_amdgcn_mfma_f32_16x16x32_bf16(ah, Bl[ks], ACC, 0, 0, 0); \
            ACC = __builtin_amdgcn_mfma_f32_16x16x32_bf16(al, Bh[ks], ACC, 0, 0, 0); \
        }
        DO_PT(0, acc0) DO_PT(1, acc1) DO_PT(2, acc2) DO_PT(3, acc3)
#undef DO_PT
    }

    int pq = (lane >> 4) * 4;
    float* outm = out + (size_t)b * 96 * HWc + (size_t)m * HWc + px0 + pq;
    *(f32x4*)(outm + 0)  = acc0;
    *(f32x4*)(outm + 16) = acc1;
    *(f32x4*)(outm + 32) = acc2;
    *(f32x4*)(outm + 48) = acc3;
}

// ---- fused k+v 1x1 conv: one z read, two frag tables, two outputs ----
__global__ __launch_bounds__(384) void conv1x1_mfma_kv(
    const float* __restrict__ in, const ushort* __restrict__ kwf,
    const ushort* __restrict__ vwf,
    float* __restrict__ outk, float* __restrict__ outv)
{
    __shared__ ushort Ah[64][128];
    __shared__ ushort Al[64][128];
    int b = blockIdx.y;
    int px0 = blockIdx.x * 64;
    int t = threadIdx.x, lane = t & 63, wv = t >> 6;
    const float* inb = in + (size_t)b * 96 * HWc + px0;

    int m = 16 * wv + (lane & 15);
    int kbase = (lane >> 4) * 8;
    bf16x8 Bkh[3], Bkl[3], Bvh[3], Bvl[3];
#pragma unroll
    for (int ks = 0; ks < 3; ++ks) {
        Bkh[ks] = *(const bf16x8*)&kwf[ks * 3072 + m * 32 + kbase];
        Bkl[ks] = *(const bf16x8*)&kwf[9216 + ks * 3072 + m * 32 + kbase];
        Bvh[ks] = *(const bf16x8*)&vwf[ks * 3072 + m * 32 + kbase];
        Bvl[ks] = *(const bf16x8*)&vwf[9216 + ks * 3072 + m * 32 + kbase];
    }

#pragma unroll
    for (int rr = 0; rr < 4; ++rr) {
        int fi = rr * 384 + t;
        int c = fi >> 4;
        int p4 = (fi & 15) * 4;
        float4 v = *(const float4*)(inb + (size_t)c * HWc + p4);
        float vv[4] = {v.x, v.y, v.z, v.w};
#pragma unroll
        for (int e = 0; e < 4; ++e) {
            int row = p4 + e;
            uint off = ((uint)(2 * c)) ^ rsw(row);
            ushort hi = f2bf_hi(vv[e]);
            float lo = vv[e] - bf2f(hi);
            *(ushort*)((char*)&Ah[row][0] + off) = hi;
            *(ushort*)((char*)&Al[row][0] + off) = f2bf_hi(lo);
        }
    }
    __syncthreads();

    f32x4 ak0 = {0.f,0.f,0.f,0.f}, ak1 = {0.f,0.f,0.f,0.f};
    f32x4 ak2 = {0.f,0.f,0.f,0.f}, ak3 = {0.f,0.f,0.f,0.f};
    f32x4 av0 = {0.f,0.f,0.f,0.f}, av1 = {0.f,0.f,0.f,0.f};
    f32x4 av2 = {0.f,0.f,0.f,0.f}, av3 = {0.f,0.f,0.f,0.f};
    int prow = lane & 15;

#pragma unroll
    for (int ks = 0; ks < 3; ++ks) {
        uint cbyte = (uint)(ks * 32 + kbase) * 2;
#define DO_PT2(PT, AK, AV)                                                     \
        {                                                                      \
            int row = (PT) * 16 + prow;                                        \
            uint off = cbyte ^ rsw(row);                                       \
            bf16x8 ah = *(const bf16x8*)((char*)&Ah[row][0] + off);            \
            bf16x8 al = *(const bf16x8*)((char*)&Al[row][0] + off);            \
            AK = __builtin_amdgcn_mfma_f32_16x16x32_bf16(ah, Bkh[ks], AK, 0, 0, 0); \
            AK = __builtin_amdgcn_mfma_f32_16x16x32_bf16(ah, Bkl[ks], AK, 0, 0, 0); \
            AK = __builtin_amdgcn_mfma_f32_16x16x32_bf16(al, Bkh[ks], AK, 0, 0, 0); \
            AV = __builtin_amdgcn_mfma_f32_16x16x32_bf16(ah, Bvh[ks], AV, 0, 0, 0); \
            AV = __builtin_amdgcn_mfma_f32_16x16x32_bf16(ah, Bvl[ks], AV, 0, 0, 0); \
            AV = __builtin_amdgcn_mfma_f32_16x16x32_bf16(al, Bvh[ks], AV, 0, 0, 0); \
        }
        DO_PT2(0, ak0, av0) DO_PT2(1, ak1, av1)
        DO_PT2(2, ak2, av2) DO_PT2(3, ak3, av3)
#undef DO_PT2
    }

    int pq = (lane >> 4) * 4;
    float* outm = outk + (size_t)b * 96 * HWc + (size_t)m * HWc + px0 + pq;
    *(f32x4*)(outm + 0)  = ak0;
    *(f32x4*)(outm + 16) = ak1;
    *(f32x4*)(outm + 32) = ak2;
    *(f32x4*)(outm + 48) = ak3;
    float* outn = outv + (size_t)b * 96 * HWc + (size_t)m * HWc + px0 + pq;
    *(f32x4*)(outn + 0)  = av0;
    *(f32x4*)(outn + 16) = av1;
    *(f32x4*)(outn + 32) = av2;
    *(f32x4*)(outn + 48) = av3;
}

// ---- merged q + kv 1x1 conv: blockIdx.y<8 => q path (in=x), else kv path ----
// Independent block populations co-scheduled -> HBM phases of one path overlap
// compute/LDS phases of the other.
__global__ __launch_bounds__(384) void conv1x1_mfma_qkv(
    const float* __restrict__ x, const float* __restrict__ z,
    const ushort* __restrict__ qwf, const ushort* __restrict__ kwf,
    const ushort* __restrict__ vwf,
    float* __restrict__ outq, float* __restrict__ outk, float* __restrict__ outv)
{
    __shared__ ushort Ah[64][128];
    __shared__ ushort Al[64][128];
    int yb2 = blockIdx.y;
    bool qpath = yb2 < 8;
    int b = qpath ? yb2 : yb2 - 8;
    const float* in = qpath ? x : z;
    int px0 = blockIdx.x * 64;
    int t = threadIdx.x, lane = t & 63, wv = t >> 6;
    const float* inb = in + (size_t)b * 96 * HWc + px0;

    int m = 16 * wv + (lane & 15);
    int kbase = (lane >> 4) * 8;

    // staging (common)
#pragma unroll
    for (int rr = 0; rr < 4; ++rr) {
        int fi = rr * 384 + t;
        int c = fi >> 4;
        int p4 = (fi & 15) * 4;
        float4 v = *(const float4*)(inb + (size_t)c * HWc + p4);
        float vv[4] = {v.x, v.y, v.z, v.w};
#pragma unroll
        for (int e = 0; e < 4; ++e) {
            int row = p4 + e;
            uint off = ((uint)(2 * c)) ^ rsw(row);
            ushort hi = f2bf_hi(vv[e]);
            float lo = vv[e] - bf2f(hi);
            *(ushort*)((char*)&Ah[row][0] + off) = hi;
            *(ushort*)((char*)&Al[row][0] + off) = f2bf_hi(lo);
        }
    }

    int prow = lane & 15;
    int pq = (lane >> 4) * 4;

    if (qpath) {
        bf16x8 Bh[3], Bl[3];
#pragma unroll
        for (int ks = 0; ks < 3; ++ks) {
            Bh[ks] = *(const bf16x8*)&qwf[ks * 3072 + m * 32 + kbase];
            Bl[ks] = *(const bf16x8*)&qwf[9216 + ks * 3072 + m * 32 + kbase];
        }
        __syncthreads();
        f32x4 acc0 = {0.f,0.f,0.f,0.f}, acc1 = {0.f,0.f,0.f,0.f};
        f32x4 acc2 = {0.f,0.f,0.f,0.f}, acc3 = {0.f,0.f,0.f,0.f};
#pragma unroll
        for (int ks = 0; ks < 3; ++ks) {
            uint cbyte = (uint)(ks * 32 + kbase) * 2;
#define DO_PT(PT, ACC)                                                         \
            {                                                                  \
                int row = (PT) * 16 + prow;                                    \
                uint off = cbyte ^ rsw(row);                                   \
                bf16x8 ah = *(const bf16x8*)((char*)&Ah[row][0] + off);        \
                bf16x8 al = *(const bf16x8*)((char*)&Al[row][0] + off);        \
                ACC = __builtin_amdgcn_mfma_f32_16x16x32_bf16(ah, Bh[ks], ACC, 0, 0, 0); \
                ACC = __builtin_amdgcn_mfma_f32_16x16x32_bf16(ah, Bl[ks], ACC, 0, 0, 0); \
                ACC = __builtin_amdgcn_mfma_f32_16x16x32_bf16(al, Bh[ks], ACC, 0, 0, 0); \
            }
            DO_PT(0, acc0) DO_PT(1, acc1) DO_PT(2, acc2) DO_PT(3, acc3)
#undef DO_PT
        }
        float* outm = outq + (size_t)b * 96 * HWc + (size_t)m * HWc + px0 + pq;
        *(f32x4*)(outm + 0)  = acc0;
        *(f32x4*)(outm + 16) = acc1;
        *(f32x4*)(outm + 32) = acc2;
        *(f32x4*)(outm + 48) = acc3;
    } else {
        bf16x8 Bkh[3], Bkl[3], Bvh[3], Bvl[3];
#pragma unroll
        for (int ks = 0; ks < 3; ++ks) {
            Bkh[ks] = *(const bf16x8*)&kwf[ks * 3072 + m * 32 + kbase];
            Bkl[ks] = *(const bf16x8*)&kwf[9216 + ks * 3072 + m * 32 + kbase];
            Bvh[ks] = *(const bf16x8*)&vwf[ks * 3072 + m * 32 + kbase];
            Bvl[ks] = *(const bf16x8*)&vwf[9216 + ks * 3072 + m * 32 + kbase];
        }
        __syncthreads();
        f32x4 ak0 = {0.f,0.f,0.f,0.f}, ak1 = {0.f,0.f,0.f,0.f};
        f32x4 ak2 = {0.f,0.f,0.f,0.f}, ak3 = {0.f,0.f,0.f,0.f};
        f32x4 av0 = {0.f,0.f,0.f,0.f}, av1 = {0.f,0.f,0.f,0.f};
        f32x4 av2 = {0.f,0.f,0.f,0.f}, av3 = {0.f,0.f,0.f,0.f};
#pragma unroll
        for (int ks = 0; ks < 3; ++ks) {
            uint cbyte = (uint)(ks * 32 + kbase) * 2;
#define DO_PT2(PT, AK, AV)                                                     \
            {                                                                  \
                int row = (PT) * 16 + prow;                                    \
                uint off = cbyte ^ rsw(row);                                   \
                bf16x8 ah = *(const bf16x8*)((char*)&Ah[row][0] + off);        \
                bf16x8 al = *(const bf16x8*)((char*)&Al[row][0] + off);        \
                AK = __builtin_amdgcn_mfma_f32_16x16x32_bf16(ah, Bkh[ks], AK, 0, 0, 0); \
                AK = __builtin_amdgcn_mfma_f32_16x16x32_bf16(ah, Bkl[ks], AK, 0, 0, 0); \
                AK = __builtin_amdgcn_mfma_f32_16x16x32_bf16(al, Bkh[ks], AK, 0, 0, 0); \
                AV = __builtin_amdgcn_mfma_f32_16x16x32_bf16(ah, Bvh[ks], AV, 0, 0, 0); \
                AV = __builtin_amdgcn_mfma_f32_16x16x32_bf16(ah, Bvl[ks], AV, 0, 0, 0); \
                AV = __builtin_amdgcn_mfma_f32_16x16x32_bf16(al, Bvh[ks], AV, 0, 0, 0); \
            }
            DO_PT2(0, ak0, av0) DO_PT2(1, ak1, av1)
            DO_PT2(2, ak2, av2) DO_PT2(3, ak3, av3)
#undef DO_PT2
        }
        float* outm = outk + (size_t)b * 96 * HWc + (size_t)m * HWc + px0 + pq;
        *(f32x4*)(outm + 0)  = ak0;
        *(f32x4*)(outm + 16) = ak1;
        *(f32x4*)(outm + 32) = ak2;
        *(f32x4*)(outm + 48) = ak3;
        float* outn = outv + (size_t)b * 96 * HWc + (size_t)m * HWc + px0 + pq;
        *(f32x4*)(outn + 0)  = av0;
        *(f32x4*)(outn + 16) = av1;
        *(f32x4*)(outn + 32) = av2;
        *(f32x4*)(outn + 48) = av3;
    }
}

// ---- depthwise 3x3 (pad=1) + per-channel sumsq ----
__global__ __launch_bounds__(256) void depthwise3x3_kernel(
    const float* __restrict__ in, const float* __restrict__ wq,
    float* __restrict__ out, float* __restrict__ ssq_q)
{
    __shared__ float red[4];
    int c = blockIdx.y, b = blockIdx.z;
    int t = threadIdx.x;
    int lane = t & 63;
    int xq = lane * 4;
    int yb = blockIdx.x * 32 + (t >> 6) * 8;

    const float* inc = in + ((size_t)(b * 96 + c)) * HWc;
    float* outc = out + ((size_t)(b * 96 + c)) * HWc;

    float w[9];
    const float* wp = wq + (size_t)c * 9;
#pragma unroll
    for (int i = 0; i < 9; ++i) w[i] = wp[i];

    float rows[3][6];

#define LOAD_ROW(yy, slot)                                                     \
    {                                                                          \
        float4 v_;                                                             \
        if ((unsigned)(yy) < (unsigned)Hd)                                     \
            v_ = *(const float4*)(inc + (size_t)(yy) * Wd + xq);               \
        else                                                                   \
            v_ = make_float4(0.f, 0.f, 0.f, 0.f);                              \
        float lw_ = __shfl_up(v_.w, 1, 64);                                    \
        float rx_ = __shfl_down(v_.x, 1, 64);                                  \
        rows[slot][0] = (lane > 0) ? lw_ : 0.f;                                \
        rows[slot][1] = v_.x; rows[slot][2] = v_.y;                            \
        rows[slot][3] = v_.z; rows[slot][4] = v_.w;                            \
        rows[slot][5] = (lane < 63) ? rx_ : 0.f;                               \
    }

    LOAD_ROW(yb - 1, 0);
    LOAD_ROW(yb, 1);

    float ssq = 0.f;
#pragma unroll
    for (int r = 0; r < 8; ++r) {
        LOAD_ROW(yb + r + 1, (r + 2) % 3);
        const float* ra = rows[r % 3];
        const float* rb = rows[(r + 1) % 3];
        const float* rc = rows[(r + 2) % 3];
        float a[4] = {0.f, 0.f, 0.f, 0.f};
#pragma unroll
        for (int dx = 0; dx < 3; ++dx)
#pragma unroll
            for (int px = 0; px < 4; ++px) {
                a[px] = fmaf(w[dx],     ra[px + dx], a[px]);
                a[px] = fmaf(w[3 + dx], rb[px + dx], a[px]);
                a[px] = fmaf(w[6 + dx], rc[px + dx], a[px]);
            }
        *(float4*)(outc + (size_t)(yb + r) * Wd + xq) = *(float4*)a;
#pragma unroll
        for (int px = 0; px < 4; ++px) ssq = fmaf(a[px], a[px], ssq);
    }
#undef LOAD_ROW

#pragma unroll
    for (int off = 32; off; off >>= 1) ssq += __shfl_down(ssq, off, 64);
    int wvi = t >> 6;
    if (lane == 0) red[wvi] = ssq;
    __syncthreads();
    if (t == 0) atomicAdd(&ssq_q[b * 96 + c], red[0] + red[1] + red[2] + red[3]);
}

// conv macro for k_logits
#define CONV_PAIR(P, SS0, SS1)                                                 \
    {                                                                          \
        const float* m0 = midb + (size_t)(2 * (P)) * HWc;                      \
        const float* m1 = m0 + HWc;                                            \
        const float* wp_ = &wls[(P) * 36];                                     \
        float k0[4] = {0.f, 0.f, 0.f, 0.f};                                    \
        float k1[4] = {0.f, 0.f, 0.f, 0.f};                                    \
        _Pragma("unroll")                                                      \
        for (int dy = 0; dy < 3; ++dy) {                                       \
            int yy = y + dy - 1;                                               \
            if ((unsigned)yy < (unsigned)Hd) {                                 \
                _Pragma("unroll")                                              \
                for (int ic = 0; ic < 2; ++ic) {                               \
                    const float* base = (ic ? m1 : m0) + (size_t)yy * Wd;      \
                    float4 cv = *(const float4*)(base + xg);                   \
                    float rr[6];                                               \
                    rr[0] = (xg > 0) ? base[xg - 1] : 0.f;                     \
                    rr[1] = cv.x; rr[2] = cv.y; rr[3] = cv.z; rr[4] = cv.w;    \
                    rr[5] = (xg < 252) ? base[xg + 4] : 0.f;                   \
                    int wb_ = ic * 9 + dy * 3;                                 \
                    _Pragma("unroll")                                          \
                    for (int px = 0; px < 4; ++px) {                           \
                        _Pragma("unroll")                                      \
                        for (int dx = 0; dx < 3; ++dx) {                       \
                            k0[px] = fmaf(wp_[wb_ + dx],      rr[px + dx], k0[px]); \
                            k1[px] = fmaf(wp_[18 + wb_ + dx], rr[px + dx], k1[px]); \
                        }                                                      \
                    }                                                          \
                }                                                              \
            }                                                                  \
        }                                                                      \
        _Pragma("unroll")                                                      \
        for (int px = 0; px < 4; ++px) {                                       \
            SS0 = fmaf(k0[px], k0[px], SS0);                                   \
            SS1 = fmaf(k1[px], k1[px], SS1);                                   \
        }                                                                      \
        store_hl4(&fr[2][2 * (P)][x0l],     &fr[3][2 * (P)][x0l],     k0);     \
        store_hl4(&fr[2][2 * (P) + 1][x0l], &fr[3][2 * (P) + 1][x0l], k1);     \
    }

#define ST_Q(FI)                                                               \
    {                                                                          \
        int ch = (FI) >> 5;                                                    \
        int xo = ((FI) & 31) * 4;                                              \
        float4 v = *(const float4*)(qrow + (size_t)ch * HWc + xo);             \
        float vv[4] = {v.x, v.y, v.z, v.w};                                    \
        store_hl4(&fr[0][ch][xo], &fr[1][ch][xo], vv);                         \
    }

// ---- fused: grouped3x3(kmid) -> k (hi/lo bf16 LDS) + MFMA Gram + ssq_k ----
__global__ __launch_bounds__(256) void k_logits_kernel(
    const float* __restrict__ mid, const float* __restrict__ w2,
    const float* __restrict__ qg, float* __restrict__ attn_raw,
    float* __restrict__ ssq_k)
{
    __shared__ ushort fr[4][32][136];
    __shared__ float wls[24 * 18];

    int bx = blockIdx.x;
    int yt = bx >> 1, xh = bx & 1;
    int h = blockIdx.y, b = blockIdx.z;
    int xbase = xh * 128;
    int t = threadIdx.x, lane = t & 63, wvi = t >> 6;
    int hi = lane >> 5, l32 = lane & 31;

    const float* midb = mid + ((size_t)b * 96 + h * 24) * HWc;
    const float* qb   = qg  + ((size_t)b * 96 + h * 24) * HWc;

    if (t < 108)
        *(float4*)&wls[4 * t] = *(const float4*)(w2 + (size_t)h * 432 + 4 * t);
    for (int i = t; i < 2176; i += 256) {
        int plane = i / 544, idx = i % 544;
        ((uint*)&fr[plane][24][0])[idx] = 0;
    }

    int pA = 2 * wvi + hi;
    int pB = 8 + 2 * wvi + hi;
    int x0l = l32 * 4;
    int xg = xbase + x0l;

    int mi = wvi >> 1, nj = wvi & 1;
    int prow16 = lane & 15, kb = (lane >> 4) * 8;

    f32x4 acc = {0.f, 0.f, 0.f, 0.f};
    float ssqA0 = 0.f, ssqA1 = 0.f, ssqB0 = 0.f, ssqB1 = 0.f;

    __syncthreads();

    for (int r = 0; r < 8; ++r) {
        int y = yt * 8 + r;
        __syncthreads();

        {
            const float* qrow = qb + (size_t)y * Wd + xbase;
            int fi = t;
            ST_Q(fi);
            fi = t + 256;
            ST_Q(fi);
        }
        CONV_PAIR(pA, ssqA0, ssqA1);
        if (t < 128) {
            CONV_PAIR(pB, ssqB0, ssqB1);
        } else {
            const float* qrow = qb + (size_t)y * Wd + xbase;
            int fi = 512 + (t - 128);
            ST_Q(fi);
            fi = 640 + (t - 128);
            ST_Q(fi);
        }
        __syncthreads();

#pragma unroll
        for (int ks2 = 0; ks2 < 4; ++ks2) {
            int col = ks2 * 32 + kb;
            bf16x8 ah = *(const bf16x8*)&fr[0][mi * 16 + prow16][col];
            bf16x8 al = *(const bf16x8*)&fr[1][mi * 16 + prow16][col];
            bf16x8 bh = *(const bf16x8*)&fr[2][nj * 16 + prow16][col];
            bf16x8 bl = *(const bf16x8*)&fr[3][nj * 16 + prow16][col];
            acc = __builtin_amdgcn_mfma_f32_16x16x32_bf16(ah, bh, acc, 0, 0, 0);
            acc = __builtin_amdgcn_mfma_f32_16x16x32_bf16(ah, bl, acc, 0, 0, 0);
            acc = __builtin_amdgcn_mfma_f32_16x16x32_bf16(al, bh, acc, 0, 0, 0);
        }
    }

    {
        float s0 = ssqA0, s1 = ssqA1;
#pragma unroll
        for (int off = 16; off; off >>= 1) {
            s0 += __shfl_down(s0, off, 32);
            s1 += __shfl_down(s1, off, 32);
        }
        if (l32 == 0) {
            atomicAdd(&ssq_k[b * 96 + h * 24 + 2 * pA],     s0);
            atomicAdd(&ssq_k[b * 96 + h * 24 + 2 * pA + 1], s1);
        }
    }
    if (t < 128) {
        float s0 = ssqB0, s1 = ssqB1;
#pragma unroll
        for (int off = 16; off; off >>= 1) {
            s0 += __shfl_down(s0, off, 32);
            s1 += __shfl_down(s1, off, 32);
        }
        if (l32 == 0) {
            atomicAdd(&ssq_k[b * 96 + h * 24 + 2 * pB],     s0);
            atomicAdd(&ssq_k[b * 96 + h * 24 + 2 * pB + 1], s1);
        }
    }

    int jcol = nj * 16 + (lane & 15);
    if (jcol < 24) {
        float* dst = attn_raw + ((size_t)b * 4 + h) * 576;
#pragma unroll
        for (int rg = 0; rg < 4; ++rg) {
            int irow = mi * 16 + (lane >> 4) * 4 + rg;
            if (irow < 24)
                atomicAdd(&dst[irow * 24 + jcol], acc[rg]);
        }
    }
}

// ---- softmax (+temperature, +norms), fold proj -> W2 bf16 hi/lo frag table ----
__global__ __launch_bounds__(256) void softmax_fold_kernel(
    const float* __restrict__ attn_raw,
    const float* __restrict__ ssq_q, const float* __restrict__ ssq_k,
    const float* __restrict__ temp, const float* __restrict__ projw,
    ushort* __restrict__ W2F)
{
    __shared__ float s[24][25];
    __shared__ float rq[24], rk[24];
    int h = blockIdx.x, b = blockIdx.y;
    int t = threadIdx.x;

    if (t < 24) {
        rq[t] = 1.f / fmaxf(sqrtf(ssq_q[b * 96 + h * 24 + t]), 1e-12f);
        rk[t] = 1.f / fmaxf(sqrtf(ssq_k[b * 96 + h * 24 + t]), 1e-12f);
    }
    __syncthreads();
    float T = temp[h];
    for (int p = t; p < 576; p += 256) {
        int i = p / 24, j = p % 24;
        s[i][j] = attn_raw[(size_t)(b * 4 + h) * 576 + p] * T * rq[i] * rk[j];
    }
    __syncthreads();
    if (t < 24) {
        float m = -1e30f;
#pragma unroll
        for (int j = 0; j < 24; ++j) m = fmaxf(m, s[t][j]);
        float sum = 0.f;
#pragma unroll
        for (int j = 0; j < 24; ++j) { float e = __expf(s[t][j] - m); s[t][j] = e; sum += e; }
        float inv = 1.f / sum;
#pragma unroll
        for (int j = 0; j < 24; ++j) s[t][j] *= inv;
    }
    __syncthreads();
    ushort* wfb = W2F + (size_t)b * 18432;
    for (int m_ = t; m_ < 96 * 24; m_ += 256) {
        int d = m_ % 24, co = m_ / 24;
        float acc = 0.f;
#pragma unroll
        for (int c = 0; c < 24; ++c)
            acc += projw[co * 96 + h * 24 + c] * s[c][d];
        int dv = h * 24 + d;
        int ks = dv >> 5, kk = dv & 31;
        ushort hi = f2bf_hi(acc);
        float lo = acc - bf2f(hi);
        wfb[ks * 3072 + co * 32 + kk] = hi;
        wfb[9216 + ks * 3072 + co * 32 + kk] = f2bf_hi(lo);
    }
}

// ---- v_proj via MFMA ----
__global__ __launch_bounds__(384) void v_proj_mfma(
    const float* __restrict__ mid, const float* __restrict__ w2,
    const ushort* __restrict__ W2F, float* __restrict__ out)
{
    __shared__ ushort Ah[64][128];
    __shared__ ushort Al[64][128];
    __shared__ float wls[1728];

    int bx = blockIdx.x, b = blockIdx.y;
    int y = bx >> 2;
    int x0 = (bx & 3) * 64;
    int t = threadIdx.x, lane = t & 63, wv = t >> 6;
    const float* midb = mid + (size_t)b * 96 * HWc;

    for (int i = t; i < 432; i += 384)
        *(float4*)&wls[4 * i] = *(const float4*)(w2 + 96 * 18 + 4 * i);

    int m = 16 * wv + (lane & 15);
    int kbase = (lane >> 4) * 8;
    const ushort* wfb = W2F + (size_t)b * 18432;
    bf16x8 Bh[3], Bl[3];
#pragma unroll
    for (int ks = 0; ks < 3; ++ks) {
        Bh[ks] = *(const bf16x8*)&wfb[ks * 3072 + m * 32 + kbase];
        Bl[ks] = *(const bf16x8*)&wfb[9216 + ks * 3072 + m * 32 + kbase];
    }
    __syncthreads();   // wls ready

    {
        int p = t >> 3;
        int xl = (t & 7) * 8;
        int xg = x0 + xl;
        const float* m0 = midb + (size_t)(2 * p) * HWc;
        const float* m1 = m0 + HWc;
        const float* wp_ = &wls[p * 36];
        float k0[8] = {0.f,0.f,0.f,0.f,0.f,0.f,0.f,0.f};
        float k1[8] = {0.f,0.f,0.f,0.f,0.f,0.f,0.f,0.f};
#pragma unroll
        for (int dy = 0; dy < 3; ++dy) {
            int yy = y + dy - 1;
            if ((unsigned)yy < (unsigned)Hd) {
#pragma unroll
                for (int ic = 0; ic < 2; ++ic) {
                    const float* base = (ic ? m1 : m0) + (size_t)yy * Wd;
                    float4 a = *(const float4*)(base + xg);
                    float4 b2 = *(const float4*)(base + xg + 4);
                    float rr[10];
                    rr[0] = (xg > 0) ? base[xg - 1] : 0.f;
                    rr[1] = a.x; rr[2] = a.y; rr[3] = a.z; rr[4] = a.w;
                    rr[5] = b2.x; rr[6] = b2.y; rr[7] = b2.z; rr[8] = b2.w;
                    rr[9] = (xg + 8 < 256) ? base[xg + 8] : 0.f;
                    int wb_ = ic * 9 + dy * 3;
#pragma unroll
                    for (int px = 0; px < 8; ++px) {
#pragma unroll
                        for (int dx = 0; dx < 3; ++dx) {
                            k0[px] = fmaf(wp_[wb_ + dx],      rr[px + dx], k0[px]);
                            k1[px] = fmaf(wp_[18 + wb_ + dx], rr[px + dx], k1[px]);
                        }
                    }
                }
            }
        }
#pragma unroll
        for (int px = 0; px < 8; ++px) {
            int row = xl + px;
            uint off = ((uint)(4 * p)) ^ rsw(row);
            ushort h0 = f2bf_hi(k0[px]);
            ushort h1 = f2bf_hi(k1[px]);
            float l0 = k0[px] - bf2f(h0);
            float l1 = k1[px] - bf2f(h1);
            *(uint*)((char*)&Ah[row][0] + off) = (uint)h0 | ((uint)h1 << 16);
            *(uint*)((char*)&Al[row][0] + off) =
                (uint)f2bf_hi(l0) | ((uint)f2bf_hi(l1) << 16);
        }
    }
    __syncthreads();

    f32x4 acc0 = {0.f, 0.f, 0.f, 0.f};
    f32x4 acc1 = {0.f, 0.f, 0.f, 0.f};
    f32x4 acc2 = {0.f, 0.f, 0.f, 0.f};
    f32x4 acc3 = {0.f, 0.f, 0.f, 0.f};
    int prow = lane & 15;

#pragma unroll
    for (int ks = 0; ks < 3; ++ks) {
        uint cbyte = (uint)(ks * 32 + kbase) * 2;
#define DO_PT(PT, ACC)                                                         \
        {                                                                      \
            int row = (PT) * 16 + prow;                                        \
            uint off = cbyte ^ rsw(row);                                       \
            bf16x8 ah = *(const bf16x8*)((char*)&Ah[row][0] + off);            \
            bf16x8 al = *(const bf16x8*)((char*)&Al[row][0] + off);            \
            ACC = __builtin_amdgcn_mfma_f32_16x16x32_bf16(ah, Bh[ks], ACC, 0, 0, 0); \
            ACC = __builtin_amdgcn_mfma_f32_16x16x32_bf16(ah, Bl[ks], ACC, 0, 0, 0); \
            ACC = __builtin_amdgcn_mfma_f32_16x16x32_bf16(al, Bh[ks], ACC, 0, 0, 0); \
        }
        DO_PT(0, acc0) DO_PT(1, acc1) DO_PT(2, acc2) DO_PT(3, acc3)
#undef DO_PT
    }

    int pq = (lane >> 4) * 4;
    float* outm = out + (size_t)b * 96 * HWc + (size_t)m * HWc
                + (size_t)y * Wd + x0 + pq;
    *(f32x4*)(outm + 0)  = acc0;
    *(f32x4*)(outm + 16) = acc1;
    *(f32x4*)(outm + 32) = acc2;
    *(f32x4*)(outm + 48) = acc3;
}

extern "C" void kernel_launch(void* const* d_in, const int* in_sizes, int n_in,
                              void* d_out, int out_size, void* d_ws, size_t ws_size,
                              hipStream_t stream) {
    const float* x     = (const float*)d_in[0];
    const float* z     = (const float*)d_in[1];
    const float* kvw1  = (const float*)d_in[2];
    const float* kvw2  = (const float*)d_in[3];
    const float* qw1   = (const float*)d_in[4];
    const float* qw2   = (const float*)d_in[5];
    const float* projw = (const float*)d_in[6];
    const float* temp  = (const float*)d_in[7];
    float* out = (float*)d_out;
    float* ws  = (float*)d_ws;
    (void)in_sizes; (void)n_in; (void)out_size;

    float* ssq_q = ws + SSQ_Q_OFF;
    float* ssq_k = ws + SSQ_K_OFF;
    float* attn  = ws + ATTN_OFF;
    ushort* qwf  = (ushort*)(ws + QWF_OFF);
    ushort* kwf  = (ushort*)(ws + KWF_OFF);
    ushort* vwf  = (ushort*)(ws + VWF_OFF);
    ushort* w2f  = (ushort*)(ws + W2F_OFF);
    float* ws1   = ws + WS1_OFF;
    float* ws2   = ws1 + WS1_LEN;
    float* ws3   = ws2 + WS1_LEN;

    bool fused3  = ws_size >= (size_t)(WS1_OFF + 3 * WS1_LEN) * sizeof(float);
    bool fused_kv = ws_size >= (size_t)(WS1_OFF + 2 * WS1_LEN) * sizeof(float);

    hipMemsetAsync(ws, 0, (768 + 768 + 18432) * sizeof(float), stream);

    prep_wfrag<<<dim3(36), 256, 0, stream>>>(qw1, 0, qwf);
    prep_wfrag<<<dim3(36), 256, 0, stream>>>(kvw1, 0, kwf);
    prep_wfrag<<<dim3(36), 256, 0, stream>>>(kvw1, 96, vwf);

    if (fused3) {
        // merged q + kv conv: q1->ws3, kmid->ws1, vmid->ws2 (one launch; the
        // two block populations overlap each other's HBM/compute phases)
        conv1x1_mfma_qkv<<<dim3(1024, 16), 384, 0, stream>>>(
            x, z, qwf, kwf, vwf, ws3, ws1, ws2);
        depthwise3x3_kernel<<<dim3(8, 96, 8), 256, 0, stream>>>(ws3, qw2, out, ssq_q);
        k_logits_kernel<<<dim3(64, 4, 8), 256, 0, stream>>>(ws1, kvw2, out, attn, ssq_k);
        softmax_fold_kernel<<<dim3(4, 8), 256, 0, stream>>>(attn, ssq_q, ssq_k, temp, projw, w2f);
        v_proj_mfma<<<dim3(1024, 8), 384, 0, stream>>>(ws2, kvw2, w2f, out);
    } else if (fused_kv) {
        conv1x1_mfma<<<dim3(1024, 8), 384, 0, stream>>>(x, qwf, ws1);
        depthwise3x3_kernel<<<dim3(8, 96, 8), 256, 0, stream>>>(ws1, qw2, out, ssq_q);
        conv1x1_mfma_kv<<<dim3(1024, 8), 384, 0, stream>>>(z, kwf, vwf, ws1, ws2);
        k_logits_kernel<<<dim3(64, 4, 8), 256, 0, stream>>>(ws1, kvw2, out, attn, ssq_k);
        softmax_fold_kernel<<<dim3(4, 8), 256, 0, stream>>>(attn, ssq_q, ssq_k, temp, projw, w2f);
        v_proj_mfma<<<dim3(1024, 8), 384, 0, stream>>>(ws2, kvw2, w2f, out);
    } else {
        conv1x1_mfma<<<dim3(1024, 8), 384, 0, stream>>>(x, qwf, ws1);
        depthwise3x3_kernel<<<dim3(8, 96, 8), 256, 0, stream>>>(ws1, qw2, out, ssq_q);
        conv1x1_mfma<<<dim3(1024, 8), 384, 0, stream>>>(z, kwf, ws1);
        k_logits_kernel<<<dim3(64, 4, 8), 256, 0, stream>>>(ws1, kvw2, out, attn, ssq_k);
        softmax_fold_kernel<<<dim3(4, 8), 256, 0, stream>>>(attn, ssq_q, ssq_k, temp, projw, w2f);
        conv1x1_mfma<<<dim3(1024, 8), 384, 0, stream>>>(z, vwf, ws1);
        v_proj_mfma<<<dim3(1024, 8), 384, 0, stream>>>(ws1, kvw2, w2f, out);
    }
}

// Round 26
// 676.941 us; speedup vs baseline: 1.1233x; 1.0022x over previous
//
#include <hip/hip_runtime.h>
#include <math.h>

#define HWc 65536
#define Wd 256
#define Hd 256

typedef __attribute__((ext_vector_type(8))) short bf16x8;
typedef __attribute__((ext_vector_type(4))) float f32x4;

__device__ inline ushort f2bf_hi(float a) {
    uint u = __float_as_uint(a);
    uint r = u + 0x7FFFu + ((u >> 16) & 1u);
    return (ushort)(r >> 16);
}
__device__ inline float bf2f(ushort h) { return __uint_as_float((uint)h << 16); }
__device__ inline uint rsw(int row) {
    return (uint)(((row & 7) ^ ((row >> 3) & 7)) << 4);
}

__device__ inline void store_hl4(ushort* hp, ushort* lp, const float* v) {
    ushort hs[4], ls[4];
#pragma unroll
    for (int e = 0; e < 4; ++e) {
        hs[e] = f2bf_hi(v[e]);
        ls[e] = f2bf_hi(v[e] - bf2f(hs[e]));
    }
    uint2 hv = make_uint2((uint)hs[0] | ((uint)hs[1] << 16),
                          (uint)hs[2] | ((uint)hs[3] << 16));
    uint2 lv = make_uint2((uint)ls[0] | ((uint)ls[1] << 16),
                          (uint)ls[2] | ((uint)ls[3] << 16));
    *(uint2*)hp = hv;
    *(uint2*)lp = lv;
}

// ---- ws layout (float offsets), small buffers FIRST ----
static const size_t SSQ_Q_OFF = 0;        // 768
static const size_t SSQ_K_OFF = 768;      // 768
static const size_t ATTN_OFF  = 1536;     // 18432 -> 19968
static const size_t QWF_OFF   = 19968;
static const size_t KWF_OFF   = 29184;
static const size_t VWF_OFF   = 38400;
static const size_t W2F_OFF   = 47616;    // -> 121344
static const size_t WS1_OFF   = 121344;   // 50331648 floats (201 MB)
static const size_t WS1_LEN   = 50331648; // per mid buffer

// ---- precompute bf16 hi/lo weight frag table ----
__global__ void prep_wfrag(const float* __restrict__ w, int woff,
                           ushort* __restrict__ wf) {
    int idx = blockIdx.x * 256 + threadIdx.x;
    if (idx < 9216) {
        int m = idx / 96, c = idx % 96;
        float val = w[(size_t)(woff + m) * 96 + c];
        ushort hi = f2bf_hi(val);
        float lo = val - bf2f(hi);
        wf[(c >> 5) * 3072 + m * 32 + (c & 31)] = hi;
        wf[9216 + (c >> 5) * 3072 + m * 32 + (c & 31)] = f2bf_hi(lo);
    }
}

// ---- 1x1 conv via MFMA (split-bf16), weights from frag table ----
__global__ __launch_bounds__(384) void conv1x1_mfma(
    const float* __restrict__ in, const ushort* __restrict__ wf,
    float* __restrict__ out)
{
    __shared__ ushort Ah[64][128];
    __shared__ ushort Al[64][128];
    int b = blockIdx.y;
    int px0 = blockIdx.x * 64;
    int t = threadIdx.x, lane = t & 63, wv = t >> 6;
    const float* inb = in + (size_t)b * 96 * HWc + px0;

    int m = 16 * wv + (lane & 15);
    int kbase = (lane >> 4) * 8;
    bf16x8 Bh[3], Bl[3];
#pragma unroll
    for (int ks = 0; ks < 3; ++ks) {
        Bh[ks] = *(const bf16x8*)&wf[ks * 3072 + m * 32 + kbase];
        Bl[ks] = *(const bf16x8*)&wf[9216 + ks * 3072 + m * 32 + kbase];
    }

#pragma unroll
    for (int rr = 0; rr < 4; ++rr) {
        int fi = rr * 384 + t;
        int c = fi >> 4;
        int p4 = (fi & 15) * 4;
        float4 v = *(const float4*)(inb + (size_t)c * HWc + p4);
        float vv[4] = {v.x, v.y, v.z, v.w};
#pragma unroll
        for (int e = 0; e < 4; ++e) {
            int row = p4 + e;
            uint off = ((uint)(2 * c)) ^ rsw(row);
            ushort hi = f2bf_hi(vv[e]);
            float lo = vv[e] - bf2f(hi);
            *(ushort*)((char*)&Ah[row][0] + off) = hi;
            *(ushort*)((char*)&Al[row][0] + off) = f2bf_hi(lo);
        }
    }
    __syncthreads();

    f32x4 acc0 = {0.f, 0.f, 0.f, 0.f};
    f32x4 acc1 = {0.f, 0.f, 0.f, 0.f};
    f32x4 acc2 = {0.f, 0.f, 0.f, 0.f};
    f32x4 acc3 = {0.f, 0.f, 0.f, 0.f};
    int prow = lane & 15;

#pragma unroll
    for (int ks = 0; ks < 3; ++ks) {
        uint cbyte = (uint)(ks * 32 + kbase) * 2;
#define DO_PT(PT, ACC)                                                         \
        {                                                                      \
            int row = (PT) * 16 + prow;                                        \
            uint off = cbyte ^ rsw(row);                                       \
            bf16x8 ah = *(const bf16x8*)((char*)&Ah[row][0] + off);            \
            bf16x8 al = *(const bf16x8*)((char*)&Al[row][0] + off);            \
            ACC = __builtin_amdgcn_mfma_f32_16x16x32_bf16(ah, Bh[ks], ACC, 0, 0, 0); \
            ACC = __builtin_amdgcn_mfma_f32_16x16x32_bf16(ah, Bl[ks], ACC, 0, 0, 0); \
            ACC = __builtin_amdgcn_mfma_f32_16x16x32_bf16(al, Bh[ks], ACC, 0, 0, 0); \
        }
        DO_PT(0, acc0) DO_PT(1, acc1) DO_PT(2, acc2) DO_PT(3, acc3)
#undef DO_PT
    }

    int pq = (lane >> 4) * 4;
    float* outm = out + (size_t)b * 96 * HWc + (size_t)m * HWc + px0 + pq;
    *(f32x4*)(outm + 0)  = acc0;
    *(f32x4*)(outm + 16) = acc1;
    *(f32x4*)(outm + 32) = acc2;
    *(f32x4*)(outm + 48) = acc3;
}

// ---- fused k+v 1x1 conv: one z read, two frag tables, two outputs ----
__global__ __launch_bounds__(384) void conv1x1_mfma_kv(
    const float* __restrict__ in, const ushort* __restrict__ kwf,
    const ushort* __restrict__ vwf,
    float* __restrict__ outk, float* __restrict__ outv)
{
    __shared__ ushort Ah[64][128];
    __shared__ ushort Al[64][128];
    int b = blockIdx.y;
    int px0 = blockIdx.x * 64;
    int t = threadIdx.x, lane = t & 63, wv = t >> 6;
    const float* inb = in + (size_t)b * 96 * HWc + px0;

    int m = 16 * wv + (lane & 15);
    int kbase = (lane >> 4) * 8;
    bf16x8 Bkh[3], Bkl[3], Bvh[3], Bvl[3];
#pragma unroll
    for (int ks = 0; ks < 3; ++ks) {
        Bkh[ks] = *(const bf16x8*)&kwf[ks * 3072 + m * 32 + kbase];
        Bkl[ks] = *(const bf16x8*)&kwf[9216 + ks * 3072 + m * 32 + kbase];
        Bvh[ks] = *(const bf16x8*)&vwf[ks * 3072 + m * 32 + kbase];
        Bvl[ks] = *(const bf16x8*)&vwf[9216 + ks * 3072 + m * 32 + kbase];
    }

#pragma unroll
    for (int rr = 0; rr < 4; ++rr) {
        int fi = rr * 384 + t;
        int c = fi >> 4;
        int p4 = (fi & 15) * 4;
        float4 v = *(const float4*)(inb + (size_t)c * HWc + p4);
        float vv[4] = {v.x, v.y, v.z, v.w};
#pragma unroll
        for (int e = 0; e < 4; ++e) {
            int row = p4 + e;
            uint off = ((uint)(2 * c)) ^ rsw(row);
            ushort hi = f2bf_hi(vv[e]);
            float lo = vv[e] - bf2f(hi);
            *(ushort*)((char*)&Ah[row][0] + off) = hi;
            *(ushort*)((char*)&Al[row][0] + off) = f2bf_hi(lo);
        }
    }
    __syncthreads();

    f32x4 ak0 = {0.f,0.f,0.f,0.f}, ak1 = {0.f,0.f,0.f,0.f};
    f32x4 ak2 = {0.f,0.f,0.f,0.f}, ak3 = {0.f,0.f,0.f,0.f};
    f32x4 av0 = {0.f,0.f,0.f,0.f}, av1 = {0.f,0.f,0.f,0.f};
    f32x4 av2 = {0.f,0.f,0.f,0.f}, av3 = {0.f,0.f,0.f,0.f};
    int prow = lane & 15;

#pragma unroll
    for (int ks = 0; ks < 3; ++ks) {
        uint cbyte = (uint)(ks * 32 + kbase) * 2;
#define DO_PT2(PT, AK, AV)                                                     \
        {                                                                      \
            int row = (PT) * 16 + prow;                                        \
            uint off = cbyte ^ rsw(row);                                       \
            bf16x8 ah = *(const bf16x8*)((char*)&Ah[row][0] + off);            \
            bf16x8 al = *(const bf16x8*)((char*)&Al[row][0] + off);            \
            AK = __builtin_amdgcn_mfma_f32_16x16x32_bf16(ah, Bkh[ks], AK, 0, 0, 0); \
            AK = __builtin_amdgcn_mfma_f32_16x16x32_bf16(ah, Bkl[ks], AK, 0, 0, 0); \
            AK = __builtin_amdgcn_mfma_f32_16x16x32_bf16(al, Bkh[ks], AK, 0, 0, 0); \
            AV = __builtin_amdgcn_mfma_f32_16x16x32_bf16(ah, Bvh[ks], AV, 0, 0, 0); \
            AV = __builtin_amdgcn_mfma_f32_16x16x32_bf16(ah, Bvl[ks], AV, 0, 0, 0); \
            AV = __builtin_amdgcn_mfma_f32_16x16x32_bf16(al, Bvh[ks], AV, 0, 0, 0); \
        }
        DO_PT2(0, ak0, av0) DO_PT2(1, ak1, av1)
        DO_PT2(2, ak2, av2) DO_PT2(3, ak3, av3)
#undef DO_PT2
    }

    int pq = (lane >> 4) * 4;
    float* outm = outk + (size_t)b * 96 * HWc + (size_t)m * HWc + px0 + pq;
    *(f32x4*)(outm + 0)  = ak0;
    *(f32x4*)(outm + 16) = ak1;
    *(f32x4*)(outm + 32) = ak2;
    *(f32x4*)(outm + 48) = ak3;
    float* outn = outv + (size_t)b * 96 * HWc + (size_t)m * HWc + px0 + pq;
    *(f32x4*)(outn + 0)  = av0;
    *(f32x4*)(outn + 16) = av1;
    *(f32x4*)(outn + 32) = av2;
    *(f32x4*)(outn + 48) = av3;
}

// ---- merged q + kv 1x1 conv: blockIdx.y<8 => q path (in=x), else kv path ----
__global__ __launch_bounds__(384) void conv1x1_mfma_qkv(
    const float* __restrict__ x, const float* __restrict__ z,
    const ushort* __restrict__ qwf, const ushort* __restrict__ kwf,
    const ushort* __restrict__ vwf,
    float* __restrict__ outq, float* __restrict__ outk, float* __restrict__ outv)
{
    __shared__ ushort Ah[64][128];
    __shared__ ushort Al[64][128];
    int yb2 = blockIdx.y;
    bool qpath = yb2 < 8;
    int b = qpath ? yb2 : yb2 - 8;
    const float* in = qpath ? x : z;
    int px0 = blockIdx.x * 64;
    int t = threadIdx.x, lane = t & 63, wv = t >> 6;
    const float* inb = in + (size_t)b * 96 * HWc + px0;

    int m = 16 * wv + (lane & 15);
    int kbase = (lane >> 4) * 8;

#pragma unroll
    for (int rr = 0; rr < 4; ++rr) {
        int fi = rr * 384 + t;
        int c = fi >> 4;
        int p4 = (fi & 15) * 4;
        float4 v = *(const float4*)(inb + (size_t)c * HWc + p4);
        float vv[4] = {v.x, v.y, v.z, v.w};
#pragma unroll
        for (int e = 0; e < 4; ++e) {
            int row = p4 + e;
            uint off = ((uint)(2 * c)) ^ rsw(row);
            ushort hi = f2bf_hi(vv[e]);
            float lo = vv[e] - bf2f(hi);
            *(ushort*)((char*)&Ah[row][0] + off) = hi;
            *(ushort*)((char*)&Al[row][0] + off) = f2bf_hi(lo);
        }
    }

    int prow = lane & 15;
    int pq = (lane >> 4) * 4;

    if (qpath) {
        bf16x8 Bh[3], Bl[3];
#pragma unroll
        for (int ks = 0; ks < 3; ++ks) {
            Bh[ks] = *(const bf16x8*)&qwf[ks * 3072 + m * 32 + kbase];
            Bl[ks] = *(const bf16x8*)&qwf[9216 + ks * 3072 + m * 32 + kbase];
        }
        __syncthreads();
        f32x4 acc0 = {0.f,0.f,0.f,0.f}, acc1 = {0.f,0.f,0.f,0.f};
        f32x4 acc2 = {0.f,0.f,0.f,0.f}, acc3 = {0.f,0.f,0.f,0.f};
#pragma unroll
        for (int ks = 0; ks < 3; ++ks) {
            uint cbyte = (uint)(ks * 32 + kbase) * 2;
#define DO_PT(PT, ACC)                                                         \
            {                                                                  \
                int row = (PT) * 16 + prow;                                    \
                uint off = cbyte ^ rsw(row);                                   \
                bf16x8 ah = *(const bf16x8*)((char*)&Ah[row][0] + off);        \
                bf16x8 al = *(const bf16x8*)((char*)&Al[row][0] + off);        \
                ACC = __builtin_amdgcn_mfma_f32_16x16x32_bf16(ah, Bh[ks], ACC, 0, 0, 0); \
                ACC = __builtin_amdgcn_mfma_f32_16x16x32_bf16(ah, Bl[ks], ACC, 0, 0, 0); \
                ACC = __builtin_amdgcn_mfma_f32_16x16x32_bf16(al, Bh[ks], ACC, 0, 0, 0); \
            }
            DO_PT(0, acc0) DO_PT(1, acc1) DO_PT(2, acc2) DO_PT(3, acc3)
#undef DO_PT
        }
        float* outm = outq + (size_t)b * 96 * HWc + (size_t)m * HWc + px0 + pq;
        *(f32x4*)(outm + 0)  = acc0;
        *(f32x4*)(outm + 16) = acc1;
        *(f32x4*)(outm + 32) = acc2;
        *(f32x4*)(outm + 48) = acc3;
    } else {
        bf16x8 Bkh[3], Bkl[3], Bvh[3], Bvl[3];
#pragma unroll
        for (int ks = 0; ks < 3; ++ks) {
            Bkh[ks] = *(const bf16x8*)&kwf[ks * 3072 + m * 32 + kbase];
            Bkl[ks] = *(const bf16x8*)&kwf[9216 + ks * 3072 + m * 32 + kbase];
            Bvh[ks] = *(const bf16x8*)&vwf[ks * 3072 + m * 32 + kbase];
            Bvl[ks] = *(const bf16x8*)&vwf[9216 + ks * 3072 + m * 32 + kbase];
        }
        __syncthreads();
        f32x4 ak0 = {0.f,0.f,0.f,0.f}, ak1 = {0.f,0.f,0.f,0.f};
        f32x4 ak2 = {0.f,0.f,0.f,0.f}, ak3 = {0.f,0.f,0.f,0.f};
        f32x4 av0 = {0.f,0.f,0.f,0.f}, av1 = {0.f,0.f,0.f,0.f};
        f32x4 av2 = {0.f,0.f,0.f,0.f}, av3 = {0.f,0.f,0.f,0.f};
#pragma unroll
        for (int ks = 0; ks < 3; ++ks) {
            uint cbyte = (uint)(ks * 32 + kbase) * 2;
#define DO_PT2(PT, AK, AV)                                                     \
            {                                                                  \
                int row = (PT) * 16 + prow;                                    \
                uint off = cbyte ^ rsw(row);                                   \
                bf16x8 ah = *(const bf16x8*)((char*)&Ah[row][0] + off);        \
                bf16x8 al = *(const bf16x8*)((char*)&Al[row][0] + off);        \
                AK = __builtin_amdgcn_mfma_f32_16x16x32_bf16(ah, Bkh[ks], AK, 0, 0, 0); \
                AK = __builtin_amdgcn_mfma_f32_16x16x32_bf16(ah, Bkl[ks], AK, 0, 0, 0); \
                AK = __builtin_amdgcn_mfma_f32_16x16x32_bf16(al, Bkh[ks], AK, 0, 0, 0); \
                AV = __builtin_amdgcn_mfma_f32_16x16x32_bf16(ah, Bvh[ks], AV, 0, 0, 0); \
                AV = __builtin_amdgcn_mfma_f32_16x16x32_bf16(ah, Bvl[ks], AV, 0, 0, 0); \
                AV = __builtin_amdgcn_mfma_f32_16x16x32_bf16(al, Bvh[ks], AV, 0, 0, 0); \
            }
            DO_PT2(0, ak0, av0) DO_PT2(1, ak1, av1)
            DO_PT2(2, ak2, av2) DO_PT2(3, ak3, av3)
#undef DO_PT2
        }
        float* outm = outk + (size_t)b * 96 * HWc + (size_t)m * HWc + px0 + pq;
        *(f32x4*)(outm + 0)  = ak0;
        *(f32x4*)(outm + 16) = ak1;
        *(f32x4*)(outm + 32) = ak2;
        *(f32x4*)(outm + 48) = ak3;
        float* outn = outv + (size_t)b * 96 * HWc + (size_t)m * HWc + px0 + pq;
        *(f32x4*)(outn + 0)  = av0;
        *(f32x4*)(outn + 16) = av1;
        *(f32x4*)(outn + 32) = av2;
        *(f32x4*)(outn + 48) = av3;
    }
}

// ---- depthwise 3x3 (pad=1) + per-channel sumsq ----
__global__ __launch_bounds__(256) void depthwise3x3_kernel(
    const float* __restrict__ in, const float* __restrict__ wq,
    float* __restrict__ out, float* __restrict__ ssq_q)
{
    __shared__ float red[4];
    int c = blockIdx.y, b = blockIdx.z;
    int t = threadIdx.x;
    int lane = t & 63;
    int xq = lane * 4;
    int yb = blockIdx.x * 32 + (t >> 6) * 8;

    const float* inc = in + ((size_t)(b * 96 + c)) * HWc;
    float* outc = out + ((size_t)(b * 96 + c)) * HWc;

    float w[9];
    const float* wp = wq + (size_t)c * 9;
#pragma unroll
    for (int i = 0; i < 9; ++i) w[i] = wp[i];

    float rows[3][6];

#define LOAD_ROW(yy, slot)                                                     \
    {                                                                          \
        float4 v_;                                                             \
        if ((unsigned)(yy) < (unsigned)Hd)                                     \
            v_ = *(const float4*)(inc + (size_t)(yy) * Wd + xq);               \
        else                                                                   \
            v_ = make_float4(0.f, 0.f, 0.f, 0.f);                              \
        float lw_ = __shfl_up(v_.w, 1, 64);                                    \
        float rx_ = __shfl_down(v_.x, 1, 64);                                  \
        rows[slot][0] = (lane > 0) ? lw_ : 0.f;                                \
        rows[slot][1] = v_.x; rows[slot][2] = v_.y;                            \
        rows[slot][3] = v_.z; rows[slot][4] = v_.w;                            \
        rows[slot][5] = (lane < 63) ? rx_ : 0.f;                               \
    }

    LOAD_ROW(yb - 1, 0);
    LOAD_ROW(yb, 1);

    float ssq = 0.f;
#pragma unroll
    for (int r = 0; r < 8; ++r) {
        LOAD_ROW(yb + r + 1, (r + 2) % 3);
        const float* ra = rows[r % 3];
        const float* rb = rows[(r + 1) % 3];
        const float* rc = rows[(r + 2) % 3];
        float a[4] = {0.f, 0.f, 0.f, 0.f};
#pragma unroll
        for (int dx = 0; dx < 3; ++dx)
#pragma unroll
            for (int px = 0; px < 4; ++px) {
                a[px] = fmaf(w[dx],     ra[px + dx], a[px]);
                a[px] = fmaf(w[3 + dx], rb[px + dx], a[px]);
                a[px] = fmaf(w[6 + dx], rc[px + dx], a[px]);
            }
        *(float4*)(outc + (size_t)(yb + r) * Wd + xq) = *(float4*)a;
#pragma unroll
        for (int px = 0; px < 4; ++px) ssq = fmaf(a[px], a[px], ssq);
    }
#undef LOAD_ROW

#pragma unroll
    for (int off = 32; off; off >>= 1) ssq += __shfl_down(ssq, off, 64);
    int wvi = t >> 6;
    if (lane == 0) red[wvi] = ssq;
    __syncthreads();
    if (t == 0) atomicAdd(&ssq_q[b * 96 + c], red[0] + red[1] + red[2] + red[3]);
}

// conv macro for k_logits (writes rows < 24, always in fr planes)
#define CONV_PAIR(P, SS0, SS1)                                                 \
    {                                                                          \
        const float* m0 = midb + (size_t)(2 * (P)) * HWc;                      \
        const float* m1 = m0 + HWc;                                            \
        const float* wp_ = &wls[(P) * 36];                                     \
        float k0[4] = {0.f, 0.f, 0.f, 0.f};                                    \
        float k1[4] = {0.f, 0.f, 0.f, 0.f};                                    \
        _Pragma("unroll")                                                      \
        for (int dy = 0; dy < 3; ++dy) {                                       \
            int yy = y + dy - 1;                                               \
            if ((unsigned)yy < (unsigned)Hd) {                                 \
                _Pragma("unroll")                                              \
                for (int ic = 0; ic < 2; ++ic) {                               \
                    const float* base = (ic ? m1 : m0) + (size_t)yy * Wd;      \
                    float4 cv = *(const float4*)(base + xg);                   \
                    float rr[6];                                               \
                    rr[0] = (xg > 0) ? base[xg - 1] : 0.f;                     \
                    rr[1] = cv.x; rr[2] = cv.y; rr[3] = cv.z; rr[4] = cv.w;    \
                    rr[5] = (xg < 252) ? base[xg + 4] : 0.f;                   \
                    int wb_ = ic * 9 + dy * 3;                                 \
                    _Pragma("unroll")                                          \
                    for (int px = 0; px < 4; ++px) {                           \
                        _Pragma("unroll")                                      \
                        for (int dx = 0; dx < 3; ++dx) {                       \
                            k0[px] = fmaf(wp_[wb_ + dx],      rr[px + dx], k0[px]); \
                            k1[px] = fmaf(wp_[18 + wb_ + dx], rr[px + dx], k1[px]); \
                        }                                                      \
                    }                                                          \
                }                                                              \
            }                                                                  \
        }                                                                      \
        _Pragma("unroll")                                                      \
        for (int px = 0; px < 4; ++px) {                                       \
            SS0 = fmaf(k0[px], k0[px], SS0);                                   \
            SS1 = fmaf(k1[px], k1[px], SS1);                                   \
        }                                                                      \
        store_hl4(&fr[2][2 * (P)][x0l],     &fr[3][2 * (P)][x0l],     k0);     \
        store_hl4(&fr[2][2 * (P) + 1][x0l], &fr[3][2 * (P) + 1][x0l], k1);     \
    }

#define ST_Q(FI)                                                               \
    {                                                                          \
        int ch = (FI) >> 5;                                                    \
        int xo = ((FI) & 31) * 4;                                              \
        float4 v = *(const float4*)(qrow + (size_t)ch * HWc + xo);             \
        float vv[4] = {v.x, v.y, v.z, v.w};                                    \
        store_hl4(&fr[0][ch][xo], &fr[1][ch][xo], vv);                         \
    }

// ---- fused: grouped3x3(kmid) -> k (hi/lo bf16 LDS) + MFMA Gram + ssq_k ----
// fr planes now 24 rows each; the 8 zero rows (24..31) that quadrant mi/nj=1
// reads are SHARED across all 4 planes via zpad (saves 8.7KB LDS -> 5 blk/CU).
// Row pointers are per-thread constants, computed once with a select.
__global__ __launch_bounds__(256) void k_logits_kernel(
    const float* __restrict__ mid, const float* __restrict__ w2,
    const float* __restrict__ qg, float* __restrict__ attn_raw,
    float* __restrict__ ssq_k)
{
    __shared__ ushort fr[4][24][136];
    __shared__ ushort zpad[8][136];
    __shared__ float wls[24 * 18];

    int bx = blockIdx.x;
    int yt = bx >> 1, xh = bx & 1;
    int h = blockIdx.y, b = blockIdx.z;
    int xbase = xh * 128;
    int t = threadIdx.x, lane = t & 63, wvi = t >> 6;
    int hi = lane >> 5, l32 = lane & 31;

    const float* midb = mid + ((size_t)b * 96 + h * 24) * HWc;
    const float* qb   = qg  + ((size_t)b * 96 + h * 24) * HWc;

    if (t < 108)
        *(float4*)&wls[4 * t] = *(const float4*)(w2 + (size_t)h * 432 + 4 * t);
    // zero the shared pad rows once (8*136 ushorts = 544 uints)
    for (int i = t; i < 544; i += 256)
        ((uint*)&zpad[0][0])[i] = 0;

    int pA = 2 * wvi + hi;
    int pB = 8 + 2 * wvi + hi;
    int x0l = l32 * 4;
    int xg = xbase + x0l;

    int mi = wvi >> 1, nj = wvi & 1;
    int prow16 = lane & 15, kb = (lane >> 4) * 8;

    // per-thread constant row pointers (select into zpad for rows >= 24)
    int rowA = mi * 16 + prow16;
    int rowB = nj * 16 + prow16;
    const ushort* pa_h = (rowA < 24) ? &fr[0][rowA][0] : &zpad[rowA - 24][0];
    const ushort* pa_l = (rowA < 24) ? &fr[1][rowA][0] : &zpad[rowA - 24][0];
    const ushort* pb_h = (rowB < 24) ? &fr[2][rowB][0] : &zpad[rowB - 24][0];
    const ushort* pb_l = (rowB < 24) ? &fr[3][rowB][0] : &zpad[rowB - 24][0];

    f32x4 acc = {0.f, 0.f, 0.f, 0.f};
    float ssqA0 = 0.f, ssqA1 = 0.f, ssqB0 = 0.f, ssqB1 = 0.f;

    __syncthreads();

    for (int r = 0; r < 8; ++r) {
        int y = yt * 8 + r;
        __syncthreads();

        {
            const float* qrow = qb + (size_t)y * Wd + xbase;
            int fi = t;
            ST_Q(fi);
            fi = t + 256;
            ST_Q(fi);
        }
        CONV_PAIR(pA, ssqA0, ssqA1);
        if (t < 128) {
            CONV_PAIR(pB, ssqB0, ssqB1);
        } else {
            const float* qrow = qb + (size_t)y * Wd + xbase;
            int fi = 512 + (t - 128);
            ST_Q(fi);
            fi = 640 + (t - 128);
            ST_Q(fi);
        }
        __syncthreads();

#pragma unroll
        for (int ks2 = 0; ks2 < 4; ++ks2) {
            int col = ks2 * 32 + kb;
            bf16x8 ah = *(const bf16x8*)(pa_h + col);
            bf16x8 al = *(const bf16x8*)(pa_l + col);
            bf16x8 bh = *(const bf16x8*)(pb_h + col);
            bf16x8 bl = *(const bf16x8*)(pb_l + col);
            acc = __builtin_amdgcn_mfma_f32_16x16x32_bf16(ah, bh, acc, 0, 0, 0);
            acc = __builtin_amdgcn_mfma_f32_16x16x32_bf16(ah, bl, acc, 0, 0, 0);
            acc = __builtin_amdgcn_mfma_f32_16x16x32_bf16(al, bh, acc, 0, 0, 0);
        }
    }

    {
        float s0 = ssqA0, s1 = ssqA1;
#pragma unroll
        for (int off = 16; off; off >>= 1) {
            s0 += __shfl_down(s0, off, 32);
            s1 += __shfl_down(s1, off, 32);
        }
        if (l32 == 0) {
            atomicAdd(&ssq_k[b * 96 + h * 24 + 2 * pA],     s0);
            atomicAdd(&ssq_k[b * 96 + h * 24 + 2 * pA + 1], s1);
        }
    }
    if (t < 128) {
        float s0 = ssqB0, s1 = ssqB1;
#pragma unroll
        for (int off = 16; off; off >>= 1) {
            s0 += __shfl_down(s0, off, 32);
            s1 += __shfl_down(s1, off, 32);
        }
        if (l32 == 0) {
            atomicAdd(&ssq_k[b * 96 + h * 24 + 2 * pB],     s0);
            atomicAdd(&ssq_k[b * 96 + h * 24 + 2 * pB + 1], s1);
        }
    }

    int jcol = nj * 16 + (lane & 15);
    if (jcol < 24) {
        float* dst = attn_raw + ((size_t)b * 4 + h) * 576;
#pragma unroll
        for (int rg = 0; rg < 4; ++rg) {
            int irow = mi * 16 + (lane >> 4) * 4 + rg;
            if (irow < 24)
                atomicAdd(&dst[irow * 24 + jcol], acc[rg]);
        }
    }
}

// ---- softmax (+temperature, +norms), fold proj -> W2 bf16 hi/lo frag table ----
__global__ __launch_bounds__(256) void softmax_fold_kernel(
    const float* __restrict__ attn_raw,
    const float* __restrict__ ssq_q, const float* __restrict__ ssq_k,
    const float* __restrict__ temp, const float* __restrict__ projw,
    ushort* __restrict__ W2F)
{
    __shared__ float s[24][25];
    __shared__ float rq[24], rk[24];
    int h = blockIdx.x, b = blockIdx.y;
    int t = threadIdx.x;

    if (t < 24) {
        rq[t] = 1.f / fmaxf(sqrtf(ssq_q[b * 96 + h * 24 + t]), 1e-12f);
        rk[t] = 1.f / fmaxf(sqrtf(ssq_k[b * 96 + h * 24 + t]), 1e-12f);
    }
    __syncthreads();
    float T = temp[h];
    for (int p = t; p < 576; p += 256) {
        int i = p / 24, j = p % 24;
        s[i][j] = attn_raw[(size_t)(b * 4 + h) * 576 + p] * T * rq[i] * rk[j];
    }
    __syncthreads();
    if (t < 24) {
        float m = -1e30f;
#pragma unroll
        for (int j = 0; j < 24; ++j) m = fmaxf(m, s[t][j]);
        float sum = 0.f;
#pragma unroll
        for (int j = 0; j < 24; ++j) { float e = __expf(s[t][j] - m); s[t][j] = e; sum += e; }
        float inv = 1.f / sum;
#pragma unroll
        for (int j = 0; j < 24; ++j) s[t][j] *= inv;
    }
    __syncthreads();
    ushort* wfb = W2F + (size_t)b * 18432;
    for (int m_ = t; m_ < 96 * 24; m_ += 256) {
        int d = m_ % 24, co = m_ / 24;
        float acc = 0.f;
#pragma unroll
        for (int c = 0; c < 24; ++c)
            acc += projw[co * 96 + h * 24 + c] * s[c][d];
        int dv = h * 24 + d;
        int ks = dv >> 5, kk = dv & 31;
        ushort hi = f2bf_hi(acc);
        float lo = acc - bf2f(hi);
        wfb[ks * 3072 + co * 32 + kk] = hi;
        wfb[9216 + ks * 3072 + co * 32 + kk] = f2bf_hi(lo);
    }
}

// ---- v_proj via MFMA ----
__global__ __launch_bounds__(384) void v_proj_mfma(
    const float* __restrict__ mid, const float* __restrict__ w2,
    const ushort* __restrict__ W2F, float* __restrict__ out)
{
    __shared__ ushort Ah[64][128];
    __shared__ ushort Al[64][128];
    __shared__ float wls[1728];

    int bx = blockIdx.x, b = blockIdx.y;
    int y = bx >> 2;
    int x0 = (bx & 3) * 64;
    int t = threadIdx.x, lane = t & 63, wv = t >> 6;
    const float* midb = mid + (size_t)b * 96 * HWc;

    for (int i = t; i < 432; i += 384)
        *(float4*)&wls[4 * i] = *(const float4*)(w2 + 96 * 18 + 4 * i);

    int m = 16 * wv + (lane & 15);
    int kbase = (lane >> 4) * 8;
    const ushort* wfb = W2F + (size_t)b * 18432;
    bf16x8 Bh[3], Bl[3];
#pragma unroll
    for (int ks = 0; ks < 3; ++ks) {
        Bh[ks] = *(const bf16x8*)&wfb[ks * 3072 + m * 32 + kbase];
        Bl[ks] = *(const bf16x8*)&wfb[9216 + ks * 3072 + m * 32 + kbase];
    }
    __syncthreads();   // wls ready

    {
        int p = t >> 3;
        int xl = (t & 7) * 8;
        int xg = x0 + xl;
        const float* m0 = midb + (size_t)(2 * p) * HWc;
        const float* m1 = m0 + HWc;
        const float* wp_ = &wls[p * 36];
        float k0[8] = {0.f,0.f,0.f,0.f,0.f,0.f,0.f,0.f};
        float k1[8] = {0.f,0.f,0.f,0.f,0.f,0.f,0.f,0.f};
#pragma unroll
        for (int dy = 0; dy < 3; ++dy) {
            int yy = y + dy - 1;
            if ((unsigned)yy < (unsigned)Hd) {
#pragma unroll
                for (int ic = 0; ic < 2; ++ic) {
                    const float* base = (ic ? m1 : m0) + (size_t)yy * Wd;
                    float4 a = *(const float4*)(base + xg);
                    float4 b2 = *(const float4*)(base + xg + 4);
                    float rr[10];
                    rr[0] = (xg > 0) ? base[xg - 1] : 0.f;
                    rr[1] = a.x; rr[2] = a.y; rr[3] = a.z; rr[4] = a.w;
                    rr[5] = b2.x; rr[6] = b2.y; rr[7] = b2.z; rr[8] = b2.w;
                    rr[9] = (xg + 8 < 256) ? base[xg + 8] : 0.f;
                    int wb_ = ic * 9 + dy * 3;
#pragma unroll
                    for (int px = 0; px < 8; ++px) {
#pragma unroll
                        for (int dx = 0; dx < 3; ++dx) {
                            k0[px] = fmaf(wp_[wb_ + dx],      rr[px + dx], k0[px]);
                            k1[px] = fmaf(wp_[18 + wb_ + dx], rr[px + dx], k1[px]);
                        }
                    }
                }
            }
        }
#pragma unroll
        for (int px = 0; px < 8; ++px) {
            int row = xl + px;
            uint off = ((uint)(4 * p)) ^ rsw(row);
            ushort h0 = f2bf_hi(k0[px]);
            ushort h1 = f2bf_hi(k1[px]);
            float l0 = k0[px] - bf2f(h0);
            float l1 = k1[px] - bf2f(h1);
            *(uint*)((char*)&Ah[row][0] + off) = (uint)h0 | ((uint)h1 << 16);
            *(uint*)((char*)&Al[row][0] + off) =
                (uint)f2bf_hi(l0) | ((uint)f2bf_hi(l1) << 16);
        }
    }
    __syncthreads();

    f32x4 acc0 = {0.f, 0.f, 0.f, 0.f};
    f32x4 acc1 = {0.f, 0.f, 0.f, 0.f};
    f32x4 acc2 = {0.f, 0.f, 0.f, 0.f};
    f32x4 acc3 = {0.f, 0.f, 0.f, 0.f};
    int prow = lane & 15;

#pragma unroll
    for (int ks = 0; ks < 3; ++ks) {
        uint cbyte = (uint)(ks * 32 + kbase) * 2;
#define DO_PT(PT, ACC)                                                         \
        {                                                                      \
            int row = (PT) * 16 + prow;                                        \
            uint off = cbyte ^ rsw(row);                                       \
            bf16x8 ah = *(const bf16x8*)((char*)&Ah[row][0] + off);            \
            bf16x8 al = *(const bf16x8*)((char*)&Al[row][0] + off);            \
            ACC = __builtin_amdgcn_mfma_f32_16x16x32_bf16(ah, Bh[ks], ACC, 0, 0, 0); \
            ACC = __builtin_amdgcn_mfma_f32_16x16x32_bf16(ah, Bl[ks], ACC, 0, 0, 0); \
            ACC = __builtin_amdgcn_mfma_f32_16x16x32_bf16(al, Bh[ks], ACC, 0, 0, 0); \
        }
        DO_PT(0, acc0) DO_PT(1, acc1) DO_PT(2, acc2) DO_PT(3, acc3)
#undef DO_PT
    }

    int pq = (lane >> 4) * 4;
    float* outm = out + (size_t)b * 96 * HWc + (size_t)m * HWc
                + (size_t)y * Wd + x0 + pq;
    *(f32x4*)(outm + 0)  = acc0;
    *(f32x4*)(outm + 16) = acc1;
    *(f32x4*)(outm + 32) = acc2;
    *(f32x4*)(outm + 48) = acc3;
}

extern "C" void kernel_launch(void* const* d_in, const int* in_sizes, int n_in,
                              void* d_out, int out_size, void* d_ws, size_t ws_size,
                              hipStream_t stream) {
    const float* x     = (const float*)d_in[0];
    const float* z     = (const float*)d_in[1];
    const float* kvw1  = (const float*)d_in[2];
    const float* kvw2  = (const float*)d_in[3];
    const float* qw1   = (const float*)d_in[4];
    const float* qw2   = (const float*)d_in[5];
    const float* projw = (const float*)d_in[6];
    const float* temp  = (const float*)d_in[7];
    float* out = (float*)d_out;
    float* ws  = (float*)d_ws;
    (void)in_sizes; (void)n_in; (void)out_size;

    float* ssq_q = ws + SSQ_Q_OFF;
    float* ssq_k = ws + SSQ_K_OFF;
    float* attn  = ws + ATTN_OFF;
    ushort* qwf  = (ushort*)(ws + QWF_OFF);
    ushort* kwf  = (ushort*)(ws + KWF_OFF);
    ushort* vwf  = (ushort*)(ws + VWF_OFF);
    ushort* w2f  = (ushort*)(ws + W2F_OFF);
    float* ws1   = ws + WS1_OFF;
    float* ws2   = ws1 + WS1_LEN;
    float* ws3   = ws2 + WS1_LEN;

    bool fused3  = ws_size >= (size_t)(WS1_OFF + 3 * WS1_LEN) * sizeof(float);
    bool fused_kv = ws_size >= (size_t)(WS1_OFF + 2 * WS1_LEN) * sizeof(float);

    hipMemsetAsync(ws, 0, (768 + 768 + 18432) * sizeof(float), stream);

    prep_wfrag<<<dim3(36), 256, 0, stream>>>(qw1, 0, qwf);
    prep_wfrag<<<dim3(36), 256, 0, stream>>>(kvw1, 0, kwf);
    prep_wfrag<<<dim3(36), 256, 0, stream>>>(kvw1, 96, vwf);

    if (fused3) {
        conv1x1_mfma_qkv<<<dim3(1024, 16), 384, 0, stream>>>(
            x, z, qwf, kwf, vwf, ws3, ws1, ws2);
        depthwise3x3_kernel<<<dim3(8, 96, 8), 256, 0, stream>>>(ws3, qw2, out, ssq_q);
        k_logits_kernel<<<dim3(64, 4, 8), 256, 0, stream>>>(ws1, kvw2, out, attn, ssq_k);
        softmax_fold_kernel<<<dim3(4, 8), 256, 0, stream>>>(attn, ssq_q, ssq_k, temp, projw, w2f);
        v_proj_mfma<<<dim3(1024, 8), 384, 0, stream>>>(ws2, kvw2, w2f, out);
    } else if (fused_kv) {
        conv1x1_mfma<<<dim3(1024, 8), 384, 0, stream>>>(x, qwf, ws1);
        depthwise3x3_kernel<<<dim3(8, 96, 8), 256, 0, stream>>>(ws1, qw2, out, ssq_q);
        conv1x1_mfma_kv<<<dim3(1024, 8), 384, 0, stream>>>(z, kwf, vwf, ws1, ws2);
        k_logits_kernel<<<dim3(64, 4, 8), 256, 0, stream>>>(ws1, kvw2, out, attn, ssq_k);
        softmax_fold_kernel<<<dim3(4, 8), 256, 0, stream>>>(attn, ssq_q, ssq_k, temp, projw, w2f);
        v_proj_mfma<<<dim3(1024, 8), 384, 0, stream>>>(ws2, kvw2, w2f, out);
    } else {
        conv1x1_mfma<<<dim3(1024, 8), 384, 0, stream>>>(x, qwf, ws1);
        depthwise3x3_kernel<<<dim3(8, 96, 8), 256, 0, stream>>>(ws1, qw2, out, ssq_q);
        conv1x1_mfma<<<dim3(1024, 8), 384, 0, stream>>>(z, kwf, ws1);
        k_logits_kernel<<<dim3(64, 4, 8), 256, 0, stream>>>(ws1, kvw2, out, attn, ssq_k);
        softmax_fold_kernel<<<dim3(4, 8), 256, 0, stream>>>(attn, ssq_q, ssq_k, temp, projw, w2f);
        conv1x1_mfma<<<dim3(1024, 8), 384, 0, stream>>>(z, vwf, ws1);
        v_proj_mfma<<<dim3(1024, 8), 384, 0, stream>>>(ws1, kvw2, w2f, out);
    }
}